// Round 1
// baseline (1481.235 us; speedup 1.0000x reference)
//
#include <hip/hip_runtime.h>

// B=16, N=512, D=512, NI=32, GH=64, H=8, L=2, OUT=128, heads=8
#define B_   16
#define N_   512
#define D_   512
#define NI_  32
#define GH_  64
#define H_   8
#define OUT_ 128
#define NH_  8

#define BND   (B_*N_*D_)     // 4194304
#define BID   (B_*NI_*D_)    // 262144
#define DD    (D_*D_)        // 262144

#define SP 524               // S row stride in floats (524%32banks=12 -> 2-way max aliasing)

typedef unsigned short u16;
typedef unsigned int   u32;
typedef __attribute__((ext_vector_type(8))) short short8;
typedef __attribute__((ext_vector_type(4))) float f32x4;

__device__ __forceinline__ u16 f2bf(float f){
  u32 x = __float_as_uint(f);
  x += 0x7fffu + ((x >> 16) & 1u);   // RNE
  return (u16)(x >> 16);
}

// blockDim must be 256
__device__ __forceinline__ float block_sum(float v, float* sm){
  #pragma unroll
  for (int o = 32; o; o >>= 1) v += __shfl_down(v, o, 64);
  int lane = threadIdx.x & 63, w = threadIdx.x >> 6;
  __syncthreads();
  if (lane == 0) sm[w] = v;
  __syncthreads();
  return sm[0] + sm[1] + sm[2] + sm[3];
}
__device__ __forceinline__ float block_max(float v, float* sm){
  #pragma unroll
  for (int o = 32; o; o >>= 1) v = fmaxf(v, __shfl_down(v, o, 64));
  int lane = threadIdx.x & 63, w = threadIdx.x >> 6;
  __syncthreads();
  if (lane == 0) sm[w] = v;
  __syncthreads();
  return fmaxf(fmaxf(sm[0], sm[1]), fmaxf(sm[2], sm[3]));
}

// ---------- elementwise ----------
__global__ __launch_bounds__(256) void bcast_k(const float* __restrict__ s, float* __restrict__ d, int n){
  int i = blockIdx.x * 256 + threadIdx.x;
  if (i < n) d[i] = s[i & (NI_*D_ - 1)];
}
__global__ __launch_bounds__(256) void add_relu_k(const float* __restrict__ a, const float* __restrict__ b,
                                                  float* __restrict__ o, int n){
  int i = blockIdx.x * 256 + threadIdx.x;
  if (i < n){ float v = a[i] + b[i]; o[i] = v > 0.0f ? v : 0.0f; }
}
__global__ __launch_bounds__(256) void add_relu_ip_k(float* __restrict__ a, const float* __restrict__ b, int n){
  int i = blockIdx.x * 256 + threadIdx.x;
  if (i < n){ float v = a[i] + b[i]; a[i] = v > 0.0f ? v : 0.0f; }
}
__global__ __launch_bounds__(256) void add_k(const float* __restrict__ a, const float* __restrict__ b,
                                             float* __restrict__ o, int n){
  int i = blockIdx.x * 256 + threadIdx.x;
  if (i < n) o[i] = a[i] + b[i];
}

// ---------- weight swizzle into MFMA B-fragment order ----------
// Bsw unit (s, nt, lane): holds W[k = s*32 + (lane>>4)*8 + j][n = nt*16 + (lane&15)], j=0..7
// offset = ((s*(Nc/16) + nt)*64 + lane)*8 + j
__global__ __launch_bounds__(256) void swz_k(const float* __restrict__ W, u16* __restrict__ o,
                                             int Nc, size_t sW, size_t sO){
  int gw = blockIdx.x * 4 + (threadIdx.x >> 6);
  int lane = threadIdx.x & 63;
  int ntc = Nc >> 4;
  int s = gw / ntc, nt = gw - s * ntc;
  const float* Wb = W + sW * blockIdx.y;
  u16* ob = o + sO * blockIdx.y;
  int n = nt*16 + (lane & 15);
  int kb = s*32 + ((lane >> 4) << 3);
  u16 t8[8];
  #pragma unroll
  for (int j = 0; j < 8; j++) t8[j] = f2bf(Wb[(size_t)(kb + j) * Nc + n]);
  *(short8*)&ob[((size_t)(s * ntc + nt) * 64 + lane) * 8] = *(short8*)t8;
}
// gat_W [H,D,GH] -> head-major-concat [D,512], swizzled
__global__ __launch_bounds__(256) void swz_gatW_k(const float* __restrict__ gw_, u16* __restrict__ o){
  int gw = blockIdx.x * 4 + (threadIdx.x >> 6);  // 512 waves
  int lane = threadIdx.x & 63;
  int s = gw >> 5, nt = gw & 31;
  int n = nt*16 + (lane & 15);
  int h = n >> 6, f = n & 63;
  int kb = s*32 + ((lane >> 4) << 3);
  u16 t8[8];
  #pragma unroll
  for (int j = 0; j < 8; j++) t8[j] = f2bf(gw_[((size_t)(h*512) + kb + j) * 64 + f]);
  *(short8*)&o[((size_t)(s*32 + nt) * 64 + lane) * 8] = *(short8*)t8;
}

// ---------- MFMA GEMM: C[M,Nc](f32) = act(A[M,512](f32->bf16) @ Bsw + bias) + resid ----------
// 128x128 tile, 4 waves, each wave 64x64 (4x4 of 16x16). K = 512 fixed.
// act: 0 none, 1 leaky, 2 elu. Batched over blockIdx.z via strides.
__global__ __launch_bounds__(256) void gemm_mfma(
    const float* __restrict__ A, const u16* __restrict__ Bw,
    const float* __restrict__ bias, const float* __restrict__ resid,
    float* __restrict__ C, int Nc, int act,
    size_t sA, size_t sB, size_t sC, size_t sR)
{
  __shared__ __align__(16) u16 As[128*64];   // frag order: ((mt*2+kt)*64 + lane)*8 + j
  __shared__ __align__(16) u16 Bs[64*128];   // frag order: ((kt*8 + nt)*64 + lane)*8 + j
  A  += sA * blockIdx.z;
  Bw += sB * blockIdx.z;
  C  += sC * blockIdx.z;
  if (resid) resid += sR * blockIdx.z;

  int tid = threadIdx.x, lane = tid & 63, wave = tid >> 6;
  int wm = wave & 1, wn = wave >> 1;
  int row0 = blockIdx.y << 7, col0 = blockIdx.x << 7;
  int ntc = Nc >> 4, nt0 = col0 >> 4;

  f32x4 acc[4][4] = {};

  for (int ks = 0; ks < 8; ks++){
    // stage A (fp32 -> bf16, fragment order)
    #pragma unroll
    for (int r = 0; r < 4; r++){
      int u = tid + (r << 8);
      int l = u & 63, kt = (u >> 6) & 1, mt = u >> 7;
      const float* src = A + (size_t)(row0 + (mt << 4) + (l & 15)) * 512
                           + (ks << 6) + (kt << 5) + ((l >> 4) << 3);
      float4 f0 = *(const float4*)src, f1 = *(const float4*)(src + 4);
      u16 t8[8] = {f2bf(f0.x), f2bf(f0.y), f2bf(f0.z), f2bf(f0.w),
                   f2bf(f1.x), f2bf(f1.y), f2bf(f1.z), f2bf(f1.w)};
      *(short8*)&As[(size_t)u * 8] = *(short8*)t8;
    }
    // stage B (straight contiguous copy of pre-swizzled chunk)
    #pragma unroll
    for (int kt = 0; kt < 2; kt++){
      const u16* sb = Bw + ((size_t)((ks*2 + kt) * ntc + nt0) << 9);
      #pragma unroll
      for (int r = 0; r < 2; r++){
        int uu = tid + (r << 8);
        *(short8*)&Bs[(kt << 12) + ((size_t)uu << 3)] = *(const short8*)(sb + ((size_t)uu << 3));
      }
    }
    __syncthreads();
    #pragma unroll
    for (int kt = 0; kt < 2; kt++){
      short8 a[4], b[4];
      #pragma unroll
      for (int i = 0; i < 4; i++)
        a[i] = *(short8*)&As[(((((wm<<2)+i) << 1) + kt) * 64 + lane) << 3];
      #pragma unroll
      for (int n = 0; n < 4; n++)
        b[n] = *(short8*)&Bs[(((kt << 3) + (wn<<2) + n) * 64 + lane) << 3];
      #pragma unroll
      for (int i = 0; i < 4; i++)
        #pragma unroll
        for (int n = 0; n < 4; n++)
          acc[i][n] = __builtin_amdgcn_mfma_f32_16x16x32_bf16(a[i], b[n], acc[i][n], 0, 0, 0);
    }
    __syncthreads();
  }

  int cq = lane >> 4, cn = lane & 15;
  #pragma unroll
  for (int i = 0; i < 4; i++){
    #pragma unroll
    for (int n = 0; n < 4; n++){
      int col = col0 + (wn<<6) + (n<<4) + cn;
      float bi = bias ? bias[col] : 0.0f;
      #pragma unroll
      for (int r = 0; r < 4; r++){
        int row = row0 + (wm<<6) + (i<<4) + (cq<<2) + r;
        float c = acc[i][n][r] + bi;
        if (act == 1) c = c > 0.0f ? c : 0.2f * c;
        else if (act == 2) c = c > 0.0f ? c : expf(c) - 1.0f;
        if (resid) c += resid[(size_t)row * Nc + col];
        C[(size_t)row * Nc + col] = c;
      }
    }
  }
}

// ---------- MFMA MHA attention ----------
// Block: 256 threads = 4 waves, handles 32 q-rows of one (b,h).
// S[32][Lk] materialized fp32 in LDS; QK^T and PV via bf16 MFMA.
// Lk padded to multiple of 64 with -inf scores / zero V (exp->0 contribution).
__global__ __launch_bounds__(256) void attn_mfma(
    const float* __restrict__ q, const float* __restrict__ k, const float* __restrict__ v,
    const int* __restrict__ mask, float* __restrict__ o, int Lq, int Lk)
{
  __shared__ float S[32][SP];                   // scores, then P (fp32)
  __shared__ __align__(16) u16 Qf[4*64*8];      // Q A-fragments: ((mt*2+kt)*64+lane)*8+j
  __shared__ __align__(16) u16 KVf[8*64*8];     // K^T / V B-fragments: ((kt*4+nt)*64+lane)*8+j
  __shared__ float inv[32];

  int tid = threadIdx.x, lane = tid & 63, wave = tid >> 6;
  int wm = wave & 1, wn = wave >> 1;
  int q0 = blockIdx.x << 5, h = blockIdx.y, b = blockIdx.z;
  int ntiles = (Lk + 63) >> 6;

  // stage Q fragments (unit = wave: mt=wave>>1, kt=wave&1)
  {
    int mt = wave >> 1, kt = wave & 1;
    const float* src = q + ((size_t)(b*Lq + q0 + (mt<<4) + (lane & 15)))*512
                         + h*64 + (kt<<5) + ((lane >> 4) << 3);
    float4 f0 = *(const float4*)src, f1 = *(const float4*)(src + 4);
    u16 t8[8] = {f2bf(f0.x),f2bf(f0.y),f2bf(f0.z),f2bf(f0.w),
                 f2bf(f1.x),f2bf(f1.y),f2bf(f1.z),f2bf(f1.w)};
    *(short8*)&Qf[(size_t)tid * 8] = *(short8*)t8;
  }

  int cq = lane >> 4, cn = lane & 15;

  // ---- QK^T -> S ----
  for (int jt = 0; jt < (ntiles << 6); jt += 64){
    #pragma unroll
    for (int r = 0; r < 2; r++){
      int u = tid + (r << 8);
      int l = u & 63, unit = u >> 6;
      int kt = unit >> 2, nt = unit & 3;
      int key = jt + (nt<<4) + (l & 15);
      u16 t8[8] = {0,0,0,0,0,0,0,0};
      if (key < Lk){
        const float* src = k + ((size_t)(b*Lk + key))*512 + h*64 + (kt<<5) + ((l >> 4) << 3);
        float4 f0 = *(const float4*)src, f1 = *(const float4*)(src + 4);
        t8[0]=f2bf(f0.x); t8[1]=f2bf(f0.y); t8[2]=f2bf(f0.z); t8[3]=f2bf(f0.w);
        t8[4]=f2bf(f1.x); t8[5]=f2bf(f1.y); t8[6]=f2bf(f1.z); t8[7]=f2bf(f1.w);
      }
      *(short8*)&KVf[(size_t)u * 8] = *(short8*)t8;
    }
    __syncthreads();
    f32x4 accs[2] = {};
    #pragma unroll
    for (int kt = 0; kt < 2; kt++){
      short8 a = *(short8*)&Qf[((((wm<<1)+kt)*64 + lane)) << 3];
      #pragma unroll
      for (int ntl = 0; ntl < 2; ntl++){
        short8 bf = *(short8*)&KVf[((((kt<<2) + (wn<<1) + ntl)*64 + lane)) << 3];
        accs[ntl] = __builtin_amdgcn_mfma_f32_16x16x32_bf16(a, bf, accs[ntl], 0, 0, 0);
      }
    }
    #pragma unroll
    for (int ntl = 0; ntl < 2; ntl++){
      int j = jt + (wn<<5) + (ntl<<4) + cn;
      #pragma unroll
      for (int r = 0; r < 4; r++){
        int srow = (wm<<4) + (cq<<2) + r;
        float e;
        if (j < Lk){
          int mv = mask[((size_t)(b*Lq) + q0 + srow)*Lk + j];
          e = mv ? accs[ntl][r] * 0.125f : -1.0e9f;
        } else e = -__builtin_inff();
        S[srow][j] = e;
      }
    }
    __syncthreads();
  }

  // ---- softmax rows (8 threads per row) ----
  {
    int row = tid >> 3, part = tid & 7;
    int Lkp = ntiles << 6;
    float mx = -3.0e38f;
    for (int j = part; j < Lkp; j += 8) mx = fmaxf(mx, S[row][j]);
    #pragma unroll
    for (int m = 1; m < 8; m <<= 1) mx = fmaxf(mx, __shfl_xor(mx, m, 8));
    float sum = 0.0f;
    for (int j = part; j < Lkp; j += 8){
      float p = expf(S[row][j] - mx);
      S[row][j] = p; sum += p;
    }
    #pragma unroll
    for (int m = 1; m < 8; m <<= 1) sum += __shfl_xor(sum, m, 8);
    if (part == 0) inv[row] = 1.0f / sum;
  }
  __syncthreads();

  // ---- PV ----
  f32x4 acco[2] = {};
  for (int jt = 0; jt < (ntiles << 6); jt += 64){
    #pragma unroll
    for (int r = 0; r < 2; r++){
      int u = tid + (r << 8);
      int l = u & 63, unit = u >> 6;
      int kt = unit >> 2, nt = unit & 3;
      int d  = (nt<<4) + (l & 15);
      int kb = (l >> 4) << 3;
      u16 t8[8];
      #pragma unroll
      for (int jj = 0; jj < 8; jj++){
        int key = jt + (kt<<5) + kb + jj;
        float vv = (key < Lk) ? v[((size_t)(b*Lk + key))*512 + h*64 + d] : 0.0f;
        t8[jj] = f2bf(vv);
      }
      *(short8*)&KVf[(size_t)u * 8] = *(short8*)t8;
    }
    __syncthreads();
    #pragma unroll
    for (int kt = 0; kt < 2; kt++){
      const float* sr = &S[(wm<<4) + (lane & 15)][jt + (kt<<5) + ((lane >> 4) << 3)];
      float4 p0 = *(const float4*)sr, p1 = *(const float4*)(sr + 4);
      u16 t8[8] = {f2bf(p0.x),f2bf(p0.y),f2bf(p0.z),f2bf(p0.w),
                   f2bf(p1.x),f2bf(p1.y),f2bf(p1.z),f2bf(p1.w)};
      short8 a = *(short8*)t8;
      #pragma unroll
      for (int ntl = 0; ntl < 2; ntl++){
        short8 bf = *(short8*)&KVf[((((kt<<2) + (wn<<1) + ntl)*64 + lane)) << 3];
        acco[ntl] = __builtin_amdgcn_mfma_f32_16x16x32_bf16(a, bf, acco[ntl], 0, 0, 0);
      }
    }
    __syncthreads();
  }

  #pragma unroll
  for (int ntl = 0; ntl < 2; ntl++){
    int d = h*64 + (wn<<5) + (ntl<<4) + cn;
    #pragma unroll
    for (int r = 0; r < 4; r++){
      int srow = (wm<<4) + (cq<<2) + r;
      o[((size_t)(b*Lq + q0 + srow))*512 + d] = acco[ntl][r] * inv[srow];
    }
  }
}

// ---------- GAT scores ----------
__global__ __launch_bounds__(256) void gat1_scores(const float* __restrict__ hall,
    const float* __restrict__ gata, float* __restrict__ s1, float* __restrict__ s2)
{
  int gw = blockIdx.x * 4 + (threadIdx.x >> 6);
  int lane = threadIdx.x & 63;
  int h = gw >> 13;
  int r = gw & 8191;
  float v = hall[(size_t)r * D_ + h * 64 + lane];
  float p1 = v * gata[h * 128 + lane];
  float p2 = v * gata[h * 128 + 64 + lane];
  #pragma unroll
  for (int o = 32; o; o >>= 1){ p1 += __shfl_down(p1, o, 64); p2 += __shfl_down(p2, o, 64); }
  if (lane == 0){ s1[h * 8192 + r] = p1; s2[h * 8192 + r] = p2; }
}
__global__ __launch_bounds__(256) void gat2_scores(const float* __restrict__ h2,
    const float* __restrict__ gatoa, float* __restrict__ s1, float* __restrict__ s2)
{
  int r = blockIdx.x * 4 + (threadIdx.x >> 6);
  int lane = threadIdx.x & 63;
  float p1 = 0.0f, p2 = 0.0f;
  for (int c = lane; c < D_; c += 64){
    float v = h2[(size_t)r * D_ + c];
    p1 += v * gatoa[c];
    p2 += v * gatoa[D_ + c];
  }
  #pragma unroll
  for (int o = 32; o; o >>= 1){ p1 += __shfl_down(p1, o, 64); p2 += __shfl_down(p2, o, 64); }
  if (lane == 0){ s1[r] = p1; s2[r] = p2; }
}

// ---------- MFMA GAT layer-1 attention ----------
// Block: 256 threads, 32 q-rows of one (b,h). Scores elementwise -> S LDS; PV via MFMA; ELU epilogue.
__global__ __launch_bounds__(256) void gat1_mfma(const int* __restrict__ adj,
    const float* __restrict__ s1, const float* __restrict__ s2,
    const float* __restrict__ hall, float* __restrict__ xc)
{
  __shared__ float S[32][SP];
  __shared__ __align__(16) u16 Vf[8*64*8];
  __shared__ float inv[32];

  int tid = threadIdx.x, lane = tid & 63, wave = tid >> 6;
  int wm = wave & 1, wn = wave >> 1;
  int q0 = blockIdx.x << 5, h = blockIdx.y, b = blockIdx.z;
  int hb = h * 8192 + b * 512;

  // scores: S = adj ? leaky(s1[q]+s2[j]) : -9e15
  for (int x = tid; x < 32*128; x += 256){
    int row = x >> 7, c4 = (x & 127) << 2;
    float s1v = s1[hb + q0 + row];
    float4 s2v = *(const float4*)(s2 + hb + c4);
    const int4 m = *(const int4*)(adj + ((size_t)(b*512) + q0 + row)*512 + c4);
    float4 e; float t;
    t = s1v + s2v.x; t = t>0?t:0.2f*t; e.x = m.x>0 ? t : -9.0e15f;
    t = s1v + s2v.y; t = t>0?t:0.2f*t; e.y = m.y>0 ? t : -9.0e15f;
    t = s1v + s2v.z; t = t>0?t:0.2f*t; e.z = m.z>0 ? t : -9.0e15f;
    t = s1v + s2v.w; t = t>0?t:0.2f*t; e.w = m.w>0 ? t : -9.0e15f;
    *(float4*)&S[row][c4] = e;
  }
  __syncthreads();

  {
    int row = tid >> 3, part = tid & 7;
    float mx = -3.0e38f;
    for (int j = part; j < 512; j += 8) mx = fmaxf(mx, S[row][j]);
    #pragma unroll
    for (int m = 1; m < 8; m <<= 1) mx = fmaxf(mx, __shfl_xor(mx, m, 8));
    float sum = 0.0f;
    for (int j = part; j < 512; j += 8){
      float p = expf(S[row][j] - mx);
      S[row][j] = p; sum += p;
    }
    #pragma unroll
    for (int m = 1; m < 8; m <<= 1) sum += __shfl_xor(sum, m, 8);
    if (part == 0) inv[row] = 1.0f / sum;
  }
  __syncthreads();

  f32x4 acco[2] = {};
  for (int jt = 0; jt < 512; jt += 64){
    #pragma unroll
    for (int r = 0; r < 2; r++){
      int u = tid + (r << 8);
      int l = u & 63, unit = u >> 6;
      int kt = unit >> 2, nt = unit & 3;
      int d  = (nt<<4) + (l & 15);
      int kb = (l >> 4) << 3;
      const float* src = hall + ((size_t)(b*512 + jt + (kt<<5) + kb))*512 + h*64 + d;
      u16 t8[8];
      #pragma unroll
      for (int jj = 0; jj < 8; jj++) t8[jj] = f2bf(src[(size_t)jj * 512]);
      *(short8*)&Vf[(size_t)u * 8] = *(short8*)t8;
    }
    __syncthreads();
    #pragma unroll
    for (int kt = 0; kt < 2; kt++){
      const float* sr = &S[(wm<<4) + (lane & 15)][jt + (kt<<5) + ((lane >> 4) << 3)];
      float4 p0 = *(const float4*)sr, p1 = *(const float4*)(sr + 4);
      u16 t8[8] = {f2bf(p0.x),f2bf(p0.y),f2bf(p0.z),f2bf(p0.w),
                   f2bf(p1.x),f2bf(p1.y),f2bf(p1.z),f2bf(p1.w)};
      short8 a = *(short8*)t8;
      #pragma unroll
      for (int ntl = 0; ntl < 2; ntl++){
        short8 bf = *(short8*)&Vf[((((kt<<2) + (wn<<1) + ntl)*64 + lane)) << 3];
        acco[ntl] = __builtin_amdgcn_mfma_f32_16x16x32_bf16(a, bf, acco[ntl], 0, 0, 0);
      }
    }
    __syncthreads();
  }

  int cq = lane >> 4, cn = lane & 15;
  #pragma unroll
  for (int ntl = 0; ntl < 2; ntl++){
    int d = h*64 + (wn<<5) + (ntl<<4) + cn;
    #pragma unroll
    for (int r = 0; r < 4; r++){
      int srow = (wm<<4) + (cq<<2) + r;
      float val = acco[ntl][r] * inv[srow];
      val = val > 0.0f ? val : expf(val) - 1.0f;
      xc[((size_t)(b*512 + q0 + srow))*512 + d] = val;
    }
  }
}

// ---------- GAT output-layer probabilities ----------
__global__ __launch_bounds__(256) void gat2_prob(const int* __restrict__ adj,
    const float* __restrict__ s1, const float* __restrict__ s2, float* __restrict__ P)
{
  __shared__ float red[4];
  int r = blockIdx.x, tid = threadIdx.x;
  int b = r >> 9;
  float s1v = s1[r];
  float e0, e1;
  {
    float t = s1v + s2[b*512 + tid];       t = t>0?t:0.2f*t;
    e0 = adj[(size_t)r*512 + tid]       > 0 ? t : -9.0e15f;
    t = s1v + s2[b*512 + tid + 256];       t = t>0?t:0.2f*t;
    e1 = adj[(size_t)r*512 + tid + 256] > 0 ? t : -9.0e15f;
  }
  float mx = block_max(fmaxf(e0, e1), red);
  float p0 = expf(e0 - mx), p1 = expf(e1 - mx);
  float s = block_sum(p0 + p1, red);
  float inv = 1.0f / s;
  P[(size_t)r*512 + tid]       = p0 * inv;
  P[(size_t)r*512 + tid + 256] = p1 * inv;
}

// ---------- LayerNorm ----------
__global__ __launch_bounds__(256) void ln_k(const float* __restrict__ in,
    const float* __restrict__ g, const float* __restrict__ bta, float* __restrict__ out)
{
  __shared__ float red[4];
  int r = blockIdx.x, tid = threadIdx.x;
  const float* x = in + (size_t)r * D_;
  float v0 = x[tid], v1 = x[tid + 256];
  float mu = block_sum(v0 + v1, red) * (1.0f / 512.0f);
  float d0 = v0 - mu, d1 = v1 - mu;
  float var = block_sum(d0 * d0 + d1 * d1, red) * (1.0f / 512.0f);
  float inv = 1.0f / sqrtf(var + 1e-6f);
  out[(size_t)r * D_ + tid]       = d0 * inv * g[tid]       + bta[tid];
  out[(size_t)r * D_ + tid + 256] = d1 * inv * g[tid + 256] + bta[tid + 256];
}

// ---------- host-side MHA helper (MFMA projections; w = swizzled bf16 base, 4 DD mats) ----------
static void run_mha(hipStream_t st, const float* q_in, int Lq, const float* kv_in, int Lk,
                    const int* mask, const u16* w, const float* g, const float* bt,
                    float* qb, float* kb, float* vb, float* ob, float* tmp, float* out)
{
  dim3 blk(256);
  gemm_mfma<<<dim3(D_/128, (B_*Lq)/128), blk, 0, st>>>(q_in,  w + (size_t)0*DD, nullptr, nullptr, qb, D_, 0, 0,0,0,0);
  gemm_mfma<<<dim3(D_/128, (B_*Lk)/128), blk, 0, st>>>(kv_in, w + (size_t)1*DD, nullptr, nullptr, kb, D_, 0, 0,0,0,0);
  gemm_mfma<<<dim3(D_/128, (B_*Lk)/128), blk, 0, st>>>(kv_in, w + (size_t)2*DD, nullptr, nullptr, vb, D_, 0, 0,0,0,0);
  attn_mfma<<<dim3(Lq/32, NH_, B_), blk, 0, st>>>(qb, kb, vb, mask, ob, Lq, Lk);
  gemm_mfma<<<dim3(D_/128, (B_*Lq)/128), blk, 0, st>>>(ob, w + (size_t)3*DD, nullptr, q_in, tmp, D_, 0, 0,0,0,0);
  ln_k<<<dim3(B_*Lq), blk, 0, st>>>(tmp, g, bt, out);
}

extern "C" void kernel_launch(void* const* d_in, const int* in_sizes, int n_in,
                              void* d_out, int out_size, void* d_ws, size_t ws_size,
                              hipStream_t stream) {
  (void)in_sizes; (void)n_in; (void)out_size; (void)ws_size;

  const float* xf    = (const float*)d_in[0];
  const int* adj_i   = (const int*)d_in[2];
  const int* adj_s   = (const int*)d_in[3];
  const int* adj_is  = (const int*)d_in[4];
  const int* adj_si  = (const int*)d_in[5];
  const float* intent= (const float*)d_in[6];
  const float* gatW  = (const float*)d_in[7];
  const float* gata  = (const float*)d_in[8];
  const float* gatoW = (const float*)d_in[9];
  const float* gatoa = (const float*)d_in[10];
  const float* mhaw  = (const float*)d_in[11];
  const float* lng   = (const float*)d_in[12];
  const float* lnb   = (const float*)d_in[13];
  const float* linW1 = (const float*)d_in[14];
  const float* linb1 = (const float*)d_in[15];
  const float* linW2 = (const float*)d_in[16];
  const float* linb2 = (const float*)d_in[17];

  float* out0 = (float*)d_out;                   // slot_out      [B,N,D]
  float* out1 = out0 + BND;                      // slot_logits   [B,N,OUT]
  float* out2 = out1 + (size_t)B_*N_*OUT_;       // slot_graph_out[B,N,D]

  // ---- workspace carve (~129 MB) ----
  float* Q    = (float*)d_ws;      // BND x6
  float* K    = Q   + BND;
  float* V    = K   + BND;
  float* O    = V   + BND;
  float* TMP  = O   + BND;
  float* HB1  = TMP + BND;
  float* ha0  = HB1 + BND;         // BID x9
  float* ha1  = ha0 + BID;
  float* ta   = ha1 + BID;
  float* tb   = ta  + BID;
  float* sqa  = tb  + BID;
  float* ska  = sqa + BID;
  float* sva  = ska + BID;
  float* soa  = sva + BID;
  float* stmp = soa + BID;
  float* s1   = stmp+ BID;         // 65536 x2
  float* s2   = s1  + 65536;
  float* s1o  = s2  + 65536;       // 8192 x2
  float* s2o  = s1o + 8192;
  u16* Wm  = (u16*)(s2o + 8192);   // 32*DD bf16 (all mhaw mats, swizzled)
  u16* Wg  = Wm  + (size_t)32*DD;  // gat Wcat swizzled
  u16* Wgo = Wg  + DD;             // gat_out_W swizzled
  u16* W1s = Wgo + DD;             // lin_W1 swizzled
  u16* W2s = W1s + DD;             // lin_W2 swizzled (512x128 -> DD/4)

  dim3 blk(256);

  // ---- weight prep (swizzle to MFMA B-fragment order) ----
  swz_k<<<dim3(128, 32), blk, 0, stream>>>(mhaw,  Wm,  D_,   DD, DD);
  swz_gatW_k<<<128, blk, 0, stream>>>(gatW, Wg);
  swz_k<<<dim3(128, 1), blk, 0, stream>>>(gatoW, Wgo, D_,   0, 0);
  swz_k<<<dim3(128, 1), blk, 0, stream>>>(linW1, W1s, D_,   0, 0);
  swz_k<<<dim3(32,  1), blk, 0, stream>>>(linW2, W2s, OUT_, 0, 0);

  // ================= MHA stack =================
  bcast_k<<<BID/256, blk, 0, stream>>>(intent, ha0, BID);

  // ---- layer 0 (h_b = xf, h_a = ha0) ----
  run_mha(stream, ha0, NI_, ha0, NI_, adj_i,  Wm +  (size_t)0*DD, lng + 0*D_, lnb + 0*D_,
          sqa, ska, sva, soa, stmp, ta);                                   // a2a -> ta
  run_mha(stream, ha0, NI_, xf,  N_,  adj_si, Wm + (size_t)12*DD, lng + 3*D_, lnb + 3*D_,
          sqa, K, V, soa, stmp, tb);                                       // b2a -> tb
  add_relu_k<<<BID/256, blk, 0, stream>>>(ta, tb, ha1, BID);               // h_a1
  run_mha(stream, xf, N_, xf, N_, adj_s,  Wm +  (size_t)4*DD, lng + 1*D_, lnb + 1*D_,
          Q, K, V, O, TMP, HB1);                                           // b2b -> HB1
  run_mha(stream, xf, N_, ha0, NI_, adj_is, Wm + (size_t)8*DD, lng + 2*D_, lnb + 2*D_,
          Q, ska, sva, O, TMP, Q);                                         // a2b -> Q
  add_relu_ip_k<<<BND/256, blk, 0, stream>>>(HB1, Q, BND);                 // h_b1

  // ---- layer 1 (h_b = HB1, h_a = ha1); a2a/b2a dead ----
  run_mha(stream, HB1, N_, HB1, N_, adj_s,  Wm + (size_t)20*DD, lng + 5*D_, lnb + 5*D_,
          Q, K, V, O, TMP, K);                                             // b2b -> K
  run_mha(stream, HB1, N_, ha1, NI_, adj_is, Wm + (size_t)24*DD, lng + 6*D_, lnb + 6*D_,
          Q, ska, sva, O, TMP, Q);                                         // a2b -> Q
  add_relu_ip_k<<<BND/256, blk, 0, stream>>>(K, Q, BND);                   // h_b2 in K

  // ---- slot_out = x + h_b2 ----
  add_k<<<BND/256, blk, 0, stream>>>(xf, K, out0, BND);
  // ---- logits ----
  gemm_mfma<<<dim3(D_/128, (B_*N_)/128), blk, 0, stream>>>(out0, W1s, linb1, nullptr, Q, D_, 1, 0,0,0,0);
  gemm_mfma<<<dim3(OUT_/128, (B_*N_)/128), blk, 0, stream>>>(Q, W2s, linb2, nullptr, out1, OUT_, 0, 0,0,0,0);

  // ================= GAT branch =================
  gemm_mfma<<<dim3(D_/128, (B_*N_)/128), blk, 0, stream>>>(xf, Wg, nullptr, nullptr, Q /*h_all*/, D_, 0, 0,0,0,0);
  gat1_scores<<<(H_*B_*N_)/4, blk, 0, stream>>>(Q, gata, s1, s2);
  gat1_mfma<<<dim3(N_/32, H_, B_), blk, 0, stream>>>(adj_s, s1, s2, Q, K /*xc*/);
  gemm_mfma<<<dim3(D_/128, (B_*N_)/128), blk, 0, stream>>>(K, Wgo, nullptr, nullptr, V /*h2*/, D_, 0, 0,0,0,0);
  gat2_scores<<<(B_*N_)/4, blk, 0, stream>>>(V, gatoa, s1o, s2o);
  gat2_prob<<<B_*N_, blk, 0, stream>>>(adj_s, s1o, s2o, HB1 /*P*/);
  // out2 = elu(P @ h2) + x : swizzle runtime h2 per batch into free O buffer, then batched MFMA GEMM
  swz_k<<<dim3(128, B_), blk, 0, stream>>>(V, (u16*)O, D_, (size_t)N_*D_, (size_t)DD);
  gemm_mfma<<<dim3(D_/128, N_/128, B_), blk, 0, stream>>>(HB1, (u16*)O, nullptr, xf, out2, D_, 2,
      (size_t)N_*N_, (size_t)DD, (size_t)N_*D_, (size_t)N_*D_);
}

// Round 2
// 1388.262 us; speedup vs baseline: 1.0670x; 1.0670x over previous
//
#include <hip/hip_runtime.h>

// B=16, N=512, D=512, NI=32, GH=64, H=8, L=2, OUT=128, heads=8
#define B_   16
#define N_   512
#define D_   512
#define NI_  32
#define GH_  64
#define H_   8
#define OUT_ 128
#define NH_  8

#define BND   (B_*N_*D_)     // 4194304
#define BID   (B_*NI_*D_)    // 262144
#define DD    (D_*D_)        // 262144

#define SPS 528              // S row stride in bf16 (528*2B=1056B=264dw; 264%32=8 -> 4 rows cover all banks)

typedef unsigned short u16;
typedef unsigned int   u32;
typedef __attribute__((ext_vector_type(8))) short short8;
typedef __attribute__((ext_vector_type(4))) short short4v;
typedef __attribute__((ext_vector_type(4))) float f32x4;

__device__ __forceinline__ u16 f2bf(float f){
  u32 x = __float_as_uint(f);
  x += 0x7fffu + ((x >> 16) & 1u);   // RNE
  return (u16)(x >> 16);
}
__device__ __forceinline__ float bf2f(u16 s){
  return __uint_as_float((u32)s << 16);
}

// blockDim must be 256
__device__ __forceinline__ float block_sum(float v, float* sm){
  #pragma unroll
  for (int o = 32; o; o >>= 1) v += __shfl_down(v, o, 64);
  int lane = threadIdx.x & 63, w = threadIdx.x >> 6;
  __syncthreads();
  if (lane == 0) sm[w] = v;
  __syncthreads();
  return sm[0] + sm[1] + sm[2] + sm[3];
}
__device__ __forceinline__ float block_max(float v, float* sm){
  #pragma unroll
  for (int o = 32; o; o >>= 1) v = fmaxf(v, __shfl_down(v, o, 64));
  int lane = threadIdx.x & 63, w = threadIdx.x >> 6;
  __syncthreads();
  if (lane == 0) sm[w] = v;
  __syncthreads();
  return fmaxf(fmaxf(sm[0], sm[1]), fmaxf(sm[2], sm[3]));
}

// ---------- mask bit-pack (adj>0 -> 1 bit) ----------
__global__ __launch_bounds__(256) void pack_mask_k(const int* __restrict__ adj, u32* __restrict__ bits){
  int i = blockIdx.x * 256 + threadIdx.x;
  unsigned long long m = __ballot(adj[i] > 0);
  if ((threadIdx.x & 63) == 0){
    bits[(i >> 5)]     = (u32)m;
    bits[(i >> 5) + 1] = (u32)(m >> 32);
  }
}

// ---------- elementwise ----------
__global__ __launch_bounds__(256) void bcast_k(const float* __restrict__ s, float* __restrict__ d, int n){
  int i = blockIdx.x * 256 + threadIdx.x;
  if (i < n) d[i] = s[i & (NI_*D_ - 1)];
}
__global__ __launch_bounds__(256) void add_relu_k(const float* __restrict__ a, const float* __restrict__ b,
                                                  float* __restrict__ o, int n){
  int i = blockIdx.x * 256 + threadIdx.x;
  if (i < n){ float v = a[i] + b[i]; o[i] = v > 0.0f ? v : 0.0f; }
}
__global__ __launch_bounds__(256) void add_relu_ip_k(float* __restrict__ a, const float* __restrict__ b, int n){
  int i = blockIdx.x * 256 + threadIdx.x;
  if (i < n){ float v = a[i] + b[i]; a[i] = v > 0.0f ? v : 0.0f; }
}
__global__ __launch_bounds__(256) void add_k(const float* __restrict__ a, const float* __restrict__ b,
                                             float* __restrict__ o, int n){
  int i = blockIdx.x * 256 + threadIdx.x;
  if (i < n) o[i] = a[i] + b[i];
}

// ---------- weight swizzle into MFMA B-fragment order ----------
// Bsw unit (s, nt, lane): holds W[k = s*32 + (lane>>4)*8 + j][n = nt*16 + (lane&15)], j=0..7
// offset = ((s*(Nc/16) + nt)*64 + lane)*8 + j
__global__ __launch_bounds__(256) void swz_k(const float* __restrict__ W, u16* __restrict__ o,
                                             int Nc, size_t sW, size_t sO){
  int gw = blockIdx.x * 4 + (threadIdx.x >> 6);
  int lane = threadIdx.x & 63;
  int ntc = Nc >> 4;
  int s = gw / ntc, nt = gw - s * ntc;
  const float* Wb = W + sW * blockIdx.y;
  u16* ob = o + sO * blockIdx.y;
  int n = nt*16 + (lane & 15);
  int kb = s*32 + ((lane >> 4) << 3);
  u16 t8[8];
  #pragma unroll
  for (int j = 0; j < 8; j++) t8[j] = f2bf(Wb[(size_t)(kb + j) * Nc + n]);
  *(short8*)&ob[((size_t)(s * ntc + nt) * 64 + lane) * 8] = *(short8*)t8;
}
// gat_W [H,D,GH] -> head-major-concat [D,512], swizzled
__global__ __launch_bounds__(256) void swz_gatW_k(const float* __restrict__ gw_, u16* __restrict__ o){
  int gw = blockIdx.x * 4 + (threadIdx.x >> 6);  // 512 waves
  int lane = threadIdx.x & 63;
  int s = gw >> 5, nt = gw & 31;
  int n = nt*16 + (lane & 15);
  int h = n >> 6, f = n & 63;
  int kb = s*32 + ((lane >> 4) << 3);
  u16 t8[8];
  #pragma unroll
  for (int j = 0; j < 8; j++) t8[j] = f2bf(gw_[((size_t)(h*512) + kb + j) * 64 + f]);
  *(short8*)&o[((size_t)(s*32 + nt) * 64 + lane) * 8] = *(short8*)t8;
}

// ---------- MFMA GEMM: C[M,Nc](f32) = act(A[M,512](f32->bf16) @ Bsw + bias) + resid ----------
// 128x128 tile, 4 waves, each wave 64x64 (4x4 of 16x16). K = 512 fixed.
// act: 0 none, 1 leaky, 2 elu. Batched over blockIdx.z via strides.
__global__ __launch_bounds__(256) void gemm_mfma(
    const float* __restrict__ A, const u16* __restrict__ Bw,
    const float* __restrict__ bias, const float* __restrict__ resid,
    float* __restrict__ C, int Nc, int act,
    size_t sA, size_t sB, size_t sC, size_t sR)
{
  __shared__ __align__(16) u16 As[128*64];   // frag order: ((mt*2+kt)*64 + lane)*8 + j
  __shared__ __align__(16) u16 Bs[64*128];   // frag order: ((kt*8 + nt)*64 + lane)*8 + j
  A  += sA * blockIdx.z;
  Bw += sB * blockIdx.z;
  C  += sC * blockIdx.z;
  if (resid) resid += sR * blockIdx.z;

  int tid = threadIdx.x, lane = tid & 63, wave = tid >> 6;
  int wm = wave & 1, wn = wave >> 1;
  int row0 = blockIdx.y << 7, col0 = blockIdx.x << 7;
  int ntc = Nc >> 4, nt0 = col0 >> 4;

  f32x4 acc[4][4] = {};

  for (int ks = 0; ks < 8; ks++){
    // stage A (fp32 -> bf16, fragment order)
    #pragma unroll
    for (int r = 0; r < 4; r++){
      int u = tid + (r << 8);
      int l = u & 63, kt = (u >> 6) & 1, mt = u >> 7;
      const float* src = A + (size_t)(row0 + (mt << 4) + (l & 15)) * 512
                           + (ks << 6) + (kt << 5) + ((l >> 4) << 3);
      float4 f0 = *(const float4*)src, f1 = *(const float4*)(src + 4);
      u16 t8[8] = {f2bf(f0.x), f2bf(f0.y), f2bf(f0.z), f2bf(f0.w),
                   f2bf(f1.x), f2bf(f1.y), f2bf(f1.z), f2bf(f1.w)};
      *(short8*)&As[(size_t)u * 8] = *(short8*)t8;
    }
    // stage B (straight contiguous copy of pre-swizzled chunk)
    #pragma unroll
    for (int kt = 0; kt < 2; kt++){
      const u16* sb = Bw + ((size_t)((ks*2 + kt) * ntc + nt0) << 9);
      #pragma unroll
      for (int r = 0; r < 2; r++){
        int uu = tid + (r << 8);
        *(short8*)&Bs[(kt << 12) + ((size_t)uu << 3)] = *(const short8*)(sb + ((size_t)uu << 3));
      }
    }
    __syncthreads();
    #pragma unroll
    for (int kt = 0; kt < 2; kt++){
      short8 a[4], b[4];
      #pragma unroll
      for (int i = 0; i < 4; i++)
        a[i] = *(short8*)&As[(((((wm<<2)+i) << 1) + kt) * 64 + lane) << 3];
      #pragma unroll
      for (int n = 0; n < 4; n++)
        b[n] = *(short8*)&Bs[(((kt << 3) + (wn<<2) + n) * 64 + lane) << 3];
      #pragma unroll
      for (int i = 0; i < 4; i++)
        #pragma unroll
        for (int n = 0; n < 4; n++)
          acc[i][n] = __builtin_amdgcn_mfma_f32_16x16x32_bf16(a[i], b[n], acc[i][n], 0, 0, 0);
    }
    __syncthreads();
  }

  int cq = lane >> 4, cn = lane & 15;
  #pragma unroll
  for (int i = 0; i < 4; i++){
    #pragma unroll
    for (int n = 0; n < 4; n++){
      int col = col0 + (wn<<6) + (n<<4) + cn;
      float bi = bias ? bias[col] : 0.0f;
      #pragma unroll
      for (int r = 0; r < 4; r++){
        int row = row0 + (wm<<6) + (i<<4) + (cq<<2) + r;
        float c = acc[i][n][r] + bi;
        if (act == 1) c = c > 0.0f ? c : 0.2f * c;
        else if (act == 2) c = c > 0.0f ? c : expf(c) - 1.0f;
        if (resid) c += resid[(size_t)row * Nc + col];
        C[(size_t)row * Nc + col] = c;
      }
    }
  }
}

// ---------- MFMA MHA attention (bit-packed mask, bf16 S) ----------
// Block: 256 threads = 4 waves, 32 q-rows of one (b,h).
// S[32][Lk] bf16 in LDS; QK^T and PV via bf16 MFMA.
// Lk padded to multiple of 64 with -inf scores / zero V.
__global__ __launch_bounds__(256) void attn_mfma(
    const float* __restrict__ q, const float* __restrict__ k, const float* __restrict__ v,
    const u32* __restrict__ mbits, float* __restrict__ o, int Lq, int Lk)
{
  __shared__ __align__(16) u16 S[32][SPS];      // scores, then P (bf16)
  __shared__ __align__(16) u16 Qf[4*64*8];      // Q A-fragments: ((mt*2+kt)*64+lane)*8+j
  __shared__ __align__(16) u16 KVf[8*64*8];     // K^T / V B-fragments: ((kt*4+nt)*64+lane)*8+j
  __shared__ float inv[32];

  int tid = threadIdx.x, lane = tid & 63, wave = tid >> 6;
  int wm = wave & 1, wn = wave >> 1;
  int q0 = blockIdx.x << 5, h = blockIdx.y, b = blockIdx.z;
  int ntiles = (Lk + 63) >> 6;

  // stage Q fragments (unit = wave: mt=wave>>1, kt=wave&1)
  {
    int mt = wave >> 1, kt = wave & 1;
    const float* src = q + ((size_t)(b*Lq + q0 + (mt<<4) + (lane & 15)))*512
                         + h*64 + (kt<<5) + ((lane >> 4) << 3);
    float4 f0 = *(const float4*)src, f1 = *(const float4*)(src + 4);
    u16 t8[8] = {f2bf(f0.x),f2bf(f0.y),f2bf(f0.z),f2bf(f0.w),
                 f2bf(f1.x),f2bf(f1.y),f2bf(f1.z),f2bf(f1.w)};
    *(short8*)&Qf[(size_t)tid * 8] = *(short8*)t8;
  }

  int cq = lane >> 4, cn = lane & 15;

  // ---- QK^T -> S ----
  for (int jt = 0; jt < (ntiles << 6); jt += 64){
    #pragma unroll
    for (int r = 0; r < 2; r++){
      int u = tid + (r << 8);
      int l = u & 63, unit = u >> 6;
      int kt = unit >> 2, nt = unit & 3;
      int key = jt + (nt<<4) + (l & 15);
      u16 t8[8] = {0,0,0,0,0,0,0,0};
      if (key < Lk){
        const float* src = k + ((size_t)(b*Lk + key))*512 + h*64 + (kt<<5) + ((l >> 4) << 3);
        float4 f0 = *(const float4*)src, f1 = *(const float4*)(src + 4);
        t8[0]=f2bf(f0.x); t8[1]=f2bf(f0.y); t8[2]=f2bf(f0.z); t8[3]=f2bf(f0.w);
        t8[4]=f2bf(f1.x); t8[5]=f2bf(f1.y); t8[6]=f2bf(f1.z); t8[7]=f2bf(f1.w);
      }
      *(short8*)&KVf[(size_t)u * 8] = *(short8*)t8;
    }
    __syncthreads();
    f32x4 accs[2] = {};
    #pragma unroll
    for (int kt = 0; kt < 2; kt++){
      short8 a = *(short8*)&Qf[((((wm<<1)+kt)*64 + lane)) << 3];
      #pragma unroll
      for (int ntl = 0; ntl < 2; ntl++){
        short8 bf = *(short8*)&KVf[((((kt<<2) + (wn<<1) + ntl)*64 + lane)) << 3];
        accs[ntl] = __builtin_amdgcn_mfma_f32_16x16x32_bf16(a, bf, accs[ntl], 0, 0, 0);
      }
    }
    #pragma unroll
    for (int ntl = 0; ntl < 2; ntl++){
      int j = jt + (wn<<5) + (ntl<<4) + cn;
      #pragma unroll
      for (int r = 0; r < 4; r++){
        int srow = (wm<<4) + (cq<<2) + r;
        float e;
        if (j < Lk){
          size_t bi = ((size_t)(b*Lq) + q0 + srow)*Lk + j;
          u32 w = mbits[bi >> 5];
          e = ((w >> (bi & 31)) & 1u) ? accs[ntl][r] * 0.125f : -1.0e9f;
        } else e = -__builtin_inff();
        S[srow][j] = f2bf(e);
      }
    }
    __syncthreads();
  }

  // ---- softmax rows (8 threads per row) ----
  {
    int row = tid >> 3, part = tid & 7;
    int Lkp = ntiles << 6;
    float mx = -3.0e38f;
    for (int j = part; j < Lkp; j += 8) mx = fmaxf(mx, bf2f(S[row][j]));
    #pragma unroll
    for (int m = 1; m < 8; m <<= 1) mx = fmaxf(mx, __shfl_xor(mx, m, 8));
    float sum = 0.0f;
    for (int j = part; j < Lkp; j += 8){
      float p = expf(bf2f(S[row][j]) - mx);
      u16 pb = f2bf(p);
      S[row][j] = pb; sum += bf2f(pb);
    }
    #pragma unroll
    for (int m = 1; m < 8; m <<= 1) sum += __shfl_xor(sum, m, 8);
    if (part == 0) inv[row] = 1.0f / sum;
  }
  __syncthreads();

  // ---- PV ----
  f32x4 acco[2] = {};
  for (int jt = 0; jt < (ntiles << 6); jt += 64){
    #pragma unroll
    for (int r = 0; r < 2; r++){
      int u = tid + (r << 8);
      int l = u & 63, unit = u >> 6;
      int kt = unit >> 2, nt = unit & 3;
      int d  = (nt<<4) + (l & 15);
      int kb = (l >> 4) << 3;
      u16 t8[8];
      #pragma unroll
      for (int jj = 0; jj < 8; jj++){
        int key = jt + (kt<<5) + kb + jj;
        float vv = (key < Lk) ? v[((size_t)(b*Lk + key))*512 + h*64 + d] : 0.0f;
        t8[jj] = f2bf(vv);
      }
      *(short8*)&KVf[(size_t)u * 8] = *(short8*)t8;
    }
    __syncthreads();
    #pragma unroll
    for (int kt = 0; kt < 2; kt++){
      short8 a = *(short8*)&S[(wm<<4) + (lane & 15)][jt + (kt<<5) + ((lane >> 4) << 3)];
      #pragma unroll
      for (int ntl = 0; ntl < 2; ntl++){
        short8 bf = *(short8*)&KVf[((((kt<<2) + (wn<<1) + ntl)*64 + lane)) << 3];
        acco[ntl] = __builtin_amdgcn_mfma_f32_16x16x32_bf16(a, bf, acco[ntl], 0, 0, 0);
      }
    }
    __syncthreads();
  }

  #pragma unroll
  for (int ntl = 0; ntl < 2; ntl++){
    int d = h*64 + (wn<<5) + (ntl<<4) + cn;
    #pragma unroll
    for (int r = 0; r < 4; r++){
      int srow = (wm<<4) + (cq<<2) + r;
      o[((size_t)(b*Lq + q0 + srow))*512 + d] = acco[ntl][r] * inv[srow];
    }
  }
}

// ---------- GAT scores ----------
__global__ __launch_bounds__(256) void gat1_scores(const float* __restrict__ hall,
    const float* __restrict__ gata, float* __restrict__ s1, float* __restrict__ s2)
{
  int gw = blockIdx.x * 4 + (threadIdx.x >> 6);
  int lane = threadIdx.x & 63;
  int h = gw >> 13;
  int r = gw & 8191;
  float v = hall[(size_t)r * D_ + h * 64 + lane];
  float p1 = v * gata[h * 128 + lane];
  float p2 = v * gata[h * 128 + 64 + lane];
  #pragma unroll
  for (int o = 32; o; o >>= 1){ p1 += __shfl_down(p1, o, 64); p2 += __shfl_down(p2, o, 64); }
  if (lane == 0){ s1[h * 8192 + r] = p1; s2[h * 8192 + r] = p2; }
}
__global__ __launch_bounds__(256) void gat2_scores(const float* __restrict__ h2,
    const float* __restrict__ gatoa, float* __restrict__ s1, float* __restrict__ s2)
{
  int r = blockIdx.x * 4 + (threadIdx.x >> 6);
  int lane = threadIdx.x & 63;
  float p1 = 0.0f, p2 = 0.0f;
  for (int c = lane; c < D_; c += 64){
    float v = h2[(size_t)r * D_ + c];
    p1 += v * gatoa[c];
    p2 += v * gatoa[D_ + c];
  }
  #pragma unroll
  for (int o = 32; o; o >>= 1){ p1 += __shfl_down(p1, o, 64); p2 += __shfl_down(p2, o, 64); }
  if (lane == 0){ s1[r] = p1; s2[r] = p2; }
}

// ---------- MFMA GAT layer-1 attention (bit-packed mask, bf16 S) ----------
__global__ __launch_bounds__(256) void gat1_mfma(const u32* __restrict__ mbits,
    const float* __restrict__ s1, const float* __restrict__ s2,
    const float* __restrict__ hall, float* __restrict__ xc)
{
  __shared__ __align__(16) u16 S[32][SPS];
  __shared__ __align__(16) u16 Vf[8*64*8];
  __shared__ float inv[32];

  int tid = threadIdx.x, lane = tid & 63, wave = tid >> 6;
  int wm = wave & 1, wn = wave >> 1;
  int q0 = blockIdx.x << 5, h = blockIdx.y, b = blockIdx.z;
  int hb = h * 8192 + b * 512;

  // scores: S = adj ? leaky(s1[q]+s2[j]) : -9e15
  for (int x = tid; x < 32*128; x += 256){
    int row = x >> 7, c4 = (x & 127) << 2;
    float s1v = s1[hb + q0 + row];
    float4 s2v = *(const float4*)(s2 + hb + c4);
    size_t bi = ((size_t)(b*512) + q0 + row)*512 + c4;
    u32 w = mbits[bi >> 5] >> (bi & 31);
    float t; u16 q4[4];
    t = s1v + s2v.x; t = t>0?t:0.2f*t; q4[0] = f2bf((w     & 1u) ? t : -9.0e15f);
    t = s1v + s2v.y; t = t>0?t:0.2f*t; q4[1] = f2bf(((w>>1) & 1u) ? t : -9.0e15f);
    t = s1v + s2v.z; t = t>0?t:0.2f*t; q4[2] = f2bf(((w>>2) & 1u) ? t : -9.0e15f);
    t = s1v + s2v.w; t = t>0?t:0.2f*t; q4[3] = f2bf(((w>>3) & 1u) ? t : -9.0e15f);
    *(short4v*)&S[row][c4] = *(short4v*)q4;
  }
  __syncthreads();

  {
    int row = tid >> 3, part = tid & 7;
    float mx = -3.0e38f;
    for (int j = part; j < 512; j += 8) mx = fmaxf(mx, bf2f(S[row][j]));
    #pragma unroll
    for (int m = 1; m < 8; m <<= 1) mx = fmaxf(mx, __shfl_xor(mx, m, 8));
    float sum = 0.0f;
    for (int j = part; j < 512; j += 8){
      float p = expf(bf2f(S[row][j]) - mx);
      u16 pb = f2bf(p);
      S[row][j] = pb; sum += bf2f(pb);
    }
    #pragma unroll
    for (int m = 1; m < 8; m <<= 1) sum += __shfl_xor(sum, m, 8);
    if (part == 0) inv[row] = 1.0f / sum;
  }
  __syncthreads();

  f32x4 acco[2] = {};
  for (int jt = 0; jt < 512; jt += 64){
    #pragma unroll
    for (int r = 0; r < 2; r++){
      int u = tid + (r << 8);
      int l = u & 63, unit = u >> 6;
      int kt = unit >> 2, nt = unit & 3;
      int d  = (nt<<4) + (l & 15);
      int kb = (l >> 4) << 3;
      const float* src = hall + ((size_t)(b*512 + jt + (kt<<5) + kb))*512 + h*64 + d;
      u16 t8[8];
      #pragma unroll
      for (int jj = 0; jj < 8; jj++) t8[jj] = f2bf(src[(size_t)jj * 512]);
      *(short8*)&Vf[(size_t)u * 8] = *(short8*)t8;
    }
    __syncthreads();
    #pragma unroll
    for (int kt = 0; kt < 2; kt++){
      short8 a = *(short8*)&S[(wm<<4) + (lane & 15)][jt + (kt<<5) + ((lane >> 4) << 3)];
      #pragma unroll
      for (int ntl = 0; ntl < 2; ntl++){
        short8 bf = *(short8*)&Vf[((((kt<<2) + (wn<<1) + ntl)*64 + lane)) << 3];
        acco[ntl] = __builtin_amdgcn_mfma_f32_16x16x32_bf16(a, bf, acco[ntl], 0, 0, 0);
      }
    }
    __syncthreads();
  }

  int cq = lane >> 4, cn = lane & 15;
  #pragma unroll
  for (int ntl = 0; ntl < 2; ntl++){
    int d = h*64 + (wn<<5) + (ntl<<4) + cn;
    #pragma unroll
    for (int r = 0; r < 4; r++){
      int srow = (wm<<4) + (cq<<2) + r;
      float val = acco[ntl][r] * inv[srow];
      val = val > 0.0f ? val : expf(val) - 1.0f;
      xc[((size_t)(b*512 + q0 + srow))*512 + d] = val;
    }
  }
}

// ---------- GAT output-layer probabilities (bit-packed mask) ----------
__global__ __launch_bounds__(256) void gat2_prob(const u32* __restrict__ mbits,
    const float* __restrict__ s1, const float* __restrict__ s2, float* __restrict__ P)
{
  __shared__ float red[4];
  int r = blockIdx.x, tid = threadIdx.x;
  int b = r >> 9;
  float s1v = s1[r];
  float e0, e1;
  {
    size_t base = (size_t)r * 512;
    u32 w0 = mbits[(base + tid) >> 5];
    u32 w1 = mbits[(base + tid + 256) >> 5];
    float t = s1v + s2[b*512 + tid];       t = t>0?t:0.2f*t;
    e0 = ((w0 >> (tid & 31)) & 1u) ? t : -9.0e15f;
    t = s1v + s2[b*512 + tid + 256];       t = t>0?t:0.2f*t;
    e1 = ((w1 >> (tid & 31)) & 1u) ? t : -9.0e15f;
  }
  float mx = block_max(fmaxf(e0, e1), red);
  float p0 = expf(e0 - mx), p1 = expf(e1 - mx);
  float s = block_sum(p0 + p1, red);
  float inv = 1.0f / s;
  P[(size_t)r*512 + tid]       = p0 * inv;
  P[(size_t)r*512 + tid + 256] = p1 * inv;
}

// ---------- LayerNorm ----------
__global__ __launch_bounds__(256) void ln_k(const float* __restrict__ in,
    const float* __restrict__ g, const float* __restrict__ bta, float* __restrict__ out)
{
  __shared__ float red[4];
  int r = blockIdx.x, tid = threadIdx.x;
  const float* x = in + (size_t)r * D_;
  float v0 = x[tid], v1 = x[tid + 256];
  float mu = block_sum(v0 + v1, red) * (1.0f / 512.0f);
  float d0 = v0 - mu, d1 = v1 - mu;
  float var = block_sum(d0 * d0 + d1 * d1, red) * (1.0f / 512.0f);
  float inv = 1.0f / sqrtf(var + 1e-6f);
  out[(size_t)r * D_ + tid]       = d0 * inv * g[tid]       + bta[tid];
  out[(size_t)r * D_ + tid + 256] = d1 * inv * g[tid + 256] + bta[tid + 256];
}

// ---------- host-side MHA helper (MFMA projections; w = swizzled bf16 base, 4 DD mats) ----------
static void run_mha(hipStream_t st, const float* q_in, int Lq, const float* kv_in, int Lk,
                    const u32* mbits, const u16* w, const float* g, const float* bt,
                    float* qb, float* kb, float* vb, float* ob, float* tmp, float* out)
{
  dim3 blk(256);
  gemm_mfma<<<dim3(D_/128, (B_*Lq)/128), blk, 0, st>>>(q_in,  w + (size_t)0*DD, nullptr, nullptr, qb, D_, 0, 0,0,0,0);
  gemm_mfma<<<dim3(D_/128, (B_*Lk)/128), blk, 0, st>>>(kv_in, w + (size_t)1*DD, nullptr, nullptr, kb, D_, 0, 0,0,0,0);
  gemm_mfma<<<dim3(D_/128, (B_*Lk)/128), blk, 0, st>>>(kv_in, w + (size_t)2*DD, nullptr, nullptr, vb, D_, 0, 0,0,0,0);
  attn_mfma<<<dim3(Lq/32, NH_, B_), blk, 0, st>>>(qb, kb, vb, mbits, ob, Lq, Lk);
  gemm_mfma<<<dim3(D_/128, (B_*Lq)/128), blk, 0, st>>>(ob, w + (size_t)3*DD, nullptr, q_in, tmp, D_, 0, 0,0,0,0);
  ln_k<<<dim3(B_*Lq), blk, 0, st>>>(tmp, g, bt, out);
}

extern "C" void kernel_launch(void* const* d_in, const int* in_sizes, int n_in,
                              void* d_out, int out_size, void* d_ws, size_t ws_size,
                              hipStream_t stream) {
  (void)in_sizes; (void)n_in; (void)out_size; (void)ws_size;

  const float* xf    = (const float*)d_in[0];
  const int* adj_i   = (const int*)d_in[2];
  const int* adj_s   = (const int*)d_in[3];
  const int* adj_is  = (const int*)d_in[4];
  const int* adj_si  = (const int*)d_in[5];
  const float* intent= (const float*)d_in[6];
  const float* gatW  = (const float*)d_in[7];
  const float* gata  = (const float*)d_in[8];
  const float* gatoW = (const float*)d_in[9];
  const float* gatoa = (const float*)d_in[10];
  const float* mhaw  = (const float*)d_in[11];
  const float* lng   = (const float*)d_in[12];
  const float* lnb   = (const float*)d_in[13];
  const float* linW1 = (const float*)d_in[14];
  const float* linb1 = (const float*)d_in[15];
  const float* linW2 = (const float*)d_in[16];
  const float* linb2 = (const float*)d_in[17];

  float* out0 = (float*)d_out;                   // slot_out      [B,N,D]
  float* out1 = out0 + BND;                      // slot_logits   [B,N,OUT]
  float* out2 = out1 + (size_t)B_*N_*OUT_;       // slot_graph_out[B,N,D]

  // ---- workspace carve (~130 MB) ----
  float* Q    = (float*)d_ws;      // BND x6
  float* K    = Q   + BND;
  float* V    = K   + BND;
  float* O    = V   + BND;
  float* TMP  = O   + BND;
  float* HB1  = TMP + BND;
  float* ha0  = HB1 + BND;         // BID x9
  float* ha1  = ha0 + BID;
  float* ta   = ha1 + BID;
  float* tb   = ta  + BID;
  float* sqa  = tb  + BID;
  float* ska  = sqa + BID;
  float* sva  = ska + BID;
  float* soa  = sva + BID;
  float* stmp = soa + BID;
  float* s1   = stmp+ BID;         // 65536 x2
  float* s2   = s1  + 65536;
  float* s1o  = s2  + 65536;       // 8192 x2
  float* s2o  = s1o + 8192;
  u16* Wm  = (u16*)(s2o + 8192);   // 32*DD bf16 (all mhaw mats, swizzled)
  u16* Wg  = Wm  + (size_t)32*DD;  // gat Wcat swizzled
  u16* Wgo = Wg  + DD;             // gat_out_W swizzled
  u16* W1s = Wgo + DD;             // lin_W1 swizzled
  u16* W2s = W1s + DD;             // lin_W2 swizzled (512x128 -> DD/4)
  u32* pm_s  = (u32*)(W2s + DD/4); // adj_s  packed: 16*512*512/32 = 131072 u32
  u32* pm_i  = pm_s + 131072;      // adj_i  packed: 16*32*32/32   = 512
  u32* pm_is = pm_i + 512;         // adj_is packed: 16*512*32/32  = 8192
  u32* pm_si = pm_is + 8192;       // adj_si packed: 16*32*512/32  = 8192

  dim3 blk(256);

  // ---- mask packing ----
  pack_mask_k<<<(B_*N_*N_)/256,   blk, 0, stream>>>(adj_s,  pm_s);
  pack_mask_k<<<(B_*NI_*NI_)/256, blk, 0, stream>>>(adj_i,  pm_i);
  pack_mask_k<<<(B_*N_*NI_)/256,  blk, 0, stream>>>(adj_is, pm_is);
  pack_mask_k<<<(B_*NI_*N_)/256,  blk, 0, stream>>>(adj_si, pm_si);

  // ---- weight prep (swizzle to MFMA B-fragment order) ----
  swz_k<<<dim3(128, 32), blk, 0, stream>>>(mhaw,  Wm,  D_,   DD, DD);
  swz_gatW_k<<<128, blk, 0, stream>>>(gatW, Wg);
  swz_k<<<dim3(128, 1), blk, 0, stream>>>(gatoW, Wgo, D_,   0, 0);
  swz_k<<<dim3(128, 1), blk, 0, stream>>>(linW1, W1s, D_,   0, 0);
  swz_k<<<dim3(32,  1), blk, 0, stream>>>(linW2, W2s, OUT_, 0, 0);

  // ================= MHA stack =================
  bcast_k<<<BID/256, blk, 0, stream>>>(intent, ha0, BID);

  // ---- layer 0 (h_b = xf, h_a = ha0) ----
  run_mha(stream, ha0, NI_, ha0, NI_, pm_i,  Wm +  (size_t)0*DD, lng + 0*D_, lnb + 0*D_,
          sqa, ska, sva, soa, stmp, ta);                                   // a2a -> ta
  run_mha(stream, ha0, NI_, xf,  N_,  pm_si, Wm + (size_t)12*DD, lng + 3*D_, lnb + 3*D_,
          sqa, K, V, soa, stmp, tb);                                       // b2a -> tb
  add_relu_k<<<BID/256, blk, 0, stream>>>(ta, tb, ha1, BID);               // h_a1
  run_mha(stream, xf, N_, xf, N_, pm_s,  Wm +  (size_t)4*DD, lng + 1*D_, lnb + 1*D_,
          Q, K, V, O, TMP, HB1);                                           // b2b -> HB1
  run_mha(stream, xf, N_, ha0, NI_, pm_is, Wm + (size_t)8*DD, lng + 2*D_, lnb + 2*D_,
          Q, ska, sva, O, TMP, Q);                                         // a2b -> Q
  add_relu_ip_k<<<BND/256, blk, 0, stream>>>(HB1, Q, BND);                 // h_b1

  // ---- layer 1 (h_b = HB1, h_a = ha1); a2a/b2a dead ----
  run_mha(stream, HB1, N_, HB1, N_, pm_s,  Wm + (size_t)20*DD, lng + 5*D_, lnb + 5*D_,
          Q, K, V, O, TMP, K);                                             // b2b -> K
  run_mha(stream, HB1, N_, ha1, NI_, pm_is, Wm + (size_t)24*DD, lng + 6*D_, lnb + 6*D_,
          Q, ska, sva, O, TMP, Q);                                         // a2b -> Q
  add_relu_ip_k<<<BND/256, blk, 0, stream>>>(K, Q, BND);                   // h_b2 in K

  // ---- slot_out = x + h_b2 ----
  add_k<<<BND/256, blk, 0, stream>>>(xf, K, out0, BND);
  // ---- logits ----
  gemm_mfma<<<dim3(D_/128, (B_*N_)/128), blk, 0, stream>>>(out0, W1s, linb1, nullptr, Q, D_, 1, 0,0,0,0);
  gemm_mfma<<<dim3(OUT_/128, (B_*N_)/128), blk, 0, stream>>>(Q, W2s, linb2, nullptr, out1, OUT_, 0, 0,0,0,0);

  // ================= GAT branch =================
  gemm_mfma<<<dim3(D_/128, (B_*N_)/128), blk, 0, stream>>>(xf, Wg, nullptr, nullptr, Q /*h_all*/, D_, 0, 0,0,0,0);
  gat1_scores<<<(H_*B_*N_)/4, blk, 0, stream>>>(Q, gata, s1, s2);
  gat1_mfma<<<dim3(N_/32, H_, B_), blk, 0, stream>>>(pm_s, s1, s2, Q, K /*xc*/);
  gemm_mfma<<<dim3(D_/128, (B_*N_)/128), blk, 0, stream>>>(K, Wgo, nullptr, nullptr, V /*h2*/, D_, 0, 0,0,0,0);
  gat2_scores<<<(B_*N_)/4, blk, 0, stream>>>(V, gatoa, s1o, s2o);
  gat2_prob<<<B_*N_, blk, 0, stream>>>(pm_s, s1o, s2o, HB1 /*P*/);
  // out2 = elu(P @ h2) + x : swizzle runtime h2 per batch into free O buffer, then batched MFMA GEMM
  swz_k<<<dim3(128, B_), blk, 0, stream>>>(V, (u16*)O, D_, (size_t)N_*D_, (size_t)DD);
  gemm_mfma<<<dim3(D_/128, N_/128, B_), blk, 0, stream>>>(HB1, (u16*)O, nullptr, xf, out2, D_, 2,
      (size_t)N_*N_, (size_t)DD, (size_t)N_*D_, (size_t)N_*D_);
}

// Round 4
// 1312.934 us; speedup vs baseline: 1.1282x; 1.0574x over previous
//
#include <hip/hip_runtime.h>

// B=16, N=512, D=512, NI=32, GH=64, H=8, L=2, OUT=128, heads=8
#define B_   16
#define N_   512
#define D_   512
#define NI_  32
#define GH_  64
#define H_   8
#define OUT_ 128
#define NH_  8

#define BND   (B_*N_*D_)     // 4194304
#define BID   (B_*NI_*D_)    // 262144
#define DD    (D_*D_)        // 262144

#define SPS 528              // S row stride in bf16

typedef unsigned short u16;
typedef unsigned int   u32;
typedef __attribute__((ext_vector_type(8))) short short8;
typedef __attribute__((ext_vector_type(4))) short short4v;
typedef __attribute__((ext_vector_type(4))) float f32x4;

__device__ __forceinline__ u16 f2bf(float f){
  u32 x = __float_as_uint(f);
  x += 0x7fffu + ((x >> 16) & 1u);   // RNE
  return (u16)(x >> 16);
}
__device__ __forceinline__ float bf2f(u16 s){
  return __uint_as_float((u32)s << 16);
}

// blockDim must be 256
__device__ __forceinline__ float block_sum(float v, float* sm){
  #pragma unroll
  for (int o = 32; o; o >>= 1) v += __shfl_down(v, o, 64);
  int lane = threadIdx.x & 63, w = threadIdx.x >> 6;
  __syncthreads();
  if (lane == 0) sm[w] = v;
  __syncthreads();
  return sm[0] + sm[1] + sm[2] + sm[3];
}
__device__ __forceinline__ float block_max(float v, float* sm){
  #pragma unroll
  for (int o = 32; o; o >>= 1) v = fmaxf(v, __shfl_down(v, o, 64));
  int lane = threadIdx.x & 63, w = threadIdx.x >> 6;
  __syncthreads();
  if (lane == 0) sm[w] = v;
  __syncthreads();
  return fmaxf(fmaxf(sm[0], sm[1]), fmaxf(sm[2], sm[3]));
}

// ---------- mask bit-pack (adj>0 -> 1 bit) ----------
__global__ __launch_bounds__(256) void pack_mask_k(const int* __restrict__ adj, u32* __restrict__ bits){
  int i = blockIdx.x * 256 + threadIdx.x;
  unsigned long long m = __ballot(adj[i] > 0);
  if ((threadIdx.x & 63) == 0){
    bits[(i >> 5)]     = (u32)m;
    bits[(i >> 5) + 1] = (u32)(m >> 32);
  }
}

// ---------- elementwise ----------
__global__ __launch_bounds__(256) void bcast_k(const float* __restrict__ s, float* __restrict__ d, int n){
  int i = blockIdx.x * 256 + threadIdx.x;
  if (i < n) d[i] = s[i & (NI_*D_ - 1)];
}
__global__ __launch_bounds__(256) void add_relu_k(const float* __restrict__ a, const float* __restrict__ b,
                                                  float* __restrict__ o, int n){
  int i = blockIdx.x * 256 + threadIdx.x;
  if (i < n){ float v = a[i] + b[i]; o[i] = v > 0.0f ? v : 0.0f; }
}
__global__ __launch_bounds__(256) void add_relu_ip_k(float* __restrict__ a, const float* __restrict__ b, int n){
  int i = blockIdx.x * 256 + threadIdx.x;
  if (i < n){ float v = a[i] + b[i]; a[i] = v > 0.0f ? v : 0.0f; }
}
__global__ __launch_bounds__(256) void add_k(const float* __restrict__ a, const float* __restrict__ b,
                                             float* __restrict__ o, int n){
  int i = blockIdx.x * 256 + threadIdx.x;
  if (i < n) o[i] = a[i] + b[i];
}

// ---------- weight swizzle into MFMA B-fragment order ----------
__global__ __launch_bounds__(256) void swz_k(const float* __restrict__ W, u16* __restrict__ o,
                                             int Nc, size_t sW, size_t sO){
  int gw = blockIdx.x * 4 + (threadIdx.x >> 6);
  int lane = threadIdx.x & 63;
  int ntc = Nc >> 4;
  int s = gw / ntc, nt = gw - s * ntc;
  const float* Wb = W + sW * blockIdx.y;
  u16* ob = o + sO * blockIdx.y;
  int n = nt*16 + (lane & 15);
  int kb = s*32 + ((lane >> 4) << 3);
  u16 t8[8];
  #pragma unroll
  for (int j = 0; j < 8; j++) t8[j] = f2bf(Wb[(size_t)(kb + j) * Nc + n]);
  *(short8*)&ob[((size_t)(s * ntc + nt) * 64 + lane) * 8] = *(short8*)t8;
}
// gat_W [H,D,GH] -> head-major-concat [D,512], swizzled
__global__ __launch_bounds__(256) void swz_gatW_k(const float* __restrict__ gw_, u16* __restrict__ o){
  int gw = blockIdx.x * 4 + (threadIdx.x >> 6);  // 512 waves
  int lane = threadIdx.x & 63;
  int s = gw >> 5, nt = gw & 31;
  int n = nt*16 + (lane & 15);
  int h = n >> 6, f = n & 63;
  int kb = s*32 + ((lane >> 4) << 3);
  u16 t8[8];
  #pragma unroll
  for (int j = 0; j < 8; j++) t8[j] = f2bf(gw_[((size_t)(h*512) + kb + j) * 64 + f]);
  *(short8*)&o[((size_t)(s*32 + nt) * 64 + lane) * 8] = *(short8*)t8;
}

// ---------- MFMA GEMM ----------
// C modes (bitmask): 1 = fp32 C[M,Nc]; 2 = bf16 Cb[M,Nc]; 4 = bf16 transposed Ct[Nc,Mtot].
// 128x128 tile, 4 waves, each wave 64x64. K = 512 fixed. act: 0 none, 1 leaky, 2 elu.
__global__ __launch_bounds__(256) void gemm_mfma(
    const float* __restrict__ A, const u16* __restrict__ Bw,
    const float* __restrict__ bias, const float* __restrict__ resid,
    float* __restrict__ C, u16* __restrict__ Cb, u16* __restrict__ Ct,
    int Mtot, int Nc, int act, int mode,
    size_t sA, size_t sB, size_t sC, size_t sR)
{
  __shared__ __align__(16) u16 As[128*64];   // frag order: ((mt*2+kt)*64 + lane)*8 + j
  __shared__ __align__(16) u16 Bs[64*128];   // frag order: ((kt*8 + nt)*64 + lane)*8 + j
  A  += sA * blockIdx.z;
  Bw += sB * blockIdx.z;
  if (C) C += sC * blockIdx.z;
  if (resid) resid += sR * blockIdx.z;

  int tid = threadIdx.x, lane = tid & 63, wave = tid >> 6;
  int wm = wave & 1, wn = wave >> 1;
  int row0 = blockIdx.y << 7, col0 = blockIdx.x << 7;
  int ntc = Nc >> 4, nt0 = col0 >> 4;

  f32x4 acc[4][4] = {};

  for (int ks = 0; ks < 8; ks++){
    // stage A (fp32 -> bf16, fragment order)
    #pragma unroll
    for (int r = 0; r < 4; r++){
      int u = tid + (r << 8);
      int l = u & 63, kt = (u >> 6) & 1, mt = u >> 7;
      const float* src = A + (size_t)(row0 + (mt << 4) + (l & 15)) * 512
                           + (ks << 6) + (kt << 5) + ((l >> 4) << 3);
      float4 f0 = *(const float4*)src, f1 = *(const float4*)(src + 4);
      u16 t8[8] = {f2bf(f0.x), f2bf(f0.y), f2bf(f0.z), f2bf(f0.w),
                   f2bf(f1.x), f2bf(f1.y), f2bf(f1.z), f2bf(f1.w)};
      *(short8*)&As[(size_t)u * 8] = *(short8*)t8;
    }
    // stage B (straight contiguous copy of pre-swizzled chunk)
    #pragma unroll
    for (int kt = 0; kt < 2; kt++){
      const u16* sb = Bw + ((size_t)((ks*2 + kt) * ntc + nt0) << 9);
      #pragma unroll
      for (int r = 0; r < 2; r++){
        int uu = tid + (r << 8);
        *(short8*)&Bs[(kt << 12) + ((size_t)uu << 3)] = *(const short8*)(sb + ((size_t)uu << 3));
      }
    }
    __syncthreads();
    #pragma unroll
    for (int kt = 0; kt < 2; kt++){
      short8 a[4], b[4];
      #pragma unroll
      for (int i = 0; i < 4; i++)
        a[i] = *(short8*)&As[(((((wm<<2)+i) << 1) + kt) * 64 + lane) << 3];
      #pragma unroll
      for (int n = 0; n < 4; n++)
        b[n] = *(short8*)&Bs[(((kt << 3) + (wn<<2) + n) * 64 + lane) << 3];
      #pragma unroll
      for (int i = 0; i < 4; i++)
        #pragma unroll
        for (int n = 0; n < 4; n++)
          acc[i][n] = __builtin_amdgcn_mfma_f32_16x16x32_bf16(a[i], b[n], acc[i][n], 0, 0, 0);
    }
    __syncthreads();
  }

  int cq = lane >> 4, cn = lane & 15;
  #pragma unroll
  for (int i = 0; i < 4; i++){
    #pragma unroll
    for (int n = 0; n < 4; n++){
      int col = col0 + (wn<<6) + (n<<4) + cn;
      float bi = bias ? bias[col] : 0.0f;
      int rowb = row0 + (wm<<6) + (i<<4) + (cq<<2);
      float vals[4];
      #pragma unroll
      for (int r = 0; r < 4; r++){
        float c = acc[i][n][r] + bi;
        if (act == 1) c = c > 0.0f ? c : 0.2f * c;
        else if (act == 2) c = c > 0.0f ? c : expf(c) - 1.0f;
        if (resid) c += resid[(size_t)(rowb + r) * Nc + col];
        vals[r] = c;
      }
      if (mode & 1){
        #pragma unroll
        for (int r = 0; r < 4; r++) C[(size_t)(rowb + r) * Nc + col] = vals[r];
      }
      if (mode & 2){
        #pragma unroll
        for (int r = 0; r < 4; r++) Cb[(size_t)(rowb + r) * Nc + col] = f2bf(vals[r]);
      }
      if (mode & 4){
        u16 t4[4] = {f2bf(vals[0]), f2bf(vals[1]), f2bf(vals[2]), f2bf(vals[3])};
        *(short4v*)&Ct[(size_t)col * Mtot + rowb] = *(short4v*)t4;
      }
    }
  }
}

// ---------- MFMA MHA attention (bf16 inputs, V transposed, bit-packed mask) ----------
// Block: 256 threads = 4 waves, 32 q-rows of one (b,h). Q frags in registers.
// q,k: bf16 [B*L, 512]. vt: bf16 [512, B*Lk] (transposed). o: fp32.
__global__ __launch_bounds__(256) void attn_mfma(
    const u16* __restrict__ q, const u16* __restrict__ k, const u16* __restrict__ vt,
    const u32* __restrict__ mbits, float* __restrict__ o, int Lq, int Lk)
{
  __shared__ __align__(16) u16 S[32][SPS];      // scores, then P (bf16)
  __shared__ __align__(16) u16 KVf[8*64*8];     // K^T / V B-fragments
  __shared__ float inv[32];

  int tid = threadIdx.x, lane = tid & 63, wave = tid >> 6;
  int wm = wave & 1, wn = wave >> 1;
  int q0 = blockIdx.x << 5, h = blockIdx.y, b = blockIdx.z;
  int ntiles = (Lk + 63) >> 6;
  size_t vM = (size_t)B_ * Lk;

  // Q fragments in registers (wave wm covers rows q0+wm*16..+15)
  short8 aq[2];
  #pragma unroll
  for (int kt = 0; kt < 2; kt++)
    aq[kt] = *(const short8*)(q + ((size_t)(b*Lq + q0 + (wm<<4) + (lane & 15)))*512
                                + h*64 + (kt<<5) + ((lane >> 4) << 3));

  int cq = lane >> 4, cn = lane & 15;

  // ---- QK^T -> S ----
  for (int jt = 0; jt < (ntiles << 6); jt += 64){
    #pragma unroll
    for (int r = 0; r < 2; r++){
      int u = tid + (r << 8);
      int l = u & 63, unit = u >> 6;
      int kt = unit >> 2, nt = unit & 3;
      int key = jt + (nt<<4) + (l & 15);
      short8 val = {0,0,0,0,0,0,0,0};
      if (key < Lk)
        val = *(const short8*)(k + ((size_t)(b*Lk + key))*512 + h*64 + (kt<<5) + ((l >> 4) << 3));
      *(short8*)&KVf[(size_t)u * 8] = val;
    }
    __syncthreads();
    f32x4 accs[2] = {};
    #pragma unroll
    for (int kt = 0; kt < 2; kt++){
      #pragma unroll
      for (int ntl = 0; ntl < 2; ntl++){
        short8 bf = *(short8*)&KVf[((((kt<<2) + (wn<<1) + ntl)*64 + lane)) << 3];
        accs[ntl] = __builtin_amdgcn_mfma_f32_16x16x32_bf16(aq[kt], bf, accs[ntl], 0, 0, 0);
      }
    }
    #pragma unroll
    for (int ntl = 0; ntl < 2; ntl++){
      int j = jt + (wn<<5) + (ntl<<4) + cn;
      #pragma unroll
      for (int r = 0; r < 4; r++){
        int srow = (wm<<4) + (cq<<2) + r;
        float e;
        if (j < Lk){
          size_t bi = ((size_t)(b*Lq) + q0 + srow)*Lk + j;
          u32 w = mbits[bi >> 5];
          e = ((w >> (bi & 31)) & 1u) ? accs[ntl][r] * 0.125f : -1.0e9f;
        } else e = -__builtin_inff();
        S[srow][j] = f2bf(e);
      }
    }
    __syncthreads();
  }

  // ---- softmax rows (8 threads per row) ----
  {
    int row = tid >> 3, part = tid & 7;
    int Lkp = ntiles << 6;
    float mx = -3.0e38f;
    for (int j = part; j < Lkp; j += 8) mx = fmaxf(mx, bf2f(S[row][j]));
    #pragma unroll
    for (int m = 1; m < 8; m <<= 1) mx = fmaxf(mx, __shfl_xor(mx, m, 8));
    float sum = 0.0f;
    for (int j = part; j < Lkp; j += 8){
      float p = expf(bf2f(S[row][j]) - mx);
      u16 pb = f2bf(p);
      S[row][j] = pb; sum += bf2f(pb);
    }
    #pragma unroll
    for (int m = 1; m < 8; m <<= 1) sum += __shfl_xor(sum, m, 8);
    if (part == 0) inv[row] = 1.0f / sum;
  }
  __syncthreads();

  // ---- PV (V read from transposed bf16: contiguous keys) ----
  f32x4 acco[2] = {};
  for (int jt = 0; jt < (ntiles << 6); jt += 64){
    #pragma unroll
    for (int r = 0; r < 2; r++){
      int u = tid + (r << 8);
      int l = u & 63, unit = u >> 6;
      int kt = unit >> 2, nt = unit & 3;
      int d  = (nt<<4) + (l & 15);
      int keyb = jt + (kt<<5) + ((l >> 4) << 3);
      short8 val = {0,0,0,0,0,0,0,0};
      if (keyb < Lk)
        val = *(const short8*)(vt + ((size_t)(h*64 + d))*vM + (size_t)b*Lk + keyb);
      *(short8*)&KVf[(size_t)u * 8] = val;
    }
    __syncthreads();
    #pragma unroll
    for (int kt = 0; kt < 2; kt++){
      short8 a = *(short8*)&S[(wm<<4) + (lane & 15)][jt + (kt<<5) + ((lane >> 4) << 3)];
      #pragma unroll
      for (int ntl = 0; ntl < 2; ntl++){
        short8 bf = *(short8*)&KVf[((((kt<<2) + (wn<<1) + ntl)*64 + lane)) << 3];
        acco[ntl] = __builtin_amdgcn_mfma_f32_16x16x32_bf16(a, bf, acco[ntl], 0, 0, 0);
      }
    }
    __syncthreads();
  }

  #pragma unroll
  for (int ntl = 0; ntl < 2; ntl++){
    int d = h*64 + (wn<<5) + (ntl<<4) + cn;
    #pragma unroll
    for (int r = 0; r < 4; r++){
      int srow = (wm<<4) + (cq<<2) + r;
      o[((size_t)(b*Lq + q0 + srow))*512 + d] = acco[ntl][r] * inv[srow];
    }
  }
}

// ---------- GAT scores ----------
__global__ __launch_bounds__(256) void gat1_scores(const float* __restrict__ hall,
    const float* __restrict__ gata, float* __restrict__ s1, float* __restrict__ s2)
{
  int gw = blockIdx.x * 4 + (threadIdx.x >> 6);
  int lane = threadIdx.x & 63;
  int h = gw >> 13;
  int r = gw & 8191;
  float v = hall[(size_t)r * D_ + h * 64 + lane];
  float p1 = v * gata[h * 128 + lane];
  float p2 = v * gata[h * 128 + 64 + lane];
  #pragma unroll
  for (int o = 32; o; o >>= 1){ p1 += __shfl_down(p1, o, 64); p2 += __shfl_down(p2, o, 64); }
  if (lane == 0){ s1[h * 8192 + r] = p1; s2[h * 8192 + r] = p2; }
}
__global__ __launch_bounds__(256) void gat2_scores(const float* __restrict__ h2,
    const float* __restrict__ gatoa, float* __restrict__ s1, float* __restrict__ s2)
{
  int r = blockIdx.x * 4 + (threadIdx.x >> 6);
  int lane = threadIdx.x & 63;
  float p1 = 0.0f, p2 = 0.0f;
  for (int c = lane; c < D_; c += 64){
    float v = h2[(size_t)r * D_ + c];
    p1 += v * gatoa[c];
    p2 += v * gatoa[D_ + c];
  }
  #pragma unroll
  for (int o = 32; o; o >>= 1){ p1 += __shfl_down(p1, o, 64); p2 += __shfl_down(p2, o, 64); }
  if (lane == 0){ s1[r] = p1; s2[r] = p2; }
}

// ---------- MFMA GAT layer-1 attention (bit-packed mask, bf16 S, transposed bf16 hall) ----------
__global__ __launch_bounds__(256) void gat1_mfma(const u32* __restrict__ mbits,
    const float* __restrict__ s1, const float* __restrict__ s2,
    const u16* __restrict__ ht, float* __restrict__ xc)
{
  __shared__ __align__(16) u16 S[32][SPS];
  __shared__ __align__(16) u16 Vf[8*64*8];
  __shared__ float inv[32];

  int tid = threadIdx.x, lane = tid & 63, wave = tid >> 6;
  int wm = wave & 1, wn = wave >> 1;
  int q0 = blockIdx.x << 5, h = blockIdx.y, b = blockIdx.z;
  int hb = h * 8192 + b * 512;

  // scores: S = adj ? leaky(s1[q]+s2[j]) : -9e15
  for (int x = tid; x < 32*128; x += 256){
    int row = x >> 7, c4 = (x & 127) << 2;
    float s1v = s1[hb + q0 + row];
    float4 s2v = *(const float4*)(s2 + hb + c4);
    size_t bi = ((size_t)(b*512) + q0 + row)*512 + c4;
    u32 w = mbits[bi >> 5] >> (bi & 31);
    float t; u16 q4[4];
    t = s1v + s2v.x; t = t>0?t:0.2f*t; q4[0] = f2bf((w     & 1u) ? t : -9.0e15f);
    t = s1v + s2v.y; t = t>0?t:0.2f*t; q4[1] = f2bf(((w>>1) & 1u) ? t : -9.0e15f);
    t = s1v + s2v.z; t = t>0?t:0.2f*t; q4[2] = f2bf(((w>>2) & 1u) ? t : -9.0e15f);
    t = s1v + s2v.w; t = t>0?t:0.2f*t; q4[3] = f2bf(((w>>3) & 1u) ? t : -9.0e15f);
    *(short4v*)&S[row][c4] = *(short4v*)q4;
  }
  __syncthreads();

  {
    int row = tid >> 3, part = tid & 7;
    float mx = -3.0e38f;
    for (int j = part; j < 512; j += 8) mx = fmaxf(mx, bf2f(S[row][j]));
    #pragma unroll
    for (int m = 1; m < 8; m <<= 1) mx = fmaxf(mx, __shfl_xor(mx, m, 8));
    float sum = 0.0f;
    for (int j = part; j < 512; j += 8){
      float p = expf(bf2f(S[row][j]) - mx);
      u16 pb = f2bf(p);
      S[row][j] = pb; sum += bf2f(pb);
    }
    #pragma unroll
    for (int m = 1; m < 8; m <<= 1) sum += __shfl_xor(sum, m, 8);
    if (part == 0) inv[row] = 1.0f / sum;
  }
  __syncthreads();

  f32x4 acco[2] = {};
  for (int jt = 0; jt < 512; jt += 64){
    #pragma unroll
    for (int r = 0; r < 2; r++){
      int u = tid + (r << 8);
      int l = u & 63, unit = u >> 6;
      int kt = unit >> 2, nt = unit & 3;
      int d  = (nt<<4) + (l & 15);
      int keyb = jt + (kt<<5) + ((l >> 4) << 3);
      *(short8*)&Vf[(size_t)u * 8] =
        *(const short8*)(ht + ((size_t)(h*64 + d))*(size_t)(B_*N_) + (size_t)b*512 + keyb);
    }
    __syncthreads();
    #pragma unroll
    for (int kt = 0; kt < 2; kt++){
      short8 a = *(short8*)&S[(wm<<4) + (lane & 15)][jt + (kt<<5) + ((lane >> 4) << 3)];
      #pragma unroll
      for (int ntl = 0; ntl < 2; ntl++){
        short8 bf = *(short8*)&Vf[((((kt<<2) + (wn<<1) + ntl)*64 + lane)) << 3];
        acco[ntl] = __builtin_amdgcn_mfma_f32_16x16x32_bf16(a, bf, acco[ntl], 0, 0, 0);
      }
    }
    __syncthreads();
  }

  int cq = lane >> 4, cn = lane & 15;
  #pragma unroll
  for (int ntl = 0; ntl < 2; ntl++){
    int d = h*64 + (wn<<5) + (ntl<<4) + cn;
    #pragma unroll
    for (int r = 0; r < 4; r++){
      int srow = (wm<<4) + (cq<<2) + r;
      float val = acco[ntl][r] * inv[srow];
      val = val > 0.0f ? val : expf(val) - 1.0f;
      xc[((size_t)(b*512 + q0 + srow))*512 + d] = val;
    }
  }
}

// ---------- GAT output-layer probabilities (bit-packed mask) ----------
__global__ __launch_bounds__(256) void gat2_prob(const u32* __restrict__ mbits,
    const float* __restrict__ s1, const float* __restrict__ s2, float* __restrict__ P)
{
  __shared__ float red[4];
  int r = blockIdx.x, tid = threadIdx.x;
  int b = r >> 9;
  float s1v = s1[r];
  float e0, e1;
  {
    size_t base = (size_t)r * 512;
    u32 w0 = mbits[(base + tid) >> 5];
    u32 w1 = mbits[(base + tid + 256) >> 5];
    float t = s1v + s2[b*512 + tid];       t = t>0?t:0.2f*t;
    e0 = ((w0 >> (tid & 31)) & 1u) ? t : -9.0e15f;
    t = s1v + s2[b*512 + tid + 256];       t = t>0?t:0.2f*t;
    e1 = ((w1 >> (tid & 31)) & 1u) ? t : -9.0e15f;
  }
  float mx = block_max(fmaxf(e0, e1), red);
  float p0 = expf(e0 - mx), p1 = expf(e1 - mx);
  float s = block_sum(p0 + p1, red);
  float inv = 1.0f / s;
  P[(size_t)r*512 + tid]       = p0 * inv;
  P[(size_t)r*512 + tid + 256] = p1 * inv;
}

// ---------- LayerNorm ----------
__global__ __launch_bounds__(256) void ln_k(const float* __restrict__ in,
    const float* __restrict__ g, const float* __restrict__ bta, float* __restrict__ out)
{
  __shared__ float red[4];
  int r = blockIdx.x, tid = threadIdx.x;
  const float* x = in + (size_t)r * D_;
  float v0 = x[tid], v1 = x[tid + 256];
  float mu = block_sum(v0 + v1, red) * (1.0f / 512.0f);
  float d0 = v0 - mu, d1 = v1 - mu;
  float var = block_sum(d0 * d0 + d1 * d1, red) * (1.0f / 512.0f);
  float inv = 1.0f / sqrtf(var + 1e-6f);
  out[(size_t)r * D_ + tid]       = d0 * inv * g[tid]       + bta[tid];
  out[(size_t)r * D_ + tid + 256] = d1 * inv * g[tid + 256] + bta[tid + 256];
}

// ---------- host-side MHA helper ----------
static void run_mha(hipStream_t st, const float* q_in, int Lq, const float* kv_in, int Lk,
                    const u32* mbits, const u16* w, const float* g, const float* bt,
                    u16* qbf, u16* kbf, u16* vtb, float* ob, float* tmp, float* out)
{
  dim3 blk(256);
  int Mq = B_*Lq, Mk = B_*Lk;
  gemm_mfma<<<dim3(4, Mq/128), blk, 0, st>>>(q_in,  w + (size_t)0*DD, nullptr, nullptr,
      nullptr, qbf, nullptr, Mq, D_, 0, 2, 0,0,0,0);
  gemm_mfma<<<dim3(4, Mk/128), blk, 0, st>>>(kv_in, w + (size_t)1*DD, nullptr, nullptr,
      nullptr, kbf, nullptr, Mk, D_, 0, 2, 0,0,0,0);
  gemm_mfma<<<dim3(4, Mk/128), blk, 0, st>>>(kv_in, w + (size_t)2*DD, nullptr, nullptr,
      nullptr, nullptr, vtb, Mk, D_, 0, 4, 0,0,0,0);
  attn_mfma<<<dim3(Lq/32, NH_, B_), blk, 0, st>>>(qbf, kbf, vtb, mbits, ob, Lq, Lk);
  gemm_mfma<<<dim3(4, Mq/128), blk, 0, st>>>(ob, w + (size_t)3*DD, nullptr, q_in,
      tmp, nullptr, nullptr, Mq, D_, 0, 1, 0,0,0,0);
  ln_k<<<dim3(Mq), blk, 0, st>>>(tmp, g, bt, out);
}

extern "C" void kernel_launch(void* const* d_in, const int* in_sizes, int n_in,
                              void* d_out, int out_size, void* d_ws, size_t ws_size,
                              hipStream_t stream) {
  (void)in_sizes; (void)n_in; (void)out_size; (void)ws_size;

  const float* xf    = (const float*)d_in[0];
  const int* adj_i   = (const int*)d_in[2];
  const int* adj_s   = (const int*)d_in[3];
  const int* adj_is  = (const int*)d_in[4];
  const int* adj_si  = (const int*)d_in[5];
  const float* intent= (const float*)d_in[6];
  const float* gatW  = (const float*)d_in[7];
  const float* gata  = (const float*)d_in[8];
  const float* gatoW = (const float*)d_in[9];
  const float* gatoa = (const float*)d_in[10];
  const float* mhaw  = (const float*)d_in[11];
  const float* lng   = (const float*)d_in[12];
  const float* lnb   = (const float*)d_in[13];
  const float* linW1 = (const float*)d_in[14];
  const float* linb1 = (const float*)d_in[15];
  const float* linW2 = (const float*)d_in[16];
  const float* linb2 = (const float*)d_in[17];

  float* out0 = (float*)d_out;                   // slot_out      [B,N,D]
  float* out1 = out0 + BND;                      // slot_logits   [B,N,OUT]
  float* out2 = out1 + (size_t)B_*N_*OUT_;       // slot_graph_out[B,N,D]

  // ---- workspace carve (~130 MB) ----
  float* Q    = (float*)d_ws;      // BND x6
  float* K    = Q   + BND;
  float* V    = K   + BND;
  float* O    = V   + BND;
  float* TMP  = O   + BND;
  float* HB1  = TMP + BND;
  float* ha0  = HB1 + BND;         // BID x9
  float* ha1  = ha0 + BID;
  float* ta   = ha1 + BID;
  float* tb   = ta  + BID;
  float* sqa  = tb  + BID;
  float* ska  = sqa + BID;
  float* sva  = ska + BID;
  float* soa  = sva + BID;
  float* stmp = soa + BID;
  float* s1   = stmp+ BID;         // 65536 x2
  float* s2   = s1  + 65536;
  float* s1o  = s2  + 65536;       // 8192 x2
  float* s2o  = s1o + 8192;
  u16* Wm  = (u16*)(s2o + 8192);   // 32*DD bf16 (all mhaw mats, swizzled)
  u16* Wg  = Wm  + (size_t)32*DD;  // gat Wcat swizzled
  u16* Wgo = Wg  + DD;             // gat_out_W swizzled
  u16* W1s = Wgo + DD;             // lin_W1 swizzled
  u16* W2s = W1s + DD;             // lin_W2 swizzled (512x128 -> DD/4)
  u32* pm_s  = (u32*)(W2s + DD/4); // adj_s  packed
  u32* pm_i  = pm_s + 131072;
  u32* pm_is = pm_i + 512;
  u32* pm_si = pm_is + 8192;

  // bf16 overlays on dead fp32 scratch:
  u16* qbf = (u16*)V;              // BND u16 (first half of V)  -- V fp32 only used in GAT phase
  u16* kbf = (u16*)V + BND;        // BND u16 (second half of V)
  u16* vtb = (u16*)TMP;            // BND u16; clobbered by out-proj AFTER attn reads it (stream-ordered)
  u16* htb = (u16*)O;              // BND u16; O fp32 dead in GAT phase until swz_k reuses it later

  dim3 blk(256);

  // ---- mask packing ----
  pack_mask_k<<<(B_*N_*N_)/256,   blk, 0, stream>>>(adj_s,  pm_s);
  pack_mask_k<<<(B_*NI_*NI_)/256, blk, 0, stream>>>(adj_i,  pm_i);
  pack_mask_k<<<(B_*N_*NI_)/256,  blk, 0, stream>>>(adj_is, pm_is);
  pack_mask_k<<<(B_*NI_*N_)/256,  blk, 0, stream>>>(adj_si, pm_si);

  // ---- weight prep ----
  swz_k<<<dim3(128, 32), blk, 0, stream>>>(mhaw,  Wm,  D_,   DD, DD);
  swz_gatW_k<<<128, blk, 0, stream>>>(gatW, Wg);
  swz_k<<<dim3(128, 1), blk, 0, stream>>>(gatoW, Wgo, D_,   0, 0);
  swz_k<<<dim3(128, 1), blk, 0, stream>>>(linW1, W1s, D_,   0, 0);
  swz_k<<<dim3(32,  1), blk, 0, stream>>>(linW2, W2s, OUT_, 0, 0);

  // ================= MHA stack =================
  bcast_k<<<BID/256, blk, 0, stream>>>(intent, ha0, BID);

  // ---- layer 0 (h_b = xf, h_a = ha0) ----
  run_mha(stream, ha0, NI_, ha0, NI_, pm_i,  Wm +  (size_t)0*DD, lng + 0*D_, lnb + 0*D_,
          qbf, kbf, vtb, soa, stmp, ta);                                   // a2a -> ta
  run_mha(stream, ha0, NI_, xf,  N_,  pm_si, Wm + (size_t)12*DD, lng + 3*D_, lnb + 3*D_,
          qbf, kbf, vtb, soa, stmp, tb);                                   // b2a -> tb
  add_relu_k<<<BID/256, blk, 0, stream>>>(ta, tb, ha1, BID);               // h_a1
  run_mha(stream, xf, N_, xf, N_, pm_s,  Wm +  (size_t)4*DD, lng + 1*D_, lnb + 1*D_,
          qbf, kbf, vtb, O, TMP, HB1);                                     // b2b -> HB1
  run_mha(stream, xf, N_, ha0, NI_, pm_is, Wm + (size_t)8*DD, lng + 2*D_, lnb + 2*D_,
          qbf, kbf, vtb, O, TMP, Q);                                       // a2b -> Q
  add_relu_ip_k<<<BND/256, blk, 0, stream>>>(HB1, Q, BND);                 // h_b1

  // ---- layer 1 (h_b = HB1, h_a = ha1); a2a/b2a dead ----
  run_mha(stream, HB1, N_, HB1, N_, pm_s,  Wm + (size_t)20*DD, lng + 5*D_, lnb + 5*D_,
          qbf, kbf, vtb, O, TMP, K);                                       // b2b -> K
  run_mha(stream, HB1, N_, ha1, NI_, pm_is, Wm + (size_t)24*DD, lng + 6*D_, lnb + 6*D_,
          qbf, kbf, vtb, O, TMP, Q);                                       // a2b -> Q
  add_relu_ip_k<<<BND/256, blk, 0, stream>>>(K, Q, BND);                   // h_b2 in K

  // ---- slot_out = x + h_b2 ----
  add_k<<<BND/256, blk, 0, stream>>>(xf, K, out0, BND);
  // ---- logits ----
  gemm_mfma<<<dim3(4, (B_*N_)/128), blk, 0, stream>>>(out0, W1s, linb1, nullptr,
      Q, nullptr, nullptr, 0, D_, 1, 1, 0,0,0,0);
  gemm_mfma<<<dim3(1, (B_*N_)/128), blk, 0, stream>>>(Q, W2s, linb2, nullptr,
      out1, nullptr, nullptr, 0, OUT_, 0, 1, 0,0,0,0);

  // ================= GAT branch =================
  // h_all -> Q (fp32) + htb (bf16 transposed, for gat1 PV)
  gemm_mfma<<<dim3(4, (B_*N_)/128), blk, 0, stream>>>(xf, Wg, nullptr, nullptr,
      Q, nullptr, htb, B_*N_, D_, 0, 5, 0,0,0,0);
  gat1_scores<<<(H_*B_*N_)/4, blk, 0, stream>>>(Q, gata, s1, s2);
  gat1_mfma<<<dim3(N_/32, H_, B_), blk, 0, stream>>>(pm_s, s1, s2, htb, K /*xc*/);
  gemm_mfma<<<dim3(4, (B_*N_)/128), blk, 0, stream>>>(K, Wgo, nullptr, nullptr,
      V /*h2*/, nullptr, nullptr, 0, D_, 0, 1, 0,0,0,0);
  gat2_scores<<<(B_*N_)/4, blk, 0, stream>>>(V, gatoa, s1o, s2o);
  gat2_prob<<<B_*N_, blk, 0, stream>>>(pm_s, s1o, s2o, HB1 /*P*/);
  // out2 = elu(P @ h2) + x : swizzle runtime h2 per batch into O (u16), batched MFMA GEMM
  swz_k<<<dim3(128, B_), blk, 0, stream>>>(V, (u16*)O, D_, (size_t)N_*D_, (size_t)DD);
  gemm_mfma<<<dim3(4, N_/128, B_), blk, 0, stream>>>(HB1, (u16*)O, nullptr, xf,
      out2, nullptr, nullptr, 0, D_, 2, 1,
      (size_t)N_*N_, (size_t)DD, (size_t)N_*D_, (size_t)N_*D_);
}

// Round 5
// 1193.745 us; speedup vs baseline: 1.2408x; 1.0998x over previous
//
#include <hip/hip_runtime.h>

// B=16, N=512, D=512, NI=32, GH=64, H=8, L=2, OUT=128, heads=8
#define B_   16
#define N_   512
#define D_   512
#define NI_  32
#define GH_  64
#define H_   8
#define OUT_ 128
#define NH_  8

#define BND   (B_*N_*D_)     // 4194304
#define BID   (B_*NI_*D_)    // 262144
#define DD    (D_*D_)        // 262144

#define SPS 528              // S row stride in bf16

typedef unsigned short u16;
typedef unsigned int   u32;
typedef __attribute__((ext_vector_type(8))) short short8;
typedef __attribute__((ext_vector_type(4))) short short4v;
typedef __attribute__((ext_vector_type(4))) float f32x4;

__device__ __forceinline__ u16 f2bf(float f){
  u32 x = __float_as_uint(f);
  x += 0x7fffu + ((x >> 16) & 1u);   // RNE
  return (u16)(x >> 16);
}
__device__ __forceinline__ float bf2f(u16 s){
  return __uint_as_float((u32)s << 16);
}

// blockDim must be 256
__device__ __forceinline__ float block_sum(float v, float* sm){
  #pragma unroll
  for (int o = 32; o; o >>= 1) v += __shfl_down(v, o, 64);
  int lane = threadIdx.x & 63, w = threadIdx.x >> 6;
  __syncthreads();
  if (lane == 0) sm[w] = v;
  __syncthreads();
  return sm[0] + sm[1] + sm[2] + sm[3];
}
__device__ __forceinline__ float block_max(float v, float* sm){
  #pragma unroll
  for (int o = 32; o; o >>= 1) v = fmaxf(v, __shfl_down(v, o, 64));
  int lane = threadIdx.x & 63, w = threadIdx.x >> 6;
  __syncthreads();
  if (lane == 0) sm[w] = v;
  __syncthreads();
  return fmaxf(fmaxf(sm[0], sm[1]), fmaxf(sm[2], sm[3]));
}

// ---------- mask bit-pack (adj>0 -> 1 bit) ----------
__global__ __launch_bounds__(256) void pack_mask_k(const int* __restrict__ adj, u32* __restrict__ bits){
  int i = blockIdx.x * 256 + threadIdx.x;
  unsigned long long m = __ballot(adj[i] > 0);
  if ((threadIdx.x & 63) == 0){
    bits[(i >> 5)]     = (u32)m;
    bits[(i >> 5) + 1] = (u32)(m >> 32);
  }
}

// ---------- elementwise ----------
__global__ __launch_bounds__(256) void bcast_k(const float* __restrict__ s, float* __restrict__ d, int n){
  int i = blockIdx.x * 256 + threadIdx.x;
  if (i < n) d[i] = s[i & (NI_*D_ - 1)];
}
__global__ __launch_bounds__(256) void add_relu_k(const float* __restrict__ a, const float* __restrict__ b,
                                                  float* __restrict__ o, int n){
  int i = blockIdx.x * 256 + threadIdx.x;
  if (i < n){ float v = a[i] + b[i]; o[i] = v > 0.0f ? v : 0.0f; }
}
__global__ __launch_bounds__(256) void add_relu_ip_k(float* __restrict__ a, const float* __restrict__ b, int n){
  int i = blockIdx.x * 256 + threadIdx.x;
  if (i < n){ float v = a[i] + b[i]; a[i] = v > 0.0f ? v : 0.0f; }
}
__global__ __launch_bounds__(256) void add_k(const float* __restrict__ a, const float* __restrict__ b,
                                             float* __restrict__ o, int n){
  int i = blockIdx.x * 256 + threadIdx.x;
  if (i < n) o[i] = a[i] + b[i];
}

// ---------- weight swizzle into MFMA B-fragment order ----------
__global__ __launch_bounds__(256) void swz_k(const float* __restrict__ W, u16* __restrict__ o,
                                             int Nc, size_t sW, size_t sO){
  int gw = blockIdx.x * 4 + (threadIdx.x >> 6);
  int lane = threadIdx.x & 63;
  int ntc = Nc >> 4;
  int s = gw / ntc, nt = gw - s * ntc;
  const float* Wb = W + sW * blockIdx.y;
  u16* ob = o + sO * blockIdx.y;
  int n = nt*16 + (lane & 15);
  int kb = s*32 + ((lane >> 4) << 3);
  u16 t8[8];
  #pragma unroll
  for (int j = 0; j < 8; j++) t8[j] = f2bf(Wb[(size_t)(kb + j) * Nc + n]);
  *(short8*)&ob[((size_t)(s * ntc + nt) * 64 + lane) * 8] = *(short8*)t8;
}
// gat_W [H,D,GH] -> head-major-concat [D,512], swizzled
__global__ __launch_bounds__(256) void swz_gatW_k(const float* __restrict__ gw_, u16* __restrict__ o){
  int gw = blockIdx.x * 4 + (threadIdx.x >> 6);  // 512 waves
  int lane = threadIdx.x & 63;
  int s = gw >> 5, nt = gw & 31;
  int n = nt*16 + (lane & 15);
  int h = n >> 6, f = n & 63;
  int kb = s*32 + ((lane >> 4) << 3);
  u16 t8[8];
  #pragma unroll
  for (int j = 0; j < 8; j++) t8[j] = f2bf(gw_[((size_t)(h*512) + kb + j) * 64 + f]);
  *(short8*)&o[((size_t)(s*32 + nt) * 64 + lane) * 8] = *(short8*)t8;
}

// ---------- MFMA GEMM ----------
// A source: fp32 A or bf16 Ab (one non-null). K = 512 fixed.
// C modes (bitmask): 1 = fp32 C[M,Nc]; 2 = bf16 Cb[M,Nc]; 4 = bf16 transposed Ct[Nc,Mtot].
// act: 0 none, 1 leaky, 2 elu. Batched over blockIdx.z via strides.
__global__ __launch_bounds__(256) void gemm_mfma(
    const float* __restrict__ A, const u16* __restrict__ Ab, const u16* __restrict__ Bw,
    const float* __restrict__ bias, const float* __restrict__ resid,
    float* __restrict__ C, u16* __restrict__ Cb, u16* __restrict__ Ct,
    int Mtot, int Nc, int act, int mode,
    size_t sA, size_t sB, size_t sC, size_t sR)
{
  __shared__ __align__(16) u16 As[128*64];   // frag order: ((mt*2+kt)*64 + lane)*8 + j
  __shared__ __align__(16) u16 Bs[64*128];   // frag order: ((kt*8 + nt)*64 + lane)*8 + j
  if (A)  A  += sA * blockIdx.z;
  if (Ab) Ab += sA * blockIdx.z;
  Bw += sB * blockIdx.z;
  if (C) C += sC * blockIdx.z;
  if (resid) resid += sR * blockIdx.z;

  int tid = threadIdx.x, lane = tid & 63, wave = tid >> 6;
  int wm = wave & 1, wn = wave >> 1;
  int row0 = blockIdx.y << 7, col0 = blockIdx.x << 7;
  int ntc = Nc >> 4, nt0 = col0 >> 4;

  f32x4 acc[4][4] = {};

  for (int ks = 0; ks < 8; ks++){
    // stage A (fragment order)
    if (Ab){
      #pragma unroll
      for (int r = 0; r < 4; r++){
        int u = tid + (r << 8);
        int l = u & 63, kt = (u >> 6) & 1, mt = u >> 7;
        const u16* src = Ab + (size_t)(row0 + (mt << 4) + (l & 15)) * 512
                            + (ks << 6) + (kt << 5) + ((l >> 4) << 3);
        *(short8*)&As[(size_t)u * 8] = *(const short8*)src;
      }
    } else {
      #pragma unroll
      for (int r = 0; r < 4; r++){
        int u = tid + (r << 8);
        int l = u & 63, kt = (u >> 6) & 1, mt = u >> 7;
        const float* src = A + (size_t)(row0 + (mt << 4) + (l & 15)) * 512
                             + (ks << 6) + (kt << 5) + ((l >> 4) << 3);
        float4 f0 = *(const float4*)src, f1 = *(const float4*)(src + 4);
        u16 t8[8] = {f2bf(f0.x), f2bf(f0.y), f2bf(f0.z), f2bf(f0.w),
                     f2bf(f1.x), f2bf(f1.y), f2bf(f1.z), f2bf(f1.w)};
        *(short8*)&As[(size_t)u * 8] = *(short8*)t8;
      }
    }
    // stage B (straight contiguous copy of pre-swizzled chunk)
    #pragma unroll
    for (int kt = 0; kt < 2; kt++){
      const u16* sb = Bw + ((size_t)((ks*2 + kt) * ntc + nt0) << 9);
      #pragma unroll
      for (int r = 0; r < 2; r++){
        int uu = tid + (r << 8);
        *(short8*)&Bs[(kt << 12) + ((size_t)uu << 3)] = *(const short8*)(sb + ((size_t)uu << 3));
      }
    }
    __syncthreads();
    #pragma unroll
    for (int kt = 0; kt < 2; kt++){
      short8 a[4], b[4];
      #pragma unroll
      for (int i = 0; i < 4; i++)
        a[i] = *(short8*)&As[(((((wm<<2)+i) << 1) + kt) * 64 + lane) << 3];
      #pragma unroll
      for (int n = 0; n < 4; n++)
        b[n] = *(short8*)&Bs[(((kt << 3) + (wn<<2) + n) * 64 + lane) << 3];
      #pragma unroll
      for (int i = 0; i < 4; i++)
        #pragma unroll
        for (int n = 0; n < 4; n++)
          acc[i][n] = __builtin_amdgcn_mfma_f32_16x16x32_bf16(a[i], b[n], acc[i][n], 0, 0, 0);
    }
    __syncthreads();
  }

  int cq = lane >> 4, cn = lane & 15;
  #pragma unroll
  for (int i = 0; i < 4; i++){
    #pragma unroll
    for (int n = 0; n < 4; n++){
      int col = col0 + (wn<<6) + (n<<4) + cn;
      float bi = bias ? bias[col] : 0.0f;
      int rowb = row0 + (wm<<6) + (i<<4) + (cq<<2);
      float vals[4];
      #pragma unroll
      for (int r = 0; r < 4; r++){
        float c = acc[i][n][r] + bi;
        if (act == 1) c = c > 0.0f ? c : 0.2f * c;
        else if (act == 2) c = c > 0.0f ? c : expf(c) - 1.0f;
        if (resid) c += resid[(size_t)(rowb + r) * Nc + col];
        vals[r] = c;
      }
      if (mode & 1){
        #pragma unroll
        for (int r = 0; r < 4; r++) C[(size_t)(rowb + r) * Nc + col] = vals[r];
      }
      if (mode & 2){
        #pragma unroll
        for (int r = 0; r < 4; r++) Cb[(size_t)(rowb + r) * Nc + col] = f2bf(vals[r]);
      }
      if (mode & 4){
        u16 t4[4] = {f2bf(vals[0]), f2bf(vals[1]), f2bf(vals[2]), f2bf(vals[3])};
        *(short4v*)&Ct[(size_t)col * Mtot + rowb] = *(short4v*)t4;
      }
    }
  }
}

// ---------- MFMA MHA attention (bf16 in/out, V transposed, LDS-staged bit mask) ----------
// Block: 256 threads = 4 waves, 32 q-rows of one (b,h). Q frags in registers.
// q,k: bf16 [B*L, 512]. vt: bf16 [512, B*Lk] (transposed). obf: bf16 out.
__global__ __launch_bounds__(256) void attn_mfma(
    const u16* __restrict__ q, const u16* __restrict__ k, const u16* __restrict__ vt,
    const u32* __restrict__ mbits, u16* __restrict__ obf, int Lq, int Lk)
{
  __shared__ __align__(16) u16 S[32][SPS];      // scores, then P (bf16)
  __shared__ __align__(16) u16 KVf[8*64*8];     // K^T / V B-fragments
  __shared__ u32 maskw[32*16];                  // mask words, row-major
  __shared__ float inv[32];

  int tid = threadIdx.x, lane = tid & 63, wave = tid >> 6;
  int wm = wave & 1, wn = wave >> 1;
  int q0 = blockIdx.x << 5, h = blockIdx.y, b = blockIdx.z;
  int ntiles = (Lk + 63) >> 6;
  size_t vM = (size_t)B_ * Lk;

  // stage mask bits (row bit-offsets are word-aligned: Lk in {512, 32})
  if (Lk == 512){
    #pragma unroll
    for (int r = 0; r < 2; r++){
      int x = tid + (r << 8);   // x = row*16 + wi
      maskw[x] = mbits[(((size_t)(b*Lq) + q0 + (x >> 4)) << 4) + (x & 15)];
    }
  } else {                       // Lk == 32
    if (tid < 32) maskw[tid << 4] = mbits[(size_t)(b*Lq) + q0 + tid];
  }

  // Q fragments in registers (wave wm covers rows q0+wm*16..+15)
  short8 aq[2];
  #pragma unroll
  for (int kt = 0; kt < 2; kt++)
    aq[kt] = *(const short8*)(q + ((size_t)(b*Lq + q0 + (wm<<4) + (lane & 15)))*512
                                + h*64 + (kt<<5) + ((lane >> 4) << 3));

  int cq = lane >> 4, cn = lane & 15;

  // ---- QK^T -> S (raw masked scores, bf16) ----
  for (int jt = 0; jt < (ntiles << 6); jt += 64){
    #pragma unroll
    for (int r = 0; r < 2; r++){
      int u = tid + (r << 8);
      int l = u & 63, unit = u >> 6;
      int kt = unit >> 2, nt = unit & 3;
      int key = jt + (nt<<4) + (l & 15);
      short8 val = {0,0,0,0,0,0,0,0};
      if (key < Lk)
        val = *(const short8*)(k + ((size_t)(b*Lk + key))*512 + h*64 + (kt<<5) + ((l >> 4) << 3));
      *(short8*)&KVf[(size_t)u * 8] = val;
    }
    __syncthreads();
    f32x4 accs[2] = {};
    #pragma unroll
    for (int kt = 0; kt < 2; kt++){
      #pragma unroll
      for (int ntl = 0; ntl < 2; ntl++){
        short8 bf = *(short8*)&KVf[((((kt<<2) + (wn<<1) + ntl)*64 + lane)) << 3];
        accs[ntl] = __builtin_amdgcn_mfma_f32_16x16x32_bf16(aq[kt], bf, accs[ntl], 0, 0, 0);
      }
    }
    int jb = jt + (wn<<5);
    if (jb < Lk){                                 // wave-uniform
      int wrd = (jt >> 5) + wn;
      #pragma unroll
      for (int r = 0; r < 4; r++){
        int srow = (wm<<4) + (cq<<2) + r;
        u32 mw = maskw[(srow << 4) + wrd];
        float e0 = ((mw >> cn) & 1u)        ? accs[0][r]*0.125f : -1.0e9f;
        float e1 = ((mw >> (16+cn)) & 1u)   ? accs[1][r]*0.125f : -1.0e9f;
        S[srow][jb + cn]      = f2bf(e0);
        S[srow][jb + 16 + cn] = f2bf(e1);
      }
    } else {                                      // padding keys -> -inf
      #pragma unroll
      for (int r = 0; r < 4; r++){
        int srow = (wm<<4) + (cq<<2) + r;
        S[srow][jb + cn]      = 0xFF80;
        S[srow][jb + 16 + cn] = 0xFF80;
      }
    }
    __syncthreads();
  }

  // ---- softmax (vectorized: each thread owns contiguous 64*ntiles/8 elems) ----
  {
    int row = tid >> 3, part = tid & 7;
    int CPT = ntiles;                    // short8 chunks per thread
    int base = part * (ntiles << 3);
    float mx = -3.0e38f;
    for (int c = 0; c < CPT; c++){
      int off = base + (((c + part) & (CPT - 1)) << 3);
      short8 sv = *(short8*)&S[row][off];
      #pragma unroll
      for (int jj = 0; jj < 8; jj++) mx = fmaxf(mx, bf2f((u16)sv[jj]));
    }
    #pragma unroll
    for (int m = 1; m < 8; m <<= 1) mx = fmaxf(mx, __shfl_xor(mx, m, 8));
    float sum = 0.0f;
    for (int c = 0; c < CPT; c++){
      int off = base + (((c + part) & (CPT - 1)) << 3);
      short8 sv = *(short8*)&S[row][off];
      u16 t8[8];
      #pragma unroll
      for (int jj = 0; jj < 8; jj++){
        float p = __expf(bf2f((u16)sv[jj]) - mx);
        sum += p;
        t8[jj] = f2bf(p);
      }
      *(short8*)&S[row][off] = *(short8*)t8;
    }
    #pragma unroll
    for (int m = 1; m < 8; m <<= 1) sum += __shfl_xor(sum, m, 8);
    if (part == 0) inv[row] = 1.0f / sum;
  }
  __syncthreads();

  // ---- PV (V read from transposed bf16: contiguous keys) ----
  f32x4 acco[2] = {};
  for (int jt = 0; jt < (ntiles << 6); jt += 64){
    #pragma unroll
    for (int r = 0; r < 2; r++){
      int u = tid + (r << 8);
      int l = u & 63, unit = u >> 6;
      int kt = unit >> 2, nt = unit & 3;
      int d  = (nt<<4) + (l & 15);
      int keyb = jt + (kt<<5) + ((l >> 4) << 3);
      short8 val = {0,0,0,0,0,0,0,0};
      if (keyb < Lk)
        val = *(const short8*)(vt + ((size_t)(h*64 + d))*vM + (size_t)b*Lk + keyb);
      *(short8*)&KVf[(size_t)u * 8] = val;
    }
    __syncthreads();
    #pragma unroll
    for (int kt = 0; kt < 2; kt++){
      short8 a = *(short8*)&S[(wm<<4) + (lane & 15)][jt + (kt<<5) + ((lane >> 4) << 3)];
      #pragma unroll
      for (int ntl = 0; ntl < 2; ntl++){
        short8 bf = *(short8*)&KVf[((((kt<<2) + (wn<<1) + ntl)*64 + lane)) << 3];
        acco[ntl] = __builtin_amdgcn_mfma_f32_16x16x32_bf16(a, bf, acco[ntl], 0, 0, 0);
      }
    }
    __syncthreads();
  }

  #pragma unroll
  for (int ntl = 0; ntl < 2; ntl++){
    int d = h*64 + (wn<<5) + (ntl<<4) + cn;
    #pragma unroll
    for (int r = 0; r < 4; r++){
      int srow = (wm<<4) + (cq<<2) + r;
      obf[((size_t)(b*Lq + q0 + srow))*512 + d] = f2bf(acco[ntl][r] * inv[srow]);
    }
  }
}

// ---------- GAT scores ----------
__global__ __launch_bounds__(256) void gat1_scores(const float* __restrict__ hall,
    const float* __restrict__ gata, float* __restrict__ s1, float* __restrict__ s2)
{
  int gw = blockIdx.x * 4 + (threadIdx.x >> 6);
  int lane = threadIdx.x & 63;
  int h = gw >> 13;
  int r = gw & 8191;
  float v = hall[(size_t)r * D_ + h * 64 + lane];
  float p1 = v * gata[h * 128 + lane];
  float p2 = v * gata[h * 128 + 64 + lane];
  #pragma unroll
  for (int o = 32; o; o >>= 1){ p1 += __shfl_down(p1, o, 64); p2 += __shfl_down(p2, o, 64); }
  if (lane == 0){ s1[h * 8192 + r] = p1; s2[h * 8192 + r] = p2; }
}
__global__ __launch_bounds__(256) void gat2_scores(const float* __restrict__ h2,
    const float* __restrict__ gatoa, float* __restrict__ s1, float* __restrict__ s2)
{
  int r = blockIdx.x * 4 + (threadIdx.x >> 6);
  int lane = threadIdx.x & 63;
  float p1 = 0.0f, p2 = 0.0f;
  for (int c = lane; c < D_; c += 64){
    float v = h2[(size_t)r * D_ + c];
    p1 += v * gatoa[c];
    p2 += v * gatoa[D_ + c];
  }
  #pragma unroll
  for (int o = 32; o; o >>= 1){ p1 += __shfl_down(p1, o, 64); p2 += __shfl_down(p2, o, 64); }
  if (lane == 0){ s1[r] = p1; s2[r] = p2; }
}

// ---------- MFMA GAT layer-1 attention (bf16 S/out, transposed bf16 hall) ----------
__global__ __launch_bounds__(256) void gat1_mfma(const u32* __restrict__ mbits,
    const float* __restrict__ s1, const float* __restrict__ s2,
    const u16* __restrict__ ht, u16* __restrict__ xcb)
{
  __shared__ __align__(16) u16 S[32][SPS];
  __shared__ __align__(16) u16 Vf[8*64*8];
  __shared__ float inv[32];

  int tid = threadIdx.x, lane = tid & 63, wave = tid >> 6;
  int wm = wave & 1, wn = wave >> 1;
  int q0 = blockIdx.x << 5, h = blockIdx.y, b = blockIdx.z;
  int hb = h * 8192 + b * 512;

  // scores: S = adj ? leaky(s1[q]+s2[j]) : -9e15
  for (int x = tid; x < 32*128; x += 256){
    int row = x >> 7, c4 = (x & 127) << 2;
    float s1v = s1[hb + q0 + row];
    float4 s2v = *(const float4*)(s2 + hb + c4);
    size_t bi = ((size_t)(b*512) + q0 + row)*512 + c4;
    u32 w = mbits[bi >> 5] >> (bi & 31);
    float t; u16 q4[4];
    t = s1v + s2v.x; t = t>0?t:0.2f*t; q4[0] = f2bf((w     & 1u) ? t : -9.0e15f);
    t = s1v + s2v.y; t = t>0?t:0.2f*t; q4[1] = f2bf(((w>>1) & 1u) ? t : -9.0e15f);
    t = s1v + s2v.z; t = t>0?t:0.2f*t; q4[2] = f2bf(((w>>2) & 1u) ? t : -9.0e15f);
    t = s1v + s2v.w; t = t>0?t:0.2f*t; q4[3] = f2bf(((w>>3) & 1u) ? t : -9.0e15f);
    *(short4v*)&S[row][c4] = *(short4v*)q4;
  }
  __syncthreads();

  // vectorized softmax (8 threads/row, contiguous 64-elem slices, rotated)
  {
    int row = tid >> 3, part = tid & 7;
    int base = part << 6;
    float mx = -3.0e38f;
    #pragma unroll
    for (int c = 0; c < 8; c++){
      int off = base + (((c + part) & 7) << 3);
      short8 sv = *(short8*)&S[row][off];
      #pragma unroll
      for (int jj = 0; jj < 8; jj++) mx = fmaxf(mx, bf2f((u16)sv[jj]));
    }
    #pragma unroll
    for (int m = 1; m < 8; m <<= 1) mx = fmaxf(mx, __shfl_xor(mx, m, 8));
    float sum = 0.0f;
    #pragma unroll
    for (int c = 0; c < 8; c++){
      int off = base + (((c + part) & 7) << 3);
      short8 sv = *(short8*)&S[row][off];
      u16 t8[8];
      #pragma unroll
      for (int jj = 0; jj < 8; jj++){
        float p = __expf(bf2f((u16)sv[jj]) - mx);
        sum += p;
        t8[jj] = f2bf(p);
      }
      *(short8*)&S[row][off] = *(short8*)t8;
    }
    #pragma unroll
    for (int m = 1; m < 8; m <<= 1) sum += __shfl_xor(sum, m, 8);
    if (part == 0) inv[row] = 1.0f / sum;
  }
  __syncthreads();

  f32x4 acco[2] = {};
  for (int jt = 0; jt < 512; jt += 64){
    #pragma unroll
    for (int r = 0; r < 2; r++){
      int u = tid + (r << 8);
      int l = u & 63, unit = u >> 6;
      int kt = unit >> 2, nt = unit & 3;
      int d  = (nt<<4) + (l & 15);
      int keyb = jt + (kt<<5) + ((l >> 4) << 3);
      *(short8*)&Vf[(size_t)u * 8] =
        *(const short8*)(ht + ((size_t)(h*64 + d))*(size_t)(B_*N_) + (size_t)b*512 + keyb);
    }
    __syncthreads();
    #pragma unroll
    for (int kt = 0; kt < 2; kt++){
      short8 a = *(short8*)&S[(wm<<4) + (lane & 15)][jt + (kt<<5) + ((lane >> 4) << 3)];
      #pragma unroll
      for (int ntl = 0; ntl < 2; ntl++){
        short8 bf = *(short8*)&Vf[((((kt<<2) + (wn<<1) + ntl)*64 + lane)) << 3];
        acco[ntl] = __builtin_amdgcn_mfma_f32_16x16x32_bf16(a, bf, acco[ntl], 0, 0, 0);
      }
    }
    __syncthreads();
  }

  int cq = lane >> 4, cn = lane & 15;
  #pragma unroll
  for (int ntl = 0; ntl < 2; ntl++){
    int d = h*64 + (wn<<5) + (ntl<<4) + cn;
    #pragma unroll
    for (int r = 0; r < 4; r++){
      int srow = (wm<<4) + (cq<<2) + r;
      float val = acco[ntl][r] * inv[srow];
      val = val > 0.0f ? val : expf(val) - 1.0f;
      xcb[((size_t)(b*512 + q0 + srow))*512 + d] = f2bf(val);
    }
  }
}

// ---------- GAT output-layer probabilities (bit-packed mask, bf16 P out) ----------
__global__ __launch_bounds__(256) void gat2_prob(const u32* __restrict__ mbits,
    const float* __restrict__ s1, const float* __restrict__ s2, u16* __restrict__ P)
{
  __shared__ float red[4];
  int r = blockIdx.x, tid = threadIdx.x;
  int b = r >> 9;
  float s1v = s1[r];
  float e0, e1;
  {
    size_t base = (size_t)r * 512;
    u32 w0 = mbits[(base + tid) >> 5];
    u32 w1 = mbits[(base + tid + 256) >> 5];
    float t = s1v + s2[b*512 + tid];       t = t>0?t:0.2f*t;
    e0 = ((w0 >> (tid & 31)) & 1u) ? t : -9.0e15f;
    t = s1v + s2[b*512 + tid + 256];       t = t>0?t:0.2f*t;
    e1 = ((w1 >> (tid & 31)) & 1u) ? t : -9.0e15f;
  }
  float mx = block_max(fmaxf(e0, e1), red);
  float p0 = __expf(e0 - mx), p1 = __expf(e1 - mx);
  float s = block_sum(p0 + p1, red);
  float inv = 1.0f / s;
  P[(size_t)r*512 + tid]       = f2bf(p0 * inv);
  P[(size_t)r*512 + tid + 256] = f2bf(p1 * inv);
}

// ---------- LayerNorm ----------
__global__ __launch_bounds__(256) void ln_k(const float* __restrict__ in,
    const float* __restrict__ g, const float* __restrict__ bta, float* __restrict__ out)
{
  __shared__ float red[4];
  int r = blockIdx.x, tid = threadIdx.x;
  const float* x = in + (size_t)r * D_;
  float v0 = x[tid], v1 = x[tid + 256];
  float mu = block_sum(v0 + v1, red) * (1.0f / 512.0f);
  float d0 = v0 - mu, d1 = v1 - mu;
  float var = block_sum(d0 * d0 + d1 * d1, red) * (1.0f / 512.0f);
  float inv = 1.0f / sqrtf(var + 1e-6f);
  out[(size_t)r * D_ + tid]       = d0 * inv * g[tid]       + bta[tid];
  out[(size_t)r * D_ + tid + 256] = d1 * inv * g[tid + 256] + bta[tid + 256];
}

// ---------- host-side MHA helper ----------
static void run_mha(hipStream_t st, const float* q_in, int Lq, const float* kv_in, int Lk,
                    const u32* mbits, const u16* w, const float* g, const float* bt,
                    u16* qbf, u16* kbf, u16* vtb, u16* obf, float* tmp, float* out)
{
  dim3 blk(256);
  int Mq = B_*Lq, Mk = B_*Lk;
  gemm_mfma<<<dim3(4, Mq/128), blk, 0, st>>>(q_in, nullptr, w + (size_t)0*DD, nullptr, nullptr,
      nullptr, qbf, nullptr, Mq, D_, 0, 2, 0,0,0,0);
  gemm_mfma<<<dim3(4, Mk/128), blk, 0, st>>>(kv_in, nullptr, w + (size_t)1*DD, nullptr, nullptr,
      nullptr, kbf, nullptr, Mk, D_, 0, 2, 0,0,0,0);
  gemm_mfma<<<dim3(4, Mk/128), blk, 0, st>>>(kv_in, nullptr, w + (size_t)2*DD, nullptr, nullptr,
      nullptr, nullptr, vtb, Mk, D_, 0, 4, 0,0,0,0);
  attn_mfma<<<dim3(Lq/32, NH_, B_), blk, 0, st>>>(qbf, kbf, vtb, mbits, obf, Lq, Lk);
  gemm_mfma<<<dim3(4, Mq/128), blk, 0, st>>>(nullptr, obf, w + (size_t)3*DD, nullptr, q_in,
      tmp, nullptr, nullptr, Mq, D_, 0, 1, 0,0,0,0);
  ln_k<<<dim3(Mq), blk, 0, st>>>(tmp, g, bt, out);
}

extern "C" void kernel_launch(void* const* d_in, const int* in_sizes, int n_in,
                              void* d_out, int out_size, void* d_ws, size_t ws_size,
                              hipStream_t stream) {
  (void)in_sizes; (void)n_in; (void)out_size; (void)ws_size;

  const float* xf    = (const float*)d_in[0];
  const int* adj_i   = (const int*)d_in[2];
  const int* adj_s   = (const int*)d_in[3];
  const int* adj_is  = (const int*)d_in[4];
  const int* adj_si  = (const int*)d_in[5];
  const float* intent= (const float*)d_in[6];
  const float* gatW  = (const float*)d_in[7];
  const float* gata  = (const float*)d_in[8];
  const float* gatoW = (const float*)d_in[9];
  const float* gatoa = (const float*)d_in[10];
  const float* mhaw  = (const float*)d_in[11];
  const float* lng   = (const float*)d_in[12];
  const float* lnb   = (const float*)d_in[13];
  const float* linW1 = (const float*)d_in[14];
  const float* linb1 = (const float*)d_in[15];
  const float* linW2 = (const float*)d_in[16];
  const float* linb2 = (const float*)d_in[17];

  float* out0 = (float*)d_out;                   // slot_out      [B,N,D]
  float* out1 = out0 + BND;                      // slot_logits   [B,N,OUT]
  float* out2 = out1 + (size_t)B_*N_*OUT_;       // slot_graph_out[B,N,D]

  // ---- workspace carve (~130 MB) ----
  float* Q    = (float*)d_ws;      // BND x6
  float* K    = Q   + BND;
  float* V    = K   + BND;
  float* O    = V   + BND;
  float* TMP  = O   + BND;
  float* HB1  = TMP + BND;
  float* ha0  = HB1 + BND;         // BID x9
  float* ha1  = ha0 + BID;
  float* ta   = ha1 + BID;
  float* tb   = ta  + BID;
  float* sqa  = tb  + BID;
  float* ska  = sqa + BID;
  float* sva  = ska + BID;
  float* soa  = sva + BID;
  float* stmp = soa + BID;
  float* s1   = stmp+ BID;         // 65536 x2
  float* s2   = s1  + 65536;
  float* s1o  = s2  + 65536;       // 8192 x2
  float* s2o  = s1o + 8192;
  u16* Wm  = (u16*)(s2o + 8192);   // 32*DD bf16 (all mhaw mats, swizzled)
  u16* Wg  = Wm  + (size_t)32*DD;  // gat Wcat swizzled
  u16* Wgo = Wg  + DD;             // gat_out_W swizzled
  u16* W1s = Wgo + DD;             // lin_W1 swizzled
  u16* W2s = W1s + DD;             // lin_W2 swizzled (512x128 -> DD/4)
  u32* pm_s  = (u32*)(W2s + DD/4); // adj_s  packed
  u32* pm_i  = pm_s + 131072;
  u32* pm_is = pm_i + 512;
  u32* pm_si = pm_is + 8192;

  // bf16 overlays on dead fp32 scratch (all uses stream-ordered):
  u16* qbf = (u16*)V;              // V fp32 only used in GAT phase
  u16* kbf = (u16*)V + BND;
  u16* vtb = (u16*)TMP;            // clobbered by out-proj AFTER attn reads it
  u16* obf = (u16*)O;              // attn bf16 output; O fp32 dead
  u16* htb = (u16*)O;              // GAT phase reuse (obf dead by then)
  u16* xcb = (u16*)K;              // gat1 bf16 output (K dead after MHA)
  u16* zb  = (u16*)Q;              // logits intermediate bf16
  u16* Pb  = (u16*)HB1;            // gat2 P bf16

  dim3 blk(256);

  // ---- mask packing ----
  pack_mask_k<<<(B_*N_*N_)/256,   blk, 0, stream>>>(adj_s,  pm_s);
  pack_mask_k<<<(B_*NI_*NI_)/256, blk, 0, stream>>>(adj_i,  pm_i);
  pack_mask_k<<<(B_*N_*NI_)/256,  blk, 0, stream>>>(adj_is, pm_is);
  pack_mask_k<<<(B_*NI_*N_)/256,  blk, 0, stream>>>(adj_si, pm_si);

  // ---- weight prep ----
  swz_k<<<dim3(128, 32), blk, 0, stream>>>(mhaw,  Wm,  D_,   DD, DD);
  swz_gatW_k<<<128, blk, 0, stream>>>(gatW, Wg);
  swz_k<<<dim3(128, 1), blk, 0, stream>>>(gatoW, Wgo, D_,   0, 0);
  swz_k<<<dim3(128, 1), blk, 0, stream>>>(linW1, W1s, D_,   0, 0);
  swz_k<<<dim3(32,  1), blk, 0, stream>>>(linW2, W2s, OUT_, 0, 0);

  // ================= MHA stack =================
  bcast_k<<<BID/256, blk, 0, stream>>>(intent, ha0, BID);

  // ---- layer 0 (h_b = xf, h_a = ha0) ----
  run_mha(stream, ha0, NI_, ha0, NI_, pm_i,  Wm +  (size_t)0*DD, lng + 0*D_, lnb + 0*D_,
          qbf, kbf, vtb, obf, stmp, ta);                                   // a2a -> ta
  run_mha(stream, ha0, NI_, xf,  N_,  pm_si, Wm + (size_t)12*DD, lng + 3*D_, lnb + 3*D_,
          qbf, kbf, vtb, obf, stmp, tb);                                   // b2a -> tb
  add_relu_k<<<BID/256, blk, 0, stream>>>(ta, tb, ha1, BID);               // h_a1
  run_mha(stream, xf, N_, xf, N_, pm_s,  Wm +  (size_t)4*DD, lng + 1*D_, lnb + 1*D_,
          qbf, kbf, vtb, obf, TMP, HB1);                                   // b2b -> HB1
  run_mha(stream, xf, N_, ha0, NI_, pm_is, Wm + (size_t)8*DD, lng + 2*D_, lnb + 2*D_,
          qbf, kbf, vtb, obf, TMP, Q);                                     // a2b -> Q
  add_relu_ip_k<<<BND/256, blk, 0, stream>>>(HB1, Q, BND);                 // h_b1

  // ---- layer 1 (h_b = HB1, h_a = ha1); a2a/b2a dead ----
  run_mha(stream, HB1, N_, HB1, N_, pm_s,  Wm + (size_t)20*DD, lng + 5*D_, lnb + 5*D_,
          qbf, kbf, vtb, obf, TMP, K);                                     // b2b -> K
  run_mha(stream, HB1, N_, ha1, NI_, pm_is, Wm + (size_t)24*DD, lng + 6*D_, lnb + 6*D_,
          qbf, kbf, vtb, obf, TMP, Q);                                     // a2b -> Q
  add_relu_ip_k<<<BND/256, blk, 0, stream>>>(K, Q, BND);                   // h_b2 in K

  // ---- slot_out = x + h_b2 ----
  add_k<<<BND/256, blk, 0, stream>>>(xf, K, out0, BND);
  // ---- logits (bf16 intermediate) ----
  gemm_mfma<<<dim3(4, (B_*N_)/128), blk, 0, stream>>>(out0, nullptr, W1s, linb1, nullptr,
      nullptr, zb, nullptr, 0, D_, 1, 2, 0,0,0,0);
  gemm_mfma<<<dim3(1, (B_*N_)/128), blk, 0, stream>>>(nullptr, zb, W2s, linb2, nullptr,
      out1, nullptr, nullptr, 0, OUT_, 0, 1, 0,0,0,0);

  // ================= GAT branch =================
  // h_all -> Q (fp32) + htb (bf16 transposed, for gat1 PV)
  gemm_mfma<<<dim3(4, (B_*N_)/128), blk, 0, stream>>>(xf, nullptr, Wg, nullptr, nullptr,
      Q, nullptr, htb, B_*N_, D_, 0, 5, 0,0,0,0);
  gat1_scores<<<(H_*B_*N_)/4, blk, 0, stream>>>(Q, gata, s1, s2);
  gat1_mfma<<<dim3(N_/32, H_, B_), blk, 0, stream>>>(pm_s, s1, s2, htb, xcb);
  gemm_mfma<<<dim3(4, (B_*N_)/128), blk, 0, stream>>>(nullptr, xcb, Wgo, nullptr, nullptr,
      V /*h2*/, nullptr, nullptr, 0, D_, 0, 1, 0,0,0,0);
  gat2_scores<<<(B_*N_)/4, blk, 0, stream>>>(V, gatoa, s1o, s2o);
  gat2_prob<<<B_*N_, blk, 0, stream>>>(pm_s, s1o, s2o, Pb);
  // out2 = elu(P @ h2) + x : swizzle runtime h2 per batch into O (u16), batched MFMA GEMM
  swz_k<<<dim3(128, B_), blk, 0, stream>>>(V, (u16*)O, D_, (size_t)N_*D_, (size_t)DD);
  gemm_mfma<<<dim3(4, N_/128, B_), blk, 0, stream>>>(nullptr, Pb, (u16*)O, nullptr, xf,
      out2, nullptr, nullptr, 0, D_, 2, 1,
      (size_t)N_*N_, (size_t)DD, (size_t)N_*D_, (size_t)N_*D_);
}

// Round 8
// 864.612 us; speedup vs baseline: 1.7132x; 1.3807x over previous
//
#include <hip/hip_runtime.h>

// B=16, N=512, D=512, NI=32, GH=64, H=8, L=2, OUT=128, heads=8
#define B_   16
#define N_   512
#define D_   512
#define NI_  32
#define GH_  64
#define H_   8
#define OUT_ 128
#define NH_  8

#define BND   (B_*N_*D_)     // 4194304
#define BID   (B_*NI_*D_)    // 262144
#define DD    (D_*D_)        // 262144

#define SPS 520              // S row stride in bf16 (row*520*2B: 16B aligned; 4-row step = 16 banks apart)

typedef unsigned short u16;
typedef unsigned int   u32;
typedef __attribute__((ext_vector_type(8))) short short8;
typedef __attribute__((ext_vector_type(4))) short short4v;
typedef __attribute__((ext_vector_type(4))) float f32x4;

__device__ __forceinline__ u16 f2bf(float f){
  u32 x = __float_as_uint(f);
  x += 0x7fffu + ((x >> 16) & 1u);   // RNE
  return (u16)(x >> 16);
}
__device__ __forceinline__ float bf2f(u16 s){
  return __uint_as_float((u32)s << 16);
}

// blockDim must be 256
__device__ __forceinline__ float block_sum(float v, float* sm){
  #pragma unroll
  for (int o = 32; o; o >>= 1) v += __shfl_down(v, o, 64);
  int lane = threadIdx.x & 63, w = threadIdx.x >> 6;
  __syncthreads();
  if (lane == 0) sm[w] = v;
  __syncthreads();
  return sm[0] + sm[1] + sm[2] + sm[3];
}
__device__ __forceinline__ float block_max(float v, float* sm){
  #pragma unroll
  for (int o = 32; o; o >>= 1) v = fmaxf(v, __shfl_down(v, o, 64));
  int lane = threadIdx.x & 63, w = threadIdx.x >> 6;
  __syncthreads();
  if (lane == 0) sm[w] = v;
  __syncthreads();
  return fmaxf(fmaxf(sm[0], sm[1]), fmaxf(sm[2], sm[3]));
}
__device__ __forceinline__ float2 block_red2(float a, float b, float2* sm){
  #pragma unroll
  for (int o = 32; o; o >>= 1){ a += __shfl_down(a, o, 64); b += __shfl_down(b, o, 64); }
  int lane = threadIdx.x & 63, w = threadIdx.x >> 6;
  __syncthreads();
  if (lane == 0) sm[w] = make_float2(a, b);
  __syncthreads();
  float2 r;
  r.x = sm[0].x + sm[1].x + sm[2].x + sm[3].x;
  r.y = sm[0].y + sm[1].y + sm[2].y + sm[3].y;
  return r;
}

// ---------- mask bit-pack (adj>0 -> 1 bit) ----------
__global__ __launch_bounds__(256) void pack_mask_k(const int* __restrict__ adj, u32* __restrict__ bits){
  int i = blockIdx.x * 256 + threadIdx.x;
  unsigned long long m = __ballot(adj[i] > 0);
  if ((threadIdx.x & 63) == 0){
    bits[(i >> 5)]     = (u32)m;
    bits[(i >> 5) + 1] = (u32)(m >> 32);
  }
}

// ---------- elementwise ----------
__global__ __launch_bounds__(256) void bcast_k(const float* __restrict__ s, float* __restrict__ d, int n){
  int i = blockIdx.x * 256 + threadIdx.x;
  if (i < n) d[i] = s[i & (NI_*D_ - 1)];
}

// ---------- weight swizzle into MFMA B-fragment order ----------
__global__ __launch_bounds__(256) void swz_k(const float* __restrict__ W, u16* __restrict__ o,
                                             int Nc, size_t sW, size_t sO){
  int gw = blockIdx.x * 4 + (threadIdx.x >> 6);
  int lane = threadIdx.x & 63;
  int ntc = Nc >> 4;
  int s = gw / ntc, nt = gw - s * ntc;
  const float* Wb = W + sW * blockIdx.y;
  u16* ob = o + sO * blockIdx.y;
  int n = nt*16 + (lane & 15);
  int kb = s*32 + ((lane >> 4) << 3);
  u16 t8[8];
  #pragma unroll
  for (int j = 0; j < 8; j++) t8[j] = f2bf(Wb[(size_t)(kb + j) * Nc + n]);
  *(short8*)&ob[((size_t)(s * ntc + nt) * 64 + lane) * 8] = *(short8*)t8;
}
// gat_W [H,D,GH] -> head-major-concat [D,512], swizzled
__global__ __launch_bounds__(256) void swz_gatW_k(const float* __restrict__ gw_, u16* __restrict__ o){
  int gw = blockIdx.x * 4 + (threadIdx.x >> 6);  // 512 waves
  int lane = threadIdx.x & 63;
  int s = gw >> 5, nt = gw & 31;
  int n = nt*16 + (lane & 15);
  int h = n >> 6, f = n & 63;
  int kb = s*32 + ((lane >> 4) << 3);
  u16 t8[8];
  #pragma unroll
  for (int j = 0; j < 8; j++) t8[j] = f2bf(gw_[((size_t)(h*512) + kb + j) * 64 + f]);
  *(short8*)&o[((size_t)(s*32 + nt) * 64 + lane) * 8] = *(short8*)t8;
}

// ---------- MFMA GEMM (register-prefetch double-buffered) ----------
// A source: fp32 A or bf16 Ab (one non-null). K = 512 fixed.
// C modes (bitmask): 1 = fp32 C[M,Nc]; 2 = bf16 Cb[M,Nc]; 4 = bf16 transposed Cx[Nc,Mtot];
//                    8 = bf16 B-fragment order Cx (batched per row>>9, Nc must be 512).
// act: 0 none, 1 leaky, 2 elu. Batched over blockIdx.z via strides.
__global__ __launch_bounds__(256) void gemm_mfma(
    const float* __restrict__ A, const u16* __restrict__ Ab, const u16* __restrict__ Bw,
    const float* __restrict__ bias, const float* __restrict__ resid,
    float* __restrict__ C, u16* __restrict__ Cb, u16* __restrict__ Cx,
    int Mtot, int Nc, int act, int mode,
    size_t sA, size_t sB, size_t sC, size_t sR)
{
  __shared__ __align__(16) u16 As[128*64];
  __shared__ __align__(16) u16 Bs[64*128];
  if (A)  A  += sA * blockIdx.z;
  if (Ab) Ab += sA * blockIdx.z;
  Bw += sB * blockIdx.z;
  if (C) C += sC * blockIdx.z;
  if (resid) resid += sR * blockIdx.z;

  int tid = threadIdx.x, lane = tid & 63, wave = tid >> 6;
  int wm = wave & 1, wn = wave >> 1;
  int row0 = blockIdx.y << 7, col0 = blockIdx.x << 7;
  int ntc = Nc >> 4, nt0 = col0 >> 4;

  // per-unit source bases
  const float* aSrcF[4];
  const u16*   aSrcB[4];
  #pragma unroll
  for (int r = 0; r < 4; r++){
    int u = tid + (r << 8);
    int l = u & 63, kt = (u >> 6) & 1, mt = u >> 7;
    size_t off = (size_t)(row0 + (mt << 4) + (l & 15)) * 512 + (kt << 5) + ((l >> 4) << 3);
    aSrcF[r] = A  ? A  + off : nullptr;
    aSrcB[r] = Ab ? Ab + off : nullptr;
  }
  const u16* bSrc[2][2];
  #pragma unroll
  for (int kt = 0; kt < 2; kt++)
    #pragma unroll
    for (int r = 0; r < 2; r++)
      bSrc[kt][r] = Bw + (((size_t)(kt * ntc + nt0)) << 9) + (((size_t)(tid + (r << 8))) << 3);
  size_t bStep = (size_t)ntc << 10;   // u16s per ks (2*ntc*512)

  float4 aF[4][2];
  short8 aB[4];
  short8 bP[2][2];

  auto doLoad = [&](int ks){
    if (Ab){
      #pragma unroll
      for (int r = 0; r < 4; r++) aB[r] = *(const short8*)(aSrcB[r] + (ks << 6));
    } else {
      #pragma unroll
      for (int r = 0; r < 4; r++){
        aF[r][0] = *(const float4*)(aSrcF[r] + (ks << 6));
        aF[r][1] = *(const float4*)(aSrcF[r] + (ks << 6) + 4);
      }
    }
    #pragma unroll
    for (int kt = 0; kt < 2; kt++)
      #pragma unroll
      for (int r = 0; r < 2; r++)
        bP[kt][r] = *(const short8*)(bSrc[kt][r] + (size_t)ks * bStep);
  };

  f32x4 acc[4][4] = {};
  doLoad(0);
  for (int ks = 0; ks < 8; ks++){
    if (Ab){
      #pragma unroll
      for (int r = 0; r < 4; r++) *(short8*)&As[(size_t)(tid + (r<<8)) * 8] = aB[r];
    } else {
      #pragma unroll
      for (int r = 0; r < 4; r++){
        u16 t8[8] = {f2bf(aF[r][0].x), f2bf(aF[r][0].y), f2bf(aF[r][0].z), f2bf(aF[r][0].w),
                     f2bf(aF[r][1].x), f2bf(aF[r][1].y), f2bf(aF[r][1].z), f2bf(aF[r][1].w)};
        *(short8*)&As[(size_t)(tid + (r<<8)) * 8] = *(short8*)t8;
      }
    }
    #pragma unroll
    for (int kt = 0; kt < 2; kt++)
      #pragma unroll
      for (int r = 0; r < 2; r++)
        *(short8*)&Bs[(kt << 12) + ((size_t)(tid + (r<<8)) << 3)] = bP[kt][r];
    __syncthreads();
    if (ks < 7) doLoad(ks + 1);
    #pragma unroll
    for (int kt = 0; kt < 2; kt++){
      short8 a[4], b[4];
      #pragma unroll
      for (int i = 0; i < 4; i++)
        a[i] = *(short8*)&As[(((((wm<<2)+i) << 1) + kt) * 64 + lane) << 3];
      #pragma unroll
      for (int n = 0; n < 4; n++)
        b[n] = *(short8*)&Bs[(((kt << 3) + (wn<<2) + n) * 64 + lane) << 3];
      #pragma unroll
      for (int i = 0; i < 4; i++)
        #pragma unroll
        for (int n = 0; n < 4; n++)
          acc[i][n] = __builtin_amdgcn_mfma_f32_16x16x32_bf16(a[i], b[n], acc[i][n], 0, 0, 0);
    }
    __syncthreads();
  }

  int cq = lane >> 4, cn = lane & 15;
  #pragma unroll
  for (int i = 0; i < 4; i++){
    #pragma unroll
    for (int n = 0; n < 4; n++){
      int col = col0 + (wn<<6) + (n<<4) + cn;
      float bi = bias ? bias[col] : 0.0f;
      int rowb = row0 + (wm<<6) + (i<<4) + (cq<<2);
      float vals[4];
      #pragma unroll
      for (int r = 0; r < 4; r++){
        float c = acc[i][n][r] + bi;
        if (act == 1) c = c > 0.0f ? c : 0.2f * c;
        else if (act == 2) c = c > 0.0f ? c : expf(c) - 1.0f;
        if (resid) c += resid[(size_t)(rowb + r) * Nc + col];
        vals[r] = c;
      }
      if (mode & 1){
        #pragma unroll
        for (int r = 0; r < 4; r++) C[(size_t)(rowb + r) * Nc + col] = vals[r];
      }
      if (mode & 2){
        #pragma unroll
        for (int r = 0; r < 4; r++) Cb[(size_t)(rowb + r) * Nc + col] = f2bf(vals[r]);
      }
      if (mode & 4){
        u16 t4[4] = {f2bf(vals[0]), f2bf(vals[1]), f2bf(vals[2]), f2bf(vals[3])};
        *(short4v*)&Cx[(size_t)col * Mtot + rowb] = *(short4v*)t4;
      }
      if (mode & 8){
        u16 t4[4] = {f2bf(vals[0]), f2bf(vals[1]), f2bf(vals[2]), f2bf(vals[3])};
        int kk = rowb & 511;
        int ln_ = (((kk >> 3) & 3) << 4) | (col & 15);
        size_t off = (size_t)(rowb >> 9) * DD
                   + ((((size_t)(kk >> 5) * 32 + ((col & 511) >> 4)) * 64 + ln_) << 3) + (kk & 7);
        *(short4v*)&Cx[off] = *(short4v*)t4;
      }
    }
  }
}

// ---------- fused projection GEMM: sel = blockIdx.x>>2 picks weight matrix ----------
// Writes: m==0 -> qb bf16 row-major; m==1 -> kb bf16 row-major; m==2 -> vt bf16 transposed [512][Mtot].
__global__ __launch_bounds__(256) void proj_fused(
    const float* __restrict__ A, const u16* __restrict__ Wbase, int mat0,
    u16* __restrict__ qb, u16* __restrict__ kb, u16* __restrict__ vt, int Mtot)
{
  __shared__ __align__(16) u16 As[128*64];
  __shared__ __align__(16) u16 Bs[64*128];
  int tid = threadIdx.x, lane = tid & 63, wave = tid >> 6;
  int wm = wave & 1, wn = wave >> 1;
  int sel = blockIdx.x >> 2;
  int row0 = blockIdx.y << 7, col0 = (blockIdx.x & 3) << 7;
  const u16* Bw = Wbase + (size_t)sel * DD;
  int nt0 = col0 >> 4;                      // ntc = 32

  const float* aSrcF[4];
  #pragma unroll
  for (int r = 0; r < 4; r++){
    int u = tid + (r << 8);
    int l = u & 63, kt = (u >> 6) & 1, mt = u >> 7;
    aSrcF[r] = A + (size_t)(row0 + (mt << 4) + (l & 15)) * 512 + (kt << 5) + ((l >> 4) << 3);
  }
  const u16* bSrc[2][2];
  #pragma unroll
  for (int kt = 0; kt < 2; kt++)
    #pragma unroll
    for (int r = 0; r < 2; r++)
      bSrc[kt][r] = Bw + (((size_t)(kt * 32 + nt0)) << 9) + (((size_t)(tid + (r << 8))) << 3);

  float4 aF[4][2];
  short8 bP[2][2];
  auto doLoad = [&](int ks){
    #pragma unroll
    for (int r = 0; r < 4; r++){
      aF[r][0] = *(const float4*)(aSrcF[r] + (ks << 6));
      aF[r][1] = *(const float4*)(aSrcF[r] + (ks << 6) + 4);
    }
    #pragma unroll
    for (int kt = 0; kt < 2; kt++)
      #pragma unroll
      for (int r = 0; r < 2; r++)
        bP[kt][r] = *(const short8*)(bSrc[kt][r] + ((size_t)ks << 15));   // 32<<10 per ks
  };

  f32x4 acc[4][4] = {};
  doLoad(0);
  for (int ks = 0; ks < 8; ks++){
    #pragma unroll
    for (int r = 0; r < 4; r++){
      u16 t8[8] = {f2bf(aF[r][0].x), f2bf(aF[r][0].y), f2bf(aF[r][0].z), f2bf(aF[r][0].w),
                   f2bf(aF[r][1].x), f2bf(aF[r][1].y), f2bf(aF[r][1].z), f2bf(aF[r][1].w)};
      *(short8*)&As[(size_t)(tid + (r<<8)) * 8] = *(short8*)t8;
    }
    #pragma unroll
    for (int kt = 0; kt < 2; kt++)
      #pragma unroll
      for (int r = 0; r < 2; r++)
        *(short8*)&Bs[(kt << 12) + ((size_t)(tid + (r<<8)) << 3)] = bP[kt][r];
    __syncthreads();
    if (ks < 7) doLoad(ks + 1);
    #pragma unroll
    for (int kt = 0; kt < 2; kt++){
      short8 a[4], b[4];
      #pragma unroll
      for (int i = 0; i < 4; i++)
        a[i] = *(short8*)&As[(((((wm<<2)+i) << 1) + kt) * 64 + lane) << 3];
      #pragma unroll
      for (int n = 0; n < 4; n++)
        b[n] = *(short8*)&Bs[(((kt << 3) + (wn<<2) + n) * 64 + lane) << 3];
      #pragma unroll
      for (int i = 0; i < 4; i++)
        #pragma unroll
        for (int n = 0; n < 4; n++)
          acc[i][n] = __builtin_amdgcn_mfma_f32_16x16x32_bf16(a[i], b[n], acc[i][n], 0, 0, 0);
    }
    __syncthreads();
  }

  int cq = lane >> 4, cn = lane & 15;
  int m = mat0 + sel;
  #pragma unroll
  for (int i = 0; i < 4; i++){
    #pragma unroll
    for (int n = 0; n < 4; n++){
      int col = col0 + (wn<<6) + (n<<4) + cn;
      int rowb = row0 + (wm<<6) + (i<<4) + (cq<<2);
      if (m == 0){
        #pragma unroll
        for (int r = 0; r < 4; r++) qb[(size_t)(rowb + r) * 512 + col] = f2bf(acc[i][n][r]);
      } else if (m == 1){
        #pragma unroll
        for (int r = 0; r < 4; r++) kb[(size_t)(rowb + r) * 512 + col] = f2bf(acc[i][n][r]);
      } else {
        u16 t4[4] = {f2bf(acc[i][n][0]), f2bf(acc[i][n][1]), f2bf(acc[i][n][2]), f2bf(acc[i][n][3])};
        *(short4v*)&vt[(size_t)col * Mtot + rowb] = *(short4v*)t4;
      }
    }
  }
}

// ---------- MFMA MHA attention (bf16 in/out, V transposed, LDS mask, reg prefetch) ----------
__global__ __launch_bounds__(256) void attn_mfma(
    const u16* __restrict__ q, const u16* __restrict__ k, const u16* __restrict__ vt,
    const u32* __restrict__ mbits, u16* __restrict__ obf, int Lq, int Lk)
{
  __shared__ __align__(16) u16 S[32][SPS];      // scores, then P (bf16)
  __shared__ __align__(16) u16 KVf[8*64*8];     // K^T / V B-fragments
  __shared__ u32 maskw[32*16];
  __shared__ float inv[32];

  int tid = threadIdx.x, lane = tid & 63, wave = tid >> 6;
  int wm = wave & 1, wn = wave >> 1;
  int q0 = blockIdx.x << 5, h = blockIdx.y, b = blockIdx.z;
  int ntiles = (Lk + 63) >> 6;
  size_t vM = (size_t)B_ * Lk;

  // stage mask bits (row bit-offsets are word-aligned: Lk in {512, 32})
  if (Lk == 512){
    #pragma unroll
    for (int r = 0; r < 2; r++){
      int x = tid + (r << 8);
      maskw[x] = mbits[(((size_t)(b*Lq) + q0 + (x >> 4)) << 4) + (x & 15)];
    }
  } else {
    if (tid < 32) maskw[tid << 4] = mbits[(size_t)(b*Lq) + q0 + tid];
  }

  // Q fragments in registers
  short8 aq[2];
  #pragma unroll
  for (int kt = 0; kt < 2; kt++)
    aq[kt] = *(const short8*)(q + ((size_t)(b*Lq + q0 + (wm<<4) + (lane & 15)))*512
                                + h*64 + (kt<<5) + ((lane >> 4) << 3));

  int cq = lane >> 4, cn = lane & 15;

  // K prefetch setup
  int keyOff[2]; const u16* kSrc[2];
  int keybOff[2]; const u16* vSrc[2];
  #pragma unroll
  for (int r = 0; r < 2; r++){
    int u = tid + (r << 8);
    int l = u & 63, unit = u >> 6;
    int kt = unit >> 2, nt = unit & 3;
    keyOff[r] = (nt<<4) + (l & 15);
    kSrc[r] = k + ((size_t)(b*Lk + keyOff[r]))*512 + h*64 + (kt<<5) + ((l >> 4) << 3);
    int d = (nt<<4) + (l & 15);
    keybOff[r] = (kt<<5) + ((l >> 4) << 3);
    vSrc[r] = vt + ((size_t)(h*64 + d))*vM + (size_t)b*Lk + keybOff[r];
  }
  short8 kR[2], vR[2];
  auto loadK = [&](int jt){
    #pragma unroll
    for (int r = 0; r < 2; r++){
      short8 val = {0,0,0,0,0,0,0,0};
      if (jt + keyOff[r] < Lk) val = *(const short8*)(kSrc[r] + (size_t)jt * 512);
      kR[r] = val;
    }
  };
  auto loadV = [&](int jt){
    #pragma unroll
    for (int r = 0; r < 2; r++){
      short8 val = {0,0,0,0,0,0,0,0};
      if (jt + keybOff[r] < Lk) val = *(const short8*)(vSrc[r] + jt);
      vR[r] = val;
    }
  };

  // ---- QK^T -> S ----
  loadK(0);
  for (int jt = 0; jt < (ntiles << 6); jt += 64){
    #pragma unroll
    for (int r = 0; r < 2; r++) *(short8*)&KVf[(size_t)(tid + (r<<8)) * 8] = kR[r];
    __syncthreads();
    if (jt + 64 < (ntiles << 6)) loadK(jt + 64);
    f32x4 accs[2] = {};
    #pragma unroll
    for (int kt = 0; kt < 2; kt++){
      #pragma unroll
      for (int ntl = 0; ntl < 2; ntl++){
        short8 bf = *(short8*)&KVf[((((kt<<2) + (wn<<1) + ntl)*64 + lane)) << 3];
        accs[ntl] = __builtin_amdgcn_mfma_f32_16x16x32_bf16(aq[kt], bf, accs[ntl], 0, 0, 0);
      }
    }
    int jb = jt + (wn<<5);
    if (jb < Lk){
      int wrd = (jt >> 5) + wn;
      #pragma unroll
      for (int r = 0; r < 4; r++){
        int srow = (wm<<4) + (cq<<2) + r;
        u32 mw = maskw[(srow << 4) + wrd];
        float e0 = ((mw >> cn) & 1u)      ? accs[0][r]*0.125f : -1.0e9f;
        float e1 = ((mw >> (16+cn)) & 1u) ? accs[1][r]*0.125f : -1.0e9f;
        S[srow][jb + cn]      = f2bf(e0);
        S[srow][jb + 16 + cn] = f2bf(e1);
      }
    } else {
      #pragma unroll
      for (int r = 0; r < 4; r++){
        int srow = (wm<<4) + (cq<<2) + r;
        S[srow][jb + cn]      = 0xFF80;
        S[srow][jb + 16 + cn] = 0xFF80;
      }
    }
    __syncthreads();
  }

  loadV(0);   // V tile 0 latency hides under softmax

  // ---- softmax (vectorized) ----
  {
    int row = tid >> 3, part = tid & 7;
    int CPT = ntiles;
    int base = part * (ntiles << 3);
    float mx = -3.0e38f;
    for (int c = 0; c < CPT; c++){
      int off = base + (((c + part) & (CPT - 1)) << 3);
      short8 sv = *(short8*)&S[row][off];
      #pragma unroll
      for (int jj = 0; jj < 8; jj++) mx = fmaxf(mx, bf2f((u16)sv[jj]));
    }
    #pragma unroll
    for (int m = 1; m < 8; m <<= 1) mx = fmaxf(mx, __shfl_xor(mx, m, 8));
    float sum = 0.0f;
    for (int c = 0; c < CPT; c++){
      int off = base + (((c + part) & (CPT - 1)) << 3);
      short8 sv = *(short8*)&S[row][off];
      u16 t8[8];
      #pragma unroll
      for (int jj = 0; jj < 8; jj++){
        float p = __expf(bf2f((u16)sv[jj]) - mx);
        sum += p;
        t8[jj] = f2bf(p);
      }
      *(short8*)&S[row][off] = *(short8*)t8;
    }
    #pragma unroll
    for (int m = 1; m < 8; m <<= 1) sum += __shfl_xor(sum, m, 8);
    if (part == 0) inv[row] = 1.0f / sum;
  }
  __syncthreads();

  // ---- PV ----
  f32x4 acco[2] = {};
  for (int jt = 0; jt < (ntiles << 6); jt += 64){
    #pragma unroll
    for (int r = 0; r < 2; r++) *(short8*)&KVf[(size_t)(tid + (r<<8)) * 8] = vR[r];
    __syncthreads();
    if (jt + 64 < (ntiles << 6)) loadV(jt + 64);
    #pragma unroll
    for (int kt = 0; kt < 2; kt++){
      short8 a = *(short8*)&S[(wm<<4) + (lane & 15)][jt + (kt<<5) + ((lane >> 4) << 3)];
      #pragma unroll
      for (int ntl = 0; ntl < 2; ntl++){
        short8 bf = *(short8*)&KVf[((((kt<<2) + (wn<<1) + ntl)*64 + lane)) << 3];
        acco[ntl] = __builtin_amdgcn_mfma_f32_16x16x32_bf16(a, bf, acco[ntl], 0, 0, 0);
      }
    }
    __syncthreads();
  }

  #pragma unroll
  for (int ntl = 0; ntl < 2; ntl++){
    int d = h*64 + (wn<<5) + (ntl<<4) + cn;
    #pragma unroll
    for (int r = 0; r < 4; r++){
      int srow = (wm<<4) + (cq<<2) + r;
      obf[((size_t)(b*Lq + q0 + srow))*512 + d] = f2bf(acco[ntl][r] * inv[srow]);
    }
  }
}

// ---------- GAT scores ----------
__global__ __launch_bounds__(256) void gat1_scores(const float* __restrict__ hall,
    const float* __restrict__ gata, float* __restrict__ s1, float* __restrict__ s2)
{
  int gw = blockIdx.x * 4 + (threadIdx.x >> 6);
  int lane = threadIdx.x & 63;
  int h = gw >> 13;
  int r = gw & 8191;
  float v = hall[(size_t)r * D_ + h * 64 + lane];
  float p1 = v * gata[h * 128 + lane];
  float p2 = v * gata[h * 128 + 64 + lane];
  #pragma unroll
  for (int o = 32; o; o >>= 1){ p1 += __shfl_down(p1, o, 64); p2 += __shfl_down(p2, o, 64); }
  if (lane == 0){ s1[h * 8192 + r] = p1; s2[h * 8192 + r] = p2; }
}
__global__ __launch_bounds__(256) void gat2_scores(const float* __restrict__ h2,
    const float* __restrict__ gatoa, float* __restrict__ s1, float* __restrict__ s2)
{
  int r = blockIdx.x * 4 + (threadIdx.x >> 6);
  int lane = threadIdx.x & 63;
  float p1 = 0.0f, p2 = 0.0f;
  for (int c = lane; c < D_; c += 64){
    float v = h2[(size_t)r * D_ + c];
    p1 += v * gatoa[c];
    p2 += v * gatoa[D_ + c];
  }
  #pragma unroll
  for (int o = 32; o; o >>= 1){ p1 += __shfl_down(p1, o, 64); p2 += __shfl_down(p2, o, 64); }
  if (lane == 0){ s1[r] = p1; s2[r] = p2; }
}

// ---------- MFMA GAT layer-1 attention (bf16 S/out, transposed bf16 hall, reg prefetch) ----------
__global__ __launch_bounds__(256) void gat1_mfma(const u32* __restrict__ mbits,
    const float* __restrict__ s1, const float* __restrict__ s2,
    const u16* __restrict__ ht, u16* __restrict__ xcb)
{
  __shared__ __align__(16) u16 S[32][SPS];
  __shared__ __align__(16) u16 Vf[8*64*8];
  __shared__ float inv[32];

  int tid = threadIdx.x, lane = tid & 63, wave = tid >> 6;
  int wm = wave & 1, wn = wave >> 1;
  int q0 = blockIdx.x << 5, h = blockIdx.y, b = blockIdx.z;
  int hb = h * 8192 + b * 512;

  // V prefetch setup
  int keybOff[2]; const u16* vSrc[2];
  #pragma unroll
  for (int r = 0; r < 2; r++){
    int u = tid + (r << 8);
    int l = u & 63, unit = u >> 6;
    int kt = unit >> 2, nt = unit & 3;
    int d = (nt<<4) + (l & 15);
    keybOff[r] = (kt<<5) + ((l >> 4) << 3);
    vSrc[r] = ht + ((size_t)(h*64 + d))*(size_t)(B_*N_) + (size_t)b*512 + keybOff[r];
  }
  short8 vR[2];
  auto loadV = [&](int jt){
    #pragma unroll
    for (int r = 0; r < 2; r++) vR[r] = *(const short8*)(vSrc[r] + jt);
  };

  // scores: S = adj ? leaky(s1[q]+s2[j]) : -9e15
  for (int x = tid; x < 32*128; x += 256){
    int row = x >> 7, c4 = (x & 127) << 2;
    float s1v = s1[hb + q0 + row];
    float4 s2v = *(const float4*)(s2 + hb + c4);
    size_t bi = ((size_t)(b*512) + q0 + row)*512 + c4;
    u32 w = mbits[bi >> 5] >> (bi & 31);
    float t; u16 q4[4];
    t = s1v + s2v.x; t = t>0?t:0.2f*t; q4[0] = f2bf((w     & 1u) ? t : -9.0e15f);
    t = s1v + s2v.y; t = t>0?t:0.2f*t; q4[1] = f2bf(((w>>1) & 1u) ? t : -9.0e15f);
    t = s1v + s2v.z; t = t>0?t:0.2f*t; q4[2] = f2bf(((w>>2) & 1u) ? t : -9.0e15f);
    t = s1v + s2v.w; t = t>0?t:0.2f*t; q4[3] = f2bf(((w>>3) & 1u) ? t : -9.0e15f);
    *(short4v*)&S[row][c4] = *(short4v*)q4;
  }
  loadV(0);
  __syncthreads();

  // vectorized softmax
  {
    int row = tid >> 3, part = tid & 7;
    int base = part << 6;
    float mx = -3.0e38f;
    #pragma unroll
    for (int c = 0; c < 8; c++){
      int off = base + (((c + part) & 7) << 3);
      short8 sv = *(short8*)&S[row][off];
      #pragma unroll
      for (int jj = 0; jj < 8; jj++) mx = fmaxf(mx, bf2f((u16)sv[jj]));
    }
    #pragma unroll
    for (int m = 1; m < 8; m <<= 1) mx = fmaxf(mx, __shfl_xor(mx, m, 8));
    float sum = 0.0f;
    #pragma unroll
    for (int c = 0; c < 8; c++){
      int off = base + (((c + part) & 7) << 3);
      short8 sv = *(short8*)&S[row][off];
      u16 t8[8];
      #pragma unroll
      for (int jj = 0; jj < 8; jj++){
        float p = __expf(bf2f((u16)sv[jj]) - mx);
        sum += p;
        t8[jj] = f2bf(p);
      }
      *(short8*)&S[row][off] = *(short8*)t8;
    }
    #pragma unroll
    for (int m = 1; m < 8; m <<= 1) sum += __shfl_xor(sum, m, 8);
    if (part == 0) inv[row] = 1.0f / sum;
  }
  __syncthreads();

  f32x4 acco[2] = {};
  for (int jt = 0; jt < 512; jt += 64){
    #pragma unroll
    for (int r = 0; r < 2; r++) *(short8*)&Vf[(size_t)(tid + (r<<8)) * 8] = vR[r];
    __syncthreads();
    if (jt + 64 < 512) loadV(jt + 64);
    #pragma unroll
    for (int kt = 0; kt < 2; kt++){
      short8 a = *(short8*)&S[(wm<<4) + (lane & 15)][jt + (kt<<5) + ((lane >> 4) << 3)];
      #pragma unroll
      for (int ntl = 0; ntl < 2; ntl++){
        short8 bf = *(short8*)&Vf[((((kt<<2) + (wn<<1) + ntl)*64 + lane)) << 3];
        acco[ntl] = __builtin_amdgcn_mfma_f32_16x16x32_bf16(a, bf, acco[ntl], 0, 0, 0);
      }
    }
    __syncthreads();
  }

  int cq = lane >> 4, cn = lane & 15;
  #pragma unroll
  for (int ntl = 0; ntl < 2; ntl++){
    int d = h*64 + (wn<<5) + (ntl<<4) + cn;
    #pragma unroll
    for (int r = 0; r < 4; r++){
      int srow = (wm<<4) + (cq<<2) + r;
      float val = acco[ntl][r] * inv[srow];
      val = val > 0.0f ? val : expf(val) - 1.0f;
      xcb[((size_t)(b*512 + q0 + srow))*512 + d] = f2bf(val);
    }
  }
}

// ---------- GAT output-layer probabilities (bit-packed mask, bf16 P out) ----------
__global__ __launch_bounds__(256) void gat2_prob(const u32* __restrict__ mbits,
    const float* __restrict__ s1, const float* __restrict__ s2, u16* __restrict__ P)
{
  __shared__ float red[4];
  int r = blockIdx.x, tid = threadIdx.x;
  int b = r >> 9;
  float s1v = s1[r];
  float e0, e1;
  {
    size_t base = (size_t)r * 512;
    u32 w0 = mbits[(base + tid) >> 5];
    u32 w1 = mbits[(base + tid + 256) >> 5];
    float t = s1v + s2[b*512 + tid];       t = t>0?t:0.2f*t;
    e0 = ((w0 >> (tid & 31)) & 1u) ? t : -9.0e15f;
    t = s1v + s2[b*512 + tid + 256];       t = t>0?t:0.2f*t;
    e1 = ((w1 >> (tid & 31)) & 1u) ? t : -9.0e15f;
  }
  float mx = block_max(fmaxf(e0, e1), red);
  float p0 = __expf(e0 - mx), p1 = __expf(e1 - mx);
  float s = block_sum(p0 + p1, red);
  float inv = 1.0f / s;
  P[(size_t)r*512 + tid]       = f2bf(p0 * inv);
  P[(size_t)r*512 + tid + 256] = f2bf(p1 * inv);
}

// ---------- fused dual-LayerNorm + relu (+ optional resid) ----------
// out = relu(LN(xa;ga,ba) + LN(xb;gb,bb)) [+ resid]
__global__ __launch_bounds__(256) void ln2_relu_k(
    const float* __restrict__ xa, const float* __restrict__ xb,
    const float* __restrict__ ga, const float* __restrict__ ba,
    const float* __restrict__ gb, const float* __restrict__ bb,
    const float* __restrict__ resid, float* __restrict__ out)
{
  __shared__ float2 red[4];
  int r = blockIdx.x, tid = threadIdx.x;
  const float* Ax = xa + (size_t)r * D_;
  const float* Bx = xb + (size_t)r * D_;
  float a0 = Ax[tid], a1 = Ax[tid + 256];
  float b0 = Bx[tid], b1 = Bx[tid + 256];
  float2 s = block_red2(a0 + a1, b0 + b1, red);
  float mua = s.x * (1.0f/512.0f), mub = s.y * (1.0f/512.0f);
  float da0 = a0 - mua, da1 = a1 - mua, db0 = b0 - mub, db1 = b1 - mub;
  float2 v = block_red2(da0*da0 + da1*da1, db0*db0 + db1*db1, red);
  float ia = rsqrtf(v.x * (1.0f/512.0f) + 1e-6f);
  float ib = rsqrtf(v.y * (1.0f/512.0f) + 1e-6f);
  float o0 = da0*ia*ga[tid]     + ba[tid]     + db0*ib*gb[tid]     + bb[tid];
  float o1 = da1*ia*ga[tid+256] + ba[tid+256] + db1*ib*gb[tid+256] + bb[tid+256];
  o0 = o0 > 0.0f ? o0 : 0.0f;
  o1 = o1 > 0.0f ? o1 : 0.0f;
  if (resid){ o0 += resid[(size_t)r*D_ + tid]; o1 += resid[(size_t)r*D_ + tid + 256]; }
  out[(size_t)r*D_ + tid]       = o0;
  out[(size_t)r*D_ + tid + 256] = o1;
}

// ---------- host-side MHA helper (no LN; writes fp32 tmp) ----------
static void run_mha_core(hipStream_t st, const float* q_in, int Lq, const float* kv_in, int Lk,
                         const u32* mbits, const u16* w,
                         u16* qbf, u16* kbf, u16* vtb, u16* obf, float* tmp)
{
  dim3 blk(256);
  int Mq = B_*Lq, Mk = B_*Lk;
  if (q_in == kv_in){
    proj_fused<<<dim3(12, Mq/128), blk, 0, st>>>(q_in, w, 0, qbf, kbf, vtb, Mk);
  } else {
    gemm_mfma<<<dim3(4, Mq/128), blk, 0, st>>>(q_in, nullptr, w, nullptr, nullptr,
        nullptr, qbf, nullptr, Mq, D_, 0, 2, 0,0,0,0);
    proj_fused<<<dim3(8, Mk/128), blk, 0, st>>>(kv_in, w + DD, 1, nullptr, kbf, vtb, Mk);
  }
  attn_mfma<<<dim3(Lq/32, NH_, B_), blk, 0, st>>>(qbf, kbf, vtb, mbits, obf, Lq, Lk);
  gemm_mfma<<<dim3(4, Mq/128), blk, 0, st>>>(nullptr, obf, w + (size_t)3*DD, nullptr, q_in,
      tmp, nullptr, nullptr, Mq, D_, 0, 1, 0,0,0,0);
}

extern "C" void kernel_launch(void* const* d_in, const int* in_sizes, int n_in,
                              void* d_out, int out_size, void* d_ws, size_t ws_size,
                              hipStream_t stream) {
  (void)in_sizes; (void)n_in; (void)out_size; (void)ws_size;

  const float* xf    = (const float*)d_in[0];
  const int* adj_i   = (const int*)d_in[2];
  const int* adj_s   = (const int*)d_in[3];
  const int* adj_is  = (const int*)d_in[4];
  const int* adj_si  = (const int*)d_in[5];
  const float* intent= (const float*)d_in[6];
  const float* gatW  = (const float*)d_in[7];
  const float* gata  = (const float*)d_in[8];
  const float* gatoW = (const float*)d_in[9];
  const float* gatoa = (const float*)d_in[10];
  const float* mhaw  = (const float*)d_in[11];
  const float* lng   = (const float*)d_in[12];
  const float* lnb   = (const float*)d_in[13];
  const float* linW1 = (const float*)d_in[14];
  const float* linb1 = (const float*)d_in[15];
  const float* linW2 = (const float*)d_in[16];
  const float* linb2 = (const float*)d_in[17];

  float* out0 = (float*)d_out;                   // slot_out      [B,N,D]
  float* out1 = out0 + BND;                      // slot_logits   [B,N,OUT]
  float* out2 = out1 + (size_t)B_*N_*OUT_;       // slot_graph_out[B,N,D]

  // ---- workspace carve ----
  float* Q    = (float*)d_ws;      // BND x6
  float* K    = Q   + BND;
  float* V    = K   + BND;
  float* O    = V   + BND;
  float* TMP  = O   + BND;
  float* HB1  = TMP + BND;
  float* ha0  = HB1 + BND;         // BID x9
  float* ha1  = ha0 + BID;
  float* ta   = ha1 + BID;
  float* tb   = ta  + BID;
  float* sqa  = tb  + BID;
  float* ska  = sqa + BID;
  float* sva  = ska + BID;
  float* soa  = sva + BID;
  float* stmp = soa + BID;
  float* s1   = stmp+ BID;         // 65536 x2
  float* s2   = s1  + 65536;
  float* s1o  = s2  + 65536;       // 8192 x2
  float* s2o  = s1o + 8192;
  u16* Wm  = (u16*)(s2o + 8192);   // 32*DD bf16 (all mhaw mats, swizzled)
  u16* Wg  = Wm  + (size_t)32*DD;  // gat Wcat swizzled
  u16* Wgo = Wg  + DD;             // gat_out_W swizzled
  u16* W1s = Wgo + DD;             // lin_W1 swizzled
  u16* W2s = W1s + DD;             // lin_W2 swizzled
  u32* pm_s  = (u32*)(W2s + DD/4); // adj_s  packed
  u32* pm_i  = pm_s + 131072;
  u32* pm_is = pm_i + 512;
  u32* pm_si = pm_is + 8192;

  // bf16 overlays on dead fp32 scratch (all uses stream-ordered):
  u16* qbf = (u16*)V;              // V fp32 only used in GAT phase
  u16* kbf = (u16*)V + BND;
  u16* vtb = (u16*)TMP;            // clobbered by out-proj AFTER attn reads it
  u16* obf = (u16*)O;              // attn bf16 output
  u16* htb = (u16*)O;              // GAT phase reuse (obf dead by then)
  u16* xcb = (u16*)K;              // gat1 bf16 output (K dead after MHA)
  u16* zb  = (u16*)Q;              // logits intermediate bf16
  u16* Pb  = (u16*)HB1;            // gat2 P bf16
  u16* h2f = (u16*)O;              // h2 in B-frag order (htb dead after gat1)
  (void)ta; (void)tb; (void)sva; (void)soa; (void)stmp;

  dim3 blk(256);

  // ---- mask packing ----
  pack_mask_k<<<(B_*N_*N_)/256,   blk, 0, stream>>>(adj_s,  pm_s);
  pack_mask_k<<<(B_*NI_*NI_)/256, blk, 0, stream>>>(adj_i,  pm_i);
  pack_mask_k<<<(B_*N_*NI_)/256,  blk, 0, stream>>>(adj_is, pm_is);
  pack_mask_k<<<(B_*NI_*N_)/256,  blk, 0, stream>>>(adj_si, pm_si);

  // ---- weight prep ----
  swz_k<<<dim3(128, 32), blk, 0, stream>>>(mhaw,  Wm,  D_,   DD, DD);
  swz_gatW_k<<<128, blk, 0, stream>>>(gatW, Wg);
  swz_k<<<dim3(128, 1), blk, 0, stream>>>(gatoW, Wgo, D_,   0, 0);
  swz_k<<<dim3(128, 1), blk, 0, stream>>>(linW1, W1s, D_,   0, 0);
  swz_k<<<dim3(32,  1), blk, 0, stream>>>(linW2, W2s, OUT_, 0, 0);

  // ================= MHA stack =================
  bcast_k<<<BID/256, blk, 0, stream>>>(intent, ha0, BID);

  // ---- layer 0 ----
  run_mha_core(stream, ha0, NI_, ha0, NI_, pm_i,  Wm +  (size_t)0*DD,
               qbf, kbf, vtb, obf, sqa);                                   // a2a -> sqa
  run_mha_core(stream, ha0, NI_, xf,  N_,  pm_si, Wm + (size_t)12*DD,
               qbf, kbf, vtb, obf, ska);                                   // b2a -> ska
  ln2_relu_k<<<dim3(B_*NI_), blk, 0, stream>>>(sqa, ska, lng + 0*D_, lnb + 0*D_,
               lng + 3*D_, lnb + 3*D_, nullptr, ha1);                      // h_a1
  run_mha_core(stream, xf, N_, xf, N_, pm_s,  Wm +  (size_t)4*DD,
               qbf, kbf, vtb, obf, HB1);                                   // b2b -> HB1 (pre-LN)
  run_mha_core(stream, xf, N_, ha0, NI_, pm_is, Wm + (size_t)8*DD,
               qbf, kbf, vtb, obf, TMP);                                   // a2b -> TMP (pre-LN)
  ln2_relu_k<<<dim3(B_*N_), blk, 0, stream>>>(HB1, TMP, lng + 1*D_, lnb + 1*D_,
               lng + 2*D_, lnb + 2*D_, nullptr, HB1);                      // h_b1

  // ---- layer 1 (a2a/b2a dead) ----
  run_mha_core(stream, HB1, N_, HB1, N_, pm_s,  Wm + (size_t)20*DD,
               qbf, kbf, vtb, obf, K);                                     // b2b -> K (pre-LN)
  run_mha_core(stream, HB1, N_, ha1, NI_, pm_is, Wm + (size_t)24*DD,
               qbf, kbf, vtb, obf, TMP);                                   // a2b -> TMP (pre-LN)
  ln2_relu_k<<<dim3(B_*N_), blk, 0, stream>>>(K, TMP, lng + 5*D_, lnb + 5*D_,
               lng + 6*D_, lnb + 6*D_, xf, out0);                          // slot_out = xf + h_b2

  // ---- logits (bf16 intermediate) ----
  gemm_mfma<<<dim3(4, (B_*N_)/128), blk, 0, stream>>>(out0, nullptr, W1s, linb1, nullptr,
      nullptr, zb, nullptr, 0, D_, 1, 2, 0,0,0,0);
  gemm_mfma<<<dim3(1, (B_*N_)/128), blk, 0, stream>>>(nullptr, zb, W2s, linb2, nullptr,
      out1, nullptr, nullptr, 0, OUT_, 0, 1, 0,0,0,0);

  // ================= GAT branch =================
  // h_all -> Q (fp32) + htb (bf16 transposed)
  gemm_mfma<<<dim3(4, (B_*N_)/128), blk, 0, stream>>>(xf, nullptr, Wg, nullptr, nullptr,
      Q, nullptr, htb, B_*N_, D_, 0, 5, 0,0,0,0);
  gat1_scores<<<(H_*B_*N_)/4, blk, 0, stream>>>(Q, gata, s1, s2);
  gat1_mfma<<<dim3(N_/32, H_, B_), blk, 0, stream>>>(pm_s, s1, s2, htb, xcb);
  // h2 = xc @ Wgo : fp32 rows (for scores) + B-fragment-order bf16 (for P@h2)
  gemm_mfma<<<dim3(4, (B_*N_)/128), blk, 0, stream>>>(nullptr, xcb, Wgo, nullptr, nullptr,
      V, nullptr, h2f, 0, D_, 0, 9, 0,0,0,0);
  gat2_scores<<<(B_*N_)/4, blk, 0, stream>>>(V, gatoa, s1o, s2o);
  gat2_prob<<<B_*N_, blk, 0, stream>>>(pm_s, s1o, s2o, Pb);
  // out2 = elu(P @ h2) + x  (batched over B; h2 already in B-frag order)
  gemm_mfma<<<dim3(4, N_/128, B_), blk, 0, stream>>>(nullptr, Pb, h2f, nullptr, xf,
      out2, nullptr, nullptr, 0, D_, 2, 1,
      (size_t)N_*N_, (size_t)DD, (size_t)N_*D_, (size_t)N_*D_);
}

// Round 11
// 736.458 us; speedup vs baseline: 2.0113x; 1.1740x over previous
//
#include <hip/hip_runtime.h>

// B=16, N=512, D=512, NI=32, GH=64, H=8, L=2, OUT=128, heads=8
#define B_   16
#define N_   512
#define D_   512
#define NI_  32
#define GH_  64
#define H_   8
#define OUT_ 128
#define NH_  8

#define BND   (B_*N_*D_)     // 4194304
#define BID   (B_*NI_*D_)    // 262144
#define DD    (D_*D_)        // 262144

#define SPS 520              // S row stride in bf16

typedef unsigned short u16;
typedef unsigned int   u32;
typedef __attribute__((ext_vector_type(8))) short short8;
typedef __attribute__((ext_vector_type(4))) short short4v;
typedef __attribute__((ext_vector_type(4))) float f32x4;

__device__ __forceinline__ u16 f2bf(float f){
  u32 x = __float_as_uint(f);
  x += 0x7fffu + ((x >> 16) & 1u);   // RNE
  return (u16)(x >> 16);
}
__device__ __forceinline__ float bf2f(u16 s){
  return __uint_as_float((u32)s << 16);
}

// blockDim must be 256
__device__ __forceinline__ float block_sum(float v, float* sm){
  #pragma unroll
  for (int o = 32; o; o >>= 1) v += __shfl_down(v, o, 64);
  int lane = threadIdx.x & 63, w = threadIdx.x >> 6;
  __syncthreads();
  if (lane == 0) sm[w] = v;
  __syncthreads();
  return sm[0] + sm[1] + sm[2] + sm[3];
}
__device__ __forceinline__ float block_max(float v, float* sm){
  #pragma unroll
  for (int o = 32; o; o >>= 1) v = fmaxf(v, __shfl_down(v, o, 64));
  int lane = threadIdx.x & 63, w = threadIdx.x >> 6;
  __syncthreads();
  if (lane == 0) sm[w] = v;
  __syncthreads();
  return fmaxf(fmaxf(sm[0], sm[1]), fmaxf(sm[2], sm[3]));
}
__device__ __forceinline__ float2 block_red2(float a, float b, float2* sm){
  #pragma unroll
  for (int o = 32; o; o >>= 1){ a += __shfl_down(a, o, 64); b += __shfl_down(b, o, 64); }
  int lane = threadIdx.x & 63, w = threadIdx.x >> 6;
  __syncthreads();
  if (lane == 0) sm[w] = make_float2(a, b);
  __syncthreads();
  float2 r;
  r.x = sm[0].x + sm[1].x + sm[2].x + sm[3].x;
  r.y = sm[0].y + sm[1].y + sm[2].y + sm[3].y;
  return r;
}

// ---------- mask bit-pack (adj>0 -> 1 bit) ----------
__global__ __launch_bounds__(256) void pack_mask_k(const int* __restrict__ adj, u32* __restrict__ bits){
  int i = blockIdx.x * 256 + threadIdx.x;
  unsigned long long m = __ballot(adj[i] > 0);
  if ((threadIdx.x & 63) == 0){
    bits[(i >> 5)]     = (u32)m;
    bits[(i >> 5) + 1] = (u32)(m >> 32);
  }
}

// ---------- elementwise ----------
__global__ __launch_bounds__(256) void bcast_k(const float* __restrict__ s, float* __restrict__ d, int n){
  int i = blockIdx.x * 256 + threadIdx.x;
  if (i < n) d[i] = s[i & (NI_*D_ - 1)];
}

// ---------- weight swizzle into MFMA B-fragment order ----------
__global__ __launch_bounds__(256) void swz_k(const float* __restrict__ W, u16* __restrict__ o,
                                             int Nc, size_t sW, size_t sO){
  int gw = blockIdx.x * 4 + (threadIdx.x >> 6);
  int lane = threadIdx.x & 63;
  int ntc = Nc >> 4;
  int s = gw / ntc, nt = gw - s * ntc;
  const float* Wb = W + sW * blockIdx.y;
  u16* ob = o + sO * blockIdx.y;
  int n = nt*16 + (lane & 15);
  int kb = s*32 + ((lane >> 4) << 3);
  u16 t8[8];
  #pragma unroll
  for (int j = 0; j < 8; j++) t8[j] = f2bf(Wb[(size_t)(kb + j) * Nc + n]);
  *(short8*)&ob[((size_t)(s * ntc + nt) * 64 + lane) * 8] = *(short8*)t8;
}
// gat_W [H,D,GH] -> head-major-concat [D,512], swizzled
__global__ __launch_bounds__(256) void swz_gatW_k(const float* __restrict__ gw_, u16* __restrict__ o){
  int gw = blockIdx.x * 4 + (threadIdx.x >> 6);  // 512 waves
  int lane = threadIdx.x & 63;
  int s = gw >> 5, nt = gw & 31;
  int n = nt*16 + (lane & 15);
  int h = n >> 6, f = n & 63;
  int kb = s*32 + ((lane >> 4) << 3);
  u16 t8[8];
  #pragma unroll
  for (int j = 0; j < 8; j++) t8[j] = f2bf(gw_[((size_t)(h*512) + kb + j) * 64 + f]);
  *(short8*)&o[((size_t)(s*32 + nt) * 64 + lane) * 8] = *(short8*)t8;
}

// ---------- MFMA GEMM (register-prefetch double-buffered) ----------
// A source: fp32 A or bf16 Ab (one non-null). K = 512 fixed.
// C modes (bitmask): 1 = fp32 C[M,Nc]; 2 = bf16 Cb[M,Nc]; 4 = bf16 transposed Cx[Nc,Mtot];
//                    8 = bf16 B-fragment order Cx (batched per row>>9, Nc must be 512).
// act: 0 none, 1 leaky, 2 elu. Batched over blockIdx.z via strides.
__global__ __launch_bounds__(256) void gemm_mfma(
    const float* __restrict__ A, const u16* __restrict__ Ab, const u16* __restrict__ Bw,
    const float* __restrict__ bias, const float* __restrict__ resid,
    float* __restrict__ C, u16* __restrict__ Cb, u16* __restrict__ Cx,
    int Mtot, int Nc, int act, int mode,
    size_t sA, size_t sB, size_t sC, size_t sR)
{
  __shared__ __align__(16) u16 As[128*64];
  __shared__ __align__(16) u16 Bs[64*128];
  if (A)  A  += sA * blockIdx.z;
  if (Ab) Ab += sA * blockIdx.z;
  Bw += sB * blockIdx.z;
  if (C) C += sC * blockIdx.z;
  if (resid) resid += sR * blockIdx.z;

  int tid = threadIdx.x, lane = tid & 63, wave = tid >> 6;
  int wm = wave & 1, wn = wave >> 1;
  int row0 = blockIdx.y << 7, col0 = blockIdx.x << 7;
  int ntc = Nc >> 4, nt0 = col0 >> 4;

  const float* aSrcF[4];
  const u16*   aSrcB[4];
  #pragma unroll
  for (int r = 0; r < 4; r++){
    int u = tid + (r << 8);
    int l = u & 63, kt = (u >> 6) & 1, mt = u >> 7;
    size_t off = (size_t)(row0 + (mt << 4) + (l & 15)) * 512 + (kt << 5) + ((l >> 4) << 3);
    aSrcF[r] = A  ? A  + off : nullptr;
    aSrcB[r] = Ab ? Ab + off : nullptr;
  }
  const u16* bSrc[2][2];
  #pragma unroll
  for (int kt = 0; kt < 2; kt++)
    #pragma unroll
    for (int r = 0; r < 2; r++)
      bSrc[kt][r] = Bw + (((size_t)(kt * ntc + nt0)) << 9) + (((size_t)(tid + (r << 8))) << 3);
  size_t bStep = (size_t)ntc << 10;

  float4 aF[4][2];
  short8 aB[4];
  short8 bP[2][2];

  auto doLoad = [&](int ks){
    if (Ab){
      #pragma unroll
      for (int r = 0; r < 4; r++) aB[r] = *(const short8*)(aSrcB[r] + (ks << 6));
    } else {
      #pragma unroll
      for (int r = 0; r < 4; r++){
        aF[r][0] = *(const float4*)(aSrcF[r] + (ks << 6));
        aF[r][1] = *(const float4*)(aSrcF[r] + (ks << 6) + 4);
      }
    }
    #pragma unroll
    for (int kt = 0; kt < 2; kt++)
      #pragma unroll
      for (int r = 0; r < 2; r++)
        bP[kt][r] = *(const short8*)(bSrc[kt][r] + (size_t)ks * bStep);
  };

  f32x4 acc[4][4] = {};
  doLoad(0);
  for (int ks = 0; ks < 8; ks++){
    if (Ab){
      #pragma unroll
      for (int r = 0; r < 4; r++) *(short8*)&As[(size_t)(tid + (r<<8)) * 8] = aB[r];
    } else {
      #pragma unroll
      for (int r = 0; r < 4; r++){
        u16 t8[8] = {f2bf(aF[r][0].x), f2bf(aF[r][0].y), f2bf(aF[r][0].z), f2bf(aF[r][0].w),
                     f2bf(aF[r][1].x), f2bf(aF[r][1].y), f2bf(aF[r][1].z), f2bf(aF[r][1].w)};
        *(short8*)&As[(size_t)(tid + (r<<8)) * 8] = *(short8*)t8;
      }
    }
    #pragma unroll
    for (int kt = 0; kt < 2; kt++)
      #pragma unroll
      for (int r = 0; r < 2; r++)
        *(short8*)&Bs[(kt << 12) + ((size_t)(tid + (r<<8)) << 3)] = bP[kt][r];
    __syncthreads();
    if (ks < 7) doLoad(ks + 1);
    #pragma unroll
    for (int kt = 0; kt < 2; kt++){
      short8 a[4], b[4];
      #pragma unroll
      for (int i = 0; i < 4; i++)
        a[i] = *(short8*)&As[(((((wm<<2)+i) << 1) + kt) * 64 + lane) << 3];
      #pragma unroll
      for (int n = 0; n < 4; n++)
        b[n] = *(short8*)&Bs[(((kt << 3) + (wn<<2) + n) * 64 + lane) << 3];
      #pragma unroll
      for (int i = 0; i < 4; i++)
        #pragma unroll
        for (int n = 0; n < 4; n++)
          acc[i][n] = __builtin_amdgcn_mfma_f32_16x16x32_bf16(a[i], b[n], acc[i][n], 0, 0, 0);
    }
    __syncthreads();
  }

  int cq = lane >> 4, cn = lane & 15;
  #pragma unroll
  for (int i = 0; i < 4; i++){
    #pragma unroll
    for (int n = 0; n < 4; n++){
      int col = col0 + (wn<<6) + (n<<4) + cn;
      float bi = bias ? bias[col] : 0.0f;
      int rowb = row0 + (wm<<6) + (i<<4) + (cq<<2);
      float vals[4];
      #pragma unroll
      for (int r = 0; r < 4; r++){
        float c = acc[i][n][r] + bi;
        if (act == 1) c = c > 0.0f ? c : 0.2f * c;
        else if (act == 2) c = c > 0.0f ? c : expf(c) - 1.0f;
        if (resid) c += resid[(size_t)(rowb + r) * Nc + col];
        vals[r] = c;
      }
      if (mode & 1){
        #pragma unroll
        for (int r = 0; r < 4; r++) C[(size_t)(rowb + r) * Nc + col] = vals[r];
      }
      if (mode & 2){
        #pragma unroll
        for (int r = 0; r < 4; r++) Cb[(size_t)(rowb + r) * Nc + col] = f2bf(vals[r]);
      }
      if (mode & 4){
        u16 t4[4] = {f2bf(vals[0]), f2bf(vals[1]), f2bf(vals[2]), f2bf(vals[3])};
        *(short4v*)&Cx[(size_t)col * Mtot + rowb] = *(short4v*)t4;
      }
      if (mode & 8){
        u16 t4[4] = {f2bf(vals[0]), f2bf(vals[1]), f2bf(vals[2]), f2bf(vals[3])};
        int kk = rowb & 511;
        int ln_ = (((kk >> 3) & 3) << 4) | (col & 15);
        size_t off = (size_t)(rowb >> 9) * DD
                   + ((((size_t)(kk >> 5) * 32 + ((col & 511) >> 4)) * 64 + ln_) << 3) + (kk & 7);
        *(short4v*)&Cx[off] = *(short4v*)t4;
      }
    }
  }
}

// ---------- multi-job GEMM: co-schedule independent Nc=512 GEMMs in one launch ----------
// Jobs found by blockIdx.x range. Per job: A fp32 or Ab bf16; mode 1(fp32+resid)/2(bf16)/4(bf16 T).
struct GJob {
  const float* A; const u16* Ab; const u16* W; const float* resid;
  float* C; u16* Cb; u16* Ct;
  int M; int mode; int blk0;
};
struct GJobs { GJob j[12]; int nj; };

__global__ __launch_bounds__(256) void gemm_multi(GJobs js)
{
  __shared__ __align__(16) u16 As[128*64];
  __shared__ __align__(16) u16 Bs[64*128];
  int jx = 0;
  #pragma unroll
  for (int t = 1; t < 12; t++)
    if (t < js.nj && (int)blockIdx.x >= js.j[t].blk0) jx = t;
  const float* A     = js.j[jx].A;
  const u16*   Ab    = js.j[jx].Ab;
  const u16*   Bw    = js.j[jx].W;
  const float* resid = js.j[jx].resid;
  float* C  = js.j[jx].C;
  u16*   Cb = js.j[jx].Cb;
  u16*   Ct = js.j[jx].Ct;
  int Mtot = js.j[jx].M, mode = js.j[jx].mode;
  int local = blockIdx.x - js.j[jx].blk0;
  int col0 = (local & 3) << 7, row0 = (local >> 2) << 7;
  int nt0 = col0 >> 4;                       // ntc = 32 (Nc=512)

  int tid = threadIdx.x, lane = tid & 63, wave = tid >> 6;
  int wm = wave & 1, wn = wave >> 1;

  const float* aSrcF[4];
  const u16*   aSrcB[4];
  #pragma unroll
  for (int r = 0; r < 4; r++){
    int u = tid + (r << 8);
    int l = u & 63, kt = (u >> 6) & 1, mt = u >> 7;
    size_t off = (size_t)(row0 + (mt << 4) + (l & 15)) * 512 + (kt << 5) + ((l >> 4) << 3);
    aSrcF[r] = A  ? A  + off : nullptr;
    aSrcB[r] = Ab ? Ab + off : nullptr;
  }
  const u16* bSrc[2][2];
  #pragma unroll
  for (int kt = 0; kt < 2; kt++)
    #pragma unroll
    for (int r = 0; r < 2; r++)
      bSrc[kt][r] = Bw + (((size_t)(kt * 32 + nt0)) << 9) + (((size_t)(tid + (r << 8))) << 3);

  float4 aF[4][2];
  short8 aB[4];
  short8 bP[2][2];
  auto doLoad = [&](int ks){
    if (Ab){
      #pragma unroll
      for (int r = 0; r < 4; r++) aB[r] = *(const short8*)(aSrcB[r] + (ks << 6));
    } else {
      #pragma unroll
      for (int r = 0; r < 4; r++){
        aF[r][0] = *(const float4*)(aSrcF[r] + (ks << 6));
        aF[r][1] = *(const float4*)(aSrcF[r] + (ks << 6) + 4);
      }
    }
    #pragma unroll
    for (int kt = 0; kt < 2; kt++)
      #pragma unroll
      for (int r = 0; r < 2; r++)
        bP[kt][r] = *(const short8*)(bSrc[kt][r] + ((size_t)ks << 15));   // 32<<10 per ks
  };

  f32x4 acc[4][4] = {};
  doLoad(0);
  for (int ks = 0; ks < 8; ks++){
    if (Ab){
      #pragma unroll
      for (int r = 0; r < 4; r++) *(short8*)&As[(size_t)(tid + (r<<8)) * 8] = aB[r];
    } else {
      #pragma unroll
      for (int r = 0; r < 4; r++){
        u16 t8[8] = {f2bf(aF[r][0].x), f2bf(aF[r][0].y), f2bf(aF[r][0].z), f2bf(aF[r][0].w),
                     f2bf(aF[r][1].x), f2bf(aF[r][1].y), f2bf(aF[r][1].z), f2bf(aF[r][1].w)};
        *(short8*)&As[(size_t)(tid + (r<<8)) * 8] = *(short8*)t8;
      }
    }
    #pragma unroll
    for (int kt = 0; kt < 2; kt++)
      #pragma unroll
      for (int r = 0; r < 2; r++)
        *(short8*)&Bs[(kt << 12) + ((size_t)(tid + (r<<8)) << 3)] = bP[kt][r];
    __syncthreads();
    if (ks < 7) doLoad(ks + 1);
    #pragma unroll
    for (int kt = 0; kt < 2; kt++){
      short8 a[4], b[4];
      #pragma unroll
      for (int i = 0; i < 4; i++)
        a[i] = *(short8*)&As[(((((wm<<2)+i) << 1) + kt) * 64 + lane) << 3];
      #pragma unroll
      for (int n = 0; n < 4; n++)
        b[n] = *(short8*)&Bs[(((kt << 3) + (wn<<2) + n) * 64 + lane) << 3];
      #pragma unroll
      for (int i = 0; i < 4; i++)
        #pragma unroll
        for (int n = 0; n < 4; n++)
          acc[i][n] = __builtin_amdgcn_mfma_f32_16x16x32_bf16(a[i], b[n], acc[i][n], 0, 0, 0);
    }
    __syncthreads();
  }

  int cq = lane >> 4, cn = lane & 15;
  #pragma unroll
  for (int i = 0; i < 4; i++){
    #pragma unroll
    for (int n = 0; n < 4; n++){
      int col = col0 + (wn<<6) + (n<<4) + cn;
      int rowb = row0 + (wm<<6) + (i<<4) + (cq<<2);
      float vals[4];
      #pragma unroll
      for (int r = 0; r < 4; r++){
        float c = acc[i][n][r];
        if (resid) c += resid[(size_t)(rowb + r) * 512 + col];
        vals[r] = c;
      }
      if (mode == 1){
        #pragma unroll
        for (int r = 0; r < 4; r++) C[(size_t)(rowb + r) * 512 + col] = vals[r];
      } else if (mode == 2){
        #pragma unroll
        for (int r = 0; r < 4; r++) Cb[(size_t)(rowb + r) * 512 + col] = f2bf(vals[r]);
      } else {
        u16 t4[4] = {f2bf(vals[0]), f2bf(vals[1]), f2bf(vals[2]), f2bf(vals[3])};
        *(short4v*)&Ct[(size_t)col * Mtot + rowb] = *(short4v*)t4;
      }
    }
  }
}

// ---------- MFMA MHA attention (bf16 in/out, V transposed, LDS mask, reg prefetch) ----------
__global__ __launch_bounds__(256) void attn_mfma(
    const u16* __restrict__ q, const u16* __restrict__ k, const u16* __restrict__ vt,
    const u32* __restrict__ mbits, u16* __restrict__ obf, int Lq, int Lk)
{
  __shared__ __align__(16) u16 S[32][SPS];      // scores, then P (bf16)
  __shared__ __align__(16) u16 KVf[8*64*8];     // K^T / V B-fragments
  __shared__ u32 maskw[32*16];
  __shared__ float inv[32];

  int tid = threadIdx.x, lane = tid & 63, wave = tid >> 6;
  int wm = wave & 1, wn = wave >> 1;
  int q0 = blockIdx.x << 5, h = blockIdx.y, b = blockIdx.z;
  int ntiles = (Lk + 63) >> 6;
  size_t vM = (size_t)B_ * Lk;

  if (Lk == 512){
    #pragma unroll
    for (int r = 0; r < 2; r++){
      int x = tid + (r << 8);
      maskw[x] = mbits[(((size_t)(b*Lq) + q0 + (x >> 4)) << 4) + (x & 15)];
    }
  } else {
    if (tid < 32) maskw[tid << 4] = mbits[(size_t)(b*Lq) + q0 + tid];
  }

  short8 aq[2];
  #pragma unroll
  for (int kt = 0; kt < 2; kt++)
    aq[kt] = *(const short8*)(q + ((size_t)(b*Lq + q0 + (wm<<4) + (lane & 15)))*512
                                + h*64 + (kt<<5) + ((lane >> 4) << 3));

  int cq = lane >> 4, cn = lane & 15;

  int keyOff[2]; const u16* kSrc[2];
  int keybOff[2]; const u16* vSrc[2];
  #pragma unroll
  for (int r = 0; r < 2; r++){
    int u = tid + (r << 8);
    int l = u & 63, unit = u >> 6;
    int kt = unit >> 2, nt = unit & 3;
    keyOff[r] = (nt<<4) + (l & 15);
    kSrc[r] = k + ((size_t)(b*Lk + keyOff[r]))*512 + h*64 + (kt<<5) + ((l >> 4) << 3);
    int d = (nt<<4) + (l & 15);
    keybOff[r] = (kt<<5) + ((l >> 4) << 3);
    vSrc[r] = vt + ((size_t)(h*64 + d))*vM + (size_t)b*Lk + keybOff[r];
  }
  short8 kR[2], vR[2];
  auto loadK = [&](int jt){
    #pragma unroll
    for (int r = 0; r < 2; r++){
      short8 val = {0,0,0,0,0,0,0,0};
      if (jt + keyOff[r] < Lk) val = *(const short8*)(kSrc[r] + (size_t)jt * 512);
      kR[r] = val;
    }
  };
  auto loadV = [&](int jt){
    #pragma unroll
    for (int r = 0; r < 2; r++){
      short8 val = {0,0,0,0,0,0,0,0};
      if (jt + keybOff[r] < Lk) val = *(const short8*)(vSrc[r] + jt);
      vR[r] = val;
    }
  };

  // ---- QK^T -> S ----
  loadK(0);
  for (int jt = 0; jt < (ntiles << 6); jt += 64){
    #pragma unroll
    for (int r = 0; r < 2; r++) *(short8*)&KVf[(size_t)(tid + (r<<8)) * 8] = kR[r];
    __syncthreads();
    if (jt + 64 < (ntiles << 6)) loadK(jt + 64);
    f32x4 accs[2] = {};
    #pragma unroll
    for (int kt = 0; kt < 2; kt++){
      #pragma unroll
      for (int ntl = 0; ntl < 2; ntl++){
        short8 bf = *(short8*)&KVf[((((kt<<2) + (wn<<1) + ntl)*64 + lane)) << 3];
        accs[ntl] = __builtin_amdgcn_mfma_f32_16x16x32_bf16(aq[kt], bf, accs[ntl], 0, 0, 0);
      }
    }
    int jb = jt + (wn<<5);
    if (jb < Lk){
      int wrd = (jt >> 5) + wn;
      #pragma unroll
      for (int r = 0; r < 4; r++){
        int srow = (wm<<4) + (cq<<2) + r;
        u32 mw = maskw[(srow << 4) + wrd];
        float e0 = ((mw >> cn) & 1u)      ? accs[0][r]*0.125f : -1.0e9f;
        float e1 = ((mw >> (16+cn)) & 1u) ? accs[1][r]*0.125f : -1.0e9f;
        S[srow][jb + cn]      = f2bf(e0);
        S[srow][jb + 16 + cn] = f2bf(e1);
      }
    } else {
      #pragma unroll
      for (int r = 0; r < 4; r++){
        int srow = (wm<<4) + (cq<<2) + r;
        S[srow][jb + cn]      = 0xFF80;
        S[srow][jb + 16 + cn] = 0xFF80;
      }
    }
    __syncthreads();
  }

  loadV(0);   // V tile 0 latency hides under softmax

  // ---- softmax (vectorized) ----
  {
    int row = tid >> 3, part = tid & 7;
    int CPT = ntiles;
    int base = part * (ntiles << 3);
    float mx = -3.0e38f;
    for (int c = 0; c < CPT; c++){
      int off = base + (((c + part) & (CPT - 1)) << 3);
      short8 sv = *(short8*)&S[row][off];
      #pragma unroll
      for (int jj = 0; jj < 8; jj++) mx = fmaxf(mx, bf2f((u16)sv[jj]));
    }
    #pragma unroll
    for (int m = 1; m < 8; m <<= 1) mx = fmaxf(mx, __shfl_xor(mx, m, 8));
    float sum = 0.0f;
    for (int c = 0; c < CPT; c++){
      int off = base + (((c + part) & (CPT - 1)) << 3);
      short8 sv = *(short8*)&S[row][off];
      u16 t8[8];
      #pragma unroll
      for (int jj = 0; jj < 8; jj++){
        float p = __expf(bf2f((u16)sv[jj]) - mx);
        sum += p;
        t8[jj] = f2bf(p);
      }
      *(short8*)&S[row][off] = *(short8*)t8;
    }
    #pragma unroll
    for (int m = 1; m < 8; m <<= 1) sum += __shfl_xor(sum, m, 8);
    if (part == 0) inv[row] = 1.0f / sum;
  }
  __syncthreads();

  // ---- PV ----
  f32x4 acco[2] = {};
  for (int jt = 0; jt < (ntiles << 6); jt += 64){
    #pragma unroll
    for (int r = 0; r < 2; r++) *(short8*)&KVf[(size_t)(tid + (r<<8)) * 8] = vR[r];
    __syncthreads();
    if (jt + 64 < (ntiles << 6)) loadV(jt + 64);
    #pragma unroll
    for (int kt = 0; kt < 2; kt++){
      short8 a = *(short8*)&S[(wm<<4) + (lane & 15)][jt + (kt<<5) + ((lane >> 4) << 3)];
      #pragma unroll
      for (int ntl = 0; ntl < 2; ntl++){
        short8 bf = *(short8*)&KVf[((((kt<<2) + (wn<<1) + ntl)*64 + lane)) << 3];
        acco[ntl] = __builtin_amdgcn_mfma_f32_16x16x32_bf16(a, bf, acco[ntl], 0, 0, 0);
      }
    }
    __syncthreads();
  }

  #pragma unroll
  for (int ntl = 0; ntl < 2; ntl++){
    int d = h*64 + (wn<<5) + (ntl<<4) + cn;
    #pragma unroll
    for (int r = 0; r < 4; r++){
      int srow = (wm<<4) + (cq<<2) + r;
      obf[((size_t)(b*Lq + q0 + srow))*512 + d] = f2bf(acco[ntl][r] * inv[srow]);
    }
  }
}

// ---------- GAT scores ----------
__global__ __launch_bounds__(256) void gat1_scores(const float* __restrict__ hall,
    const float* __restrict__ gata, float* __restrict__ s1, float* __restrict__ s2)
{
  int gw = blockIdx.x * 4 + (threadIdx.x >> 6);
  int lane = threadIdx.x & 63;
  int h = gw >> 13;
  int r = gw & 8191;
  float v = hall[(size_t)r * D_ + h * 64 + lane];
  float p1 = v * gata[h * 128 + lane];
  float p2 = v * gata[h * 128 + 64 + lane];
  #pragma unroll
  for (int o = 32; o; o >>= 1){ p1 += __shfl_down(p1, o, 64); p2 += __shfl_down(p2, o, 64); }
  if (lane == 0){ s1[h * 8192 + r] = p1; s2[h * 8192 + r] = p2; }
}
__global__ __launch_bounds__(256) void gat2_scores(const float* __restrict__ h2,
    const float* __restrict__ gatoa, float* __restrict__ s1, float* __restrict__ s2)
{
  int r = blockIdx.x * 4 + (threadIdx.x >> 6);
  int lane = threadIdx.x & 63;
  float p1 = 0.0f, p2 = 0.0f;
  for (int c = lane; c < D_; c += 64){
    float v = h2[(size_t)r * D_ + c];
    p1 += v * gatoa[c];
    p2 += v * gatoa[D_ + c];
  }
  #pragma unroll
  for (int o = 32; o; o >>= 1){ p1 += __shfl_down(p1, o, 64); p2 += __shfl_down(p2, o, 64); }
  if (lane == 0){ s1[r] = p1; s2[r] = p2; }
}

// ---------- MFMA GAT layer-1 attention (bf16 S/out, transposed bf16 hall, reg prefetch) ----------
__global__ __launch_bounds__(256) void gat1_mfma(const u32* __restrict__ mbits,
    const float* __restrict__ s1, const float* __restrict__ s2,
    const u16* __restrict__ ht, u16* __restrict__ xcb)
{
  __shared__ __align__(16) u16 S[32][SPS];
  __shared__ __align__(16) u16 Vf[8*64*8];
  __shared__ float inv[32];

  int tid = threadIdx.x, lane = tid & 63, wave = tid >> 6;
  int wm = wave & 1, wn = wave >> 1;
  int q0 = blockIdx.x << 5, h = blockIdx.y, b = blockIdx.z;
  int hb = h * 8192 + b * 512;

  int keybOff[2]; const u16* vSrc[2];
  #pragma unroll
  for (int r = 0; r < 2; r++){
    int u = tid + (r << 8);
    int l = u & 63, unit = u >> 6;
    int kt = unit >> 2, nt = unit & 3;
    int d = (nt<<4) + (l & 15);
    keybOff[r] = (kt<<5) + ((l >> 4) << 3);
    vSrc[r] = ht + ((size_t)(h*64 + d))*(size_t)(B_*N_) + (size_t)b*512 + keybOff[r];
  }
  short8 vR[2];
  auto loadV = [&](int jt){
    #pragma unroll
    for (int r = 0; r < 2; r++) vR[r] = *(const short8*)(vSrc[r] + jt);
  };

  for (int x = tid; x < 32*128; x += 256){
    int row = x >> 7, c4 = (x & 127) << 2;
    float s1v = s1[hb + q0 + row];
    float4 s2v = *(const float4*)(s2 + hb + c4);
    size_t bi = ((size_t)(b*512) + q0 + row)*512 + c4;
    u32 w = mbits[bi >> 5] >> (bi & 31);
    float t; u16 q4[4];
    t = s1v + s2v.x; t = t>0?t:0.2f*t; q4[0] = f2bf((w     & 1u) ? t : -9.0e15f);
    t = s1v + s2v.y; t = t>0?t:0.2f*t; q4[1] = f2bf(((w>>1) & 1u) ? t : -9.0e15f);
    t = s1v + s2v.z; t = t>0?t:0.2f*t; q4[2] = f2bf(((w>>2) & 1u) ? t : -9.0e15f);
    t = s1v + s2v.w; t = t>0?t:0.2f*t; q4[3] = f2bf(((w>>3) & 1u) ? t : -9.0e15f);
    *(short4v*)&S[row][c4] = *(short4v*)q4;
  }
  loadV(0);
  __syncthreads();

  {
    int row = tid >> 3, part = tid & 7;
    int base = part << 6;
    float mx = -3.0e38f;
    #pragma unroll
    for (int c = 0; c < 8; c++){
      int off = base + (((c + part) & 7) << 3);
      short8 sv = *(short8*)&S[row][off];
      #pragma unroll
      for (int jj = 0; jj < 8; jj++) mx = fmaxf(mx, bf2f((u16)sv[jj]));
    }
    #pragma unroll
    for (int m = 1; m < 8; m <<= 1) mx = fmaxf(mx, __shfl_xor(mx, m, 8));
    float sum = 0.0f;
    #pragma unroll
    for (int c = 0; c < 8; c++){
      int off = base + (((c + part) & 7) << 3);
      short8 sv = *(short8*)&S[row][off];
      u16 t8[8];
      #pragma unroll
      for (int jj = 0; jj < 8; jj++){
        float p = __expf(bf2f((u16)sv[jj]) - mx);
        sum += p;
        t8[jj] = f2bf(p);
      }
      *(short8*)&S[row][off] = *(short8*)t8;
    }
    #pragma unroll
    for (int m = 1; m < 8; m <<= 1) sum += __shfl_xor(sum, m, 8);
    if (part == 0) inv[row] = 1.0f / sum;
  }
  __syncthreads();

  f32x4 acco[2] = {};
  for (int jt = 0; jt < 512; jt += 64){
    #pragma unroll
    for (int r = 0; r < 2; r++) *(short8*)&Vf[(size_t)(tid + (r<<8)) * 8] = vR[r];
    __syncthreads();
    if (jt + 64 < 512) loadV(jt + 64);
    #pragma unroll
    for (int kt = 0; kt < 2; kt++){
      short8 a = *(short8*)&S[(wm<<4) + (lane & 15)][jt + (kt<<5) + ((lane >> 4) << 3)];
      #pragma unroll
      for (int ntl = 0; ntl < 2; ntl++){
        short8 bf = *(short8*)&Vf[((((kt<<2) + (wn<<1) + ntl)*64 + lane)) << 3];
        acco[ntl] = __builtin_amdgcn_mfma_f32_16x16x32_bf16(a, bf, acco[ntl], 0, 0, 0);
      }
    }
    __syncthreads();
  }

  int cq = lane >> 4, cn = lane & 15;
  #pragma unroll
  for (int ntl = 0; ntl < 2; ntl++){
    int d = h*64 + (wn<<5) + (ntl<<4) + cn;
    #pragma unroll
    for (int r = 0; r < 4; r++){
      int srow = (wm<<4) + (cq<<2) + r;
      float val = acco[ntl][r] * inv[srow];
      val = val > 0.0f ? val : expf(val) - 1.0f;
      xcb[((size_t)(b*512 + q0 + srow))*512 + d] = f2bf(val);
    }
  }
}

// ---------- GAT output-layer probabilities (bit-packed mask, bf16 P out) ----------
__global__ __launch_bounds__(256) void gat2_prob(const u32* __restrict__ mbits,
    const float* __restrict__ s1, const float* __restrict__ s2, u16* __restrict__ P)
{
  __shared__ float red[4];
  int r = blockIdx.x, tid = threadIdx.x;
  int b = r >> 9;
  float s1v = s1[r];
  float e0, e1;
  {
    size_t base = (size_t)r * 512;
    u32 w0 = mbits[(base + tid) >> 5];
    u32 w1 = mbits[(base + tid + 256) >> 5];
    float t = s1v + s2[b*512 + tid];       t = t>0?t:0.2f*t;
    e0 = ((w0 >> (tid & 31)) & 1u) ? t : -9.0e15f;
    t = s1v + s2[b*512 + tid + 256];       t = t>0?t:0.2f*t;
    e1 = ((w1 >> (tid & 31)) & 1u) ? t : -9.0e15f;
  }
  float mx = block_max(fmaxf(e0, e1), red);
  float p0 = __expf(e0 - mx), p1 = __expf(e1 - mx);
  float s = block_sum(p0 + p1, red);
  float inv = 1.0f / s;
  P[(size_t)r*512 + tid]       = f2bf(p0 * inv);
  P[(size_t)r*512 + tid + 256] = f2bf(p1 * inv);
}

// ---------- fused dual-LayerNorm + relu (+ optional resid) ----------
__global__ __launch_bounds__(256) void ln2_relu_k(
    const float* __restrict__ xa, const float* __restrict__ xb,
    const float* __restrict__ ga, const float* __restrict__ ba,
    const float* __restrict__ gb, const float* __restrict__ bb,
    const float* __restrict__ resid, float* __restrict__ out)
{
  __shared__ float2 red[4];
  int r = blockIdx.x, tid = threadIdx.x;
  const float* Ax = xa + (size_t)r * D_;
  const float* Bx = xb + (size_t)r * D_;
  float a0 = Ax[tid], a1 = Ax[tid + 256];
  float b0 = Bx[tid], b1 = Bx[tid + 256];
  float2 s = block_red2(a0 + a1, b0 + b1, red);
  float mua = s.x * (1.0f/512.0f), mub = s.y * (1.0f/512.0f);
  float da0 = a0 - mua, da1 = a1 - mua, db0 = b0 - mub, db1 = b1 - mub;
  float2 v = block_red2(da0*da0 + da1*da1, db0*db0 + db1*db1, red);
  float ia = rsqrtf(v.x * (1.0f/512.0f) + 1e-6f);
  float ib = rsqrtf(v.y * (1.0f/512.0f) + 1e-6f);
  float o0 = da0*ia*ga[tid]     + ba[tid]     + db0*ib*gb[tid]     + bb[tid];
  float o1 = da1*ia*ga[tid+256] + ba[tid+256] + db1*ib*gb[tid+256] + bb[tid+256];
  o0 = o0 > 0.0f ? o0 : 0.0f;
  o1 = o1 > 0.0f ? o1 : 0.0f;
  if (resid){ o0 += resid[(size_t)r*D_ + tid]; o1 += resid[(size_t)r*D_ + tid + 256]; }
  out[(size_t)r*D_ + tid]       = o0;
  out[(size_t)r*D_ + tid + 256] = o1;
}

// ---------- host helper: append job ----------
static void add_job(GJobs& js, int& nb, const float* A, const u16* Ab, const u16* W,
                    const float* rs, float* C, u16* Cb, u16* Ct, int M, int mode){
  js.j[js.nj] = GJob{A, Ab, W, rs, C, Cb, Ct, M, mode, nb};
  nb += 4 * (M >> 7);
  js.nj++;
}

extern "C" void kernel_launch(void* const* d_in, const int* in_sizes, int n_in,
                              void* d_out, int out_size, void* d_ws, size_t ws_size,
                              hipStream_t stream) {
  (void)in_sizes; (void)n_in; (void)out_size; (void)ws_size;

  const float* xf    = (const float*)d_in[0];
  const int* adj_i   = (const int*)d_in[2];
  const int* adj_s   = (const int*)d_in[3];
  const int* adj_is  = (const int*)d_in[4];
  const int* adj_si  = (const int*)d_in[5];
  const float* intent= (const float*)d_in[6];
  const float* gatW  = (const float*)d_in[7];
  const float* gata  = (const float*)d_in[8];
  const float* gatoW = (const float*)d_in[9];
  const float* gatoa = (const float*)d_in[10];
  const float* mhaw  = (const float*)d_in[11];
  const float* lng   = (const float*)d_in[12];
  const float* lnb   = (const float*)d_in[13];
  const float* linW1 = (const float*)d_in[14];
  const float* linb1 = (const float*)d_in[15];
  const float* linW2 = (const float*)d_in[16];
  const float* linb2 = (const float*)d_in[17];

  float* out0 = (float*)d_out;                   // slot_out      [B,N,D]
  float* out1 = out0 + BND;                      // slot_logits   [B,N,OUT]
  float* out2 = out1 + (size_t)B_*N_*OUT_;       // slot_graph_out[B,N,D]

  // ---- workspace carve ----
  float* Q    = (float*)d_ws;      // BND fp32 x6
  float* K    = Q   + BND;
  float* V    = K   + BND;
  float* O    = V   + BND;
  float* TMP  = O   + BND;
  float* HB1  = TMP + BND;
  float* ha0  = HB1 + BND;         // BID x4
  float* ha1  = ha0 + BID;
  float* sqa  = ha1 + BID;
  float* ska  = sqa + BID;
  float* s1   = ska + BID;         // 65536 x2
  float* s2   = s1  + 65536;
  float* s1o  = s2  + 65536;       // 8192 x2
  float* s2o  = s1o + 8192;
  u16* Wm  = (u16*)(s2o + 8192);   // 32*DD bf16 (all mhaw mats, swizzled)
  u16* Wg  = Wm  + (size_t)32*DD;
  u16* Wgo = Wg  + DD;
  u16* W1s = Wgo + DD;
  u16* W2s = W1s + DD;
  u32* pm_s  = (u32*)(W2s + DD/4);
  u32* pm_i  = pm_s + 131072;
  u32* pm_is = pm_i + 512;
  u32* pm_si = pm_is + 8192;

  // ---- bf16 overlay carve on Q..O (4 fp32 BND bufs = 8*BND u16 units) ----
  u16* base = (u16*)Q;
  u16* qb_b2b = base;                       // BND u16 each
  u16* kb_b2b = base + (size_t)1*BND;
  u16* vt_b2b = base + (size_t)2*BND;
  u16* qb_a2b = base + (size_t)3*BND;
  u16* kb_b2a = base + (size_t)4*BND;
  u16* vt_b2a = base + (size_t)5*BND;
  u16* sm     = base + (size_t)6*BND;       // smalls, DD u16 each
  u16* q_a2a  = sm + 0*(size_t)DD;
  u16* k_a2a  = sm + 1*(size_t)DD;
  u16* vt_a2a = sm + 2*(size_t)DD;
  u16* q_b2a  = sm + 3*(size_t)DD;
  u16* k_a2b  = sm + 4*(size_t)DD;
  u16* vt_a2b = sm + 5*(size_t)DD;
  u16* o_a2a  = sm + 6*(size_t)DD;
  u16* o_b2a  = sm + 7*(size_t)DD;
  u16* o_b2b  = (u16*)out2;                 // out2 fp32 BND = 2*BND u16 scratch
  u16* o_a2b  = (u16*)out2 + (size_t)BND;
  // GAT-phase overlays (same slots, later in time):
  u16* zb  = (u16*)Q;                       // logits bf16 (slot 0, dead qb_b2b)
  u16* htb = (u16*)O;                       // = sm region (dead smalls)
  u16* xcb = (u16*)K;                       // dead pre-LN K
  u16* h2f = (u16*)O;                       // htb dead after gat1
  u16* Pb  = (u16*)HB1;

  dim3 blk(256);

  // ---- mask packing ----
  pack_mask_k<<<(B_*N_*N_)/256,   blk, 0, stream>>>(adj_s,  pm_s);
  pack_mask_k<<<(B_*NI_*NI_)/256, blk, 0, stream>>>(adj_i,  pm_i);
  pack_mask_k<<<(B_*N_*NI_)/256,  blk, 0, stream>>>(adj_is, pm_is);
  pack_mask_k<<<(B_*NI_*N_)/256,  blk, 0, stream>>>(adj_si, pm_si);

  // ---- weight prep ----
  swz_k<<<dim3(128, 32), blk, 0, stream>>>(mhaw,  Wm,  D_,   DD, DD);
  swz_gatW_k<<<128, blk, 0, stream>>>(gatW, Wg);
  swz_k<<<dim3(128, 1), blk, 0, stream>>>(gatoW, Wgo, D_,   0, 0);
  swz_k<<<dim3(128, 1), blk, 0, stream>>>(linW1, W1s, D_,   0, 0);
  swz_k<<<dim3(32,  1), blk, 0, stream>>>(linW2, W2s, OUT_, 0, 0);

  bcast_k<<<BID/256, blk, 0, stream>>>(intent, ha0, BID);

  // ================= layer 0 =================
  // Phase A: all 12 projections in one launch (smalls first)
  {
    GJobs pa{}; int nb = 0;
    add_job(pa, nb, ha0, 0, Wm +  (size_t)0*DD, 0, 0, q_a2a,  0, 512, 2);
    add_job(pa, nb, ha0, 0, Wm +  (size_t)1*DD, 0, 0, k_a2a,  0, 512, 2);
    add_job(pa, nb, ha0, 0, Wm +  (size_t)2*DD, 0, 0, 0, vt_a2a, 512, 4);
    add_job(pa, nb, ha0, 0, Wm + (size_t)12*DD, 0, 0, q_b2a,  0, 512, 2);
    add_job(pa, nb, ha0, 0, Wm +  (size_t)9*DD, 0, 0, k_a2b,  0, 512, 2);
    add_job(pa, nb, ha0, 0, Wm + (size_t)10*DD, 0, 0, 0, vt_a2b, 512, 4);
    add_job(pa, nb, xf,  0, Wm + (size_t)13*DD, 0, 0, kb_b2a, 0, 8192, 2);
    add_job(pa, nb, xf,  0, Wm + (size_t)14*DD, 0, 0, 0, vt_b2a, 8192, 4);
    add_job(pa, nb, xf,  0, Wm +  (size_t)4*DD, 0, 0, qb_b2b, 0, 8192, 2);
    add_job(pa, nb, xf,  0, Wm +  (size_t)5*DD, 0, 0, kb_b2b, 0, 8192, 2);
    add_job(pa, nb, xf,  0, Wm +  (size_t)6*DD, 0, 0, 0, vt_b2b, 8192, 4);
    add_job(pa, nb, xf,  0, Wm +  (size_t)8*DD, 0, 0, qb_a2b, 0, 8192, 2);
    gemm_multi<<<nb, blk, 0, stream>>>(pa);
  }
  // Phase B: 4 attentions
  attn_mfma<<<dim3(1, NH_, B_),  blk, 0, stream>>>(q_a2a,  k_a2a,  vt_a2a, pm_i,  o_a2a, NI_, NI_);
  attn_mfma<<<dim3(1, NH_, B_),  blk, 0, stream>>>(q_b2a,  kb_b2a, vt_b2a, pm_si, o_b2a, NI_, N_);
  attn_mfma<<<dim3(16, NH_, B_), blk, 0, stream>>>(qb_b2b, kb_b2b, vt_b2b, pm_s,  o_b2b, N_,  N_);
  attn_mfma<<<dim3(16, NH_, B_), blk, 0, stream>>>(qb_a2b, k_a2b,  vt_a2b, pm_is, o_a2b, N_,  NI_);
  // Phase C: 4 out-projections in one launch
  {
    GJobs pc{}; int nb = 0;
    add_job(pc, nb, 0, o_a2a, Wm +  (size_t)3*DD, ha0, sqa, 0, 0, 512, 1);
    add_job(pc, nb, 0, o_b2a, Wm + (size_t)15*DD, ha0, ska, 0, 0, 512, 1);
    add_job(pc, nb, 0, o_b2b, Wm +  (size_t)7*DD, xf,  HB1, 0, 0, 8192, 1);
    add_job(pc, nb, 0, o_a2b, Wm + (size_t)11*DD, xf,  TMP, 0, 0, 8192, 1);
    gemm_multi<<<nb, blk, 0, stream>>>(pc);
  }
  ln2_relu_k<<<dim3(B_*NI_), blk, 0, stream>>>(sqa, ska, lng + 0*D_, lnb + 0*D_,
               lng + 3*D_, lnb + 3*D_, nullptr, ha1);                      // h_a1
  ln2_relu_k<<<dim3(B_*N_), blk, 0, stream>>>(HB1, TMP, lng + 1*D_, lnb + 1*D_,
               lng + 2*D_, lnb + 2*D_, nullptr, HB1);                      // h_b1

  // ================= layer 1 (a2a/b2a dead) =================
  {
    GJobs pe{}; int nb = 0;
    add_job(pe, nb, ha1, 0, Wm + (size_t)25*DD, 0, 0, k_a2b,  0, 512, 2);
    add_job(pe, nb, ha1, 0, Wm + (size_t)26*DD, 0, 0, 0, vt_a2b, 512, 4);
    add_job(pe, nb, HB1, 0, Wm + (size_t)20*DD, 0, 0, qb_b2b, 0, 8192, 2);
    add_job(pe, nb, HB1, 0, Wm + (size_t)21*DD, 0, 0, kb_b2b, 0, 8192, 2);
    add_job(pe, nb, HB1, 0, Wm + (size_t)22*DD, 0, 0, 0, vt_b2b, 8192, 4);
    add_job(pe, nb, HB1, 0, Wm + (size_t)24*DD, 0, 0, qb_a2b, 0, 8192, 2);
    gemm_multi<<<nb, blk, 0, stream>>>(pe);
  }
  attn_mfma<<<dim3(16, NH_, B_), blk, 0, stream>>>(qb_b2b, kb_b2b, vt_b2b, pm_s,  o_b2b, N_, N_);
  attn_mfma<<<dim3(16, NH_, B_), blk, 0, stream>>>(qb_a2b, k_a2b,  vt_a2b, pm_is, o_a2b, N_, NI_);
  {
    GJobs pg{}; int nb = 0;
    add_job(pg, nb, 0, o_b2b, Wm + (size_t)23*DD, HB1, K,   0, 0, 8192, 1);  // K overlays dead vt_b2b/qb_a2b
    add_job(pg, nb, 0, o_a2b, Wm + (size_t)27*DD, HB1, TMP, 0, 0, 8192, 1);
    gemm_multi<<<nb, blk, 0, stream>>>(pg);
  }
  ln2_relu_k<<<dim3(B_*N_), blk, 0, stream>>>(K, TMP, lng + 5*D_, lnb + 5*D_,
               lng + 6*D_, lnb + 6*D_, xf, out0);                          // slot_out = xf + h_b2

  // ---- logits (bf16 intermediate in slot 0) ----
  gemm_mfma<<<dim3(4, (B_*N_)/128), blk, 0, stream>>>(out0, nullptr, W1s, linb1, nullptr,
      nullptr, zb, nullptr, 0, D_, 1, 2, 0,0,0,0);
  gemm_mfma<<<dim3(1, (B_*N_)/128), blk, 0, stream>>>(nullptr, zb, W2s, linb2, nullptr,
      out1, nullptr, nullptr, 0, OUT_, 0, 1, 0,0,0,0);

  // ================= GAT branch =================
  gemm_mfma<<<dim3(4, (B_*N_)/128), blk, 0, stream>>>(xf, nullptr, Wg, nullptr, nullptr,
      Q, nullptr, htb, B_*N_, D_, 0, 5, 0,0,0,0);
  gat1_scores<<<(H_*B_*N_)/4, blk, 0, stream>>>(Q, gata, s1, s2);
  gat1_mfma<<<dim3(N_/32, H_, B_), blk, 0, stream>>>(pm_s, s1, s2, htb, xcb);
  gemm_mfma<<<dim3(4, (B_*N_)/128), blk, 0, stream>>>(nullptr, xcb, Wgo, nullptr, nullptr,
      V, nullptr, h2f, 0, D_, 0, 9, 0,0,0,0);
  gat2_scores<<<(B_*N_)/4, blk, 0, stream>>>(V, gatoa, s1o, s2o);
  gat2_prob<<<B_*N_, blk, 0, stream>>>(pm_s, s1o, s2o, Pb);
  gemm_mfma<<<dim3(4, N_/128, B_), blk, 0, stream>>>(nullptr, Pb, h2f, nullptr, xf,
      out2, nullptr, nullptr, 0, D_, 2, 1,
      (size_t)N_*N_, (size_t)DD, (size_t)N_*D_, (size_t)N_*D_);
}

// Round 12
// 689.627 us; speedup vs baseline: 2.1479x; 1.0679x over previous
//
#include <hip/hip_runtime.h>

// B=16, N=512, D=512, NI=32, GH=64, H=8, L=2, OUT=128, heads=8
#define B_   16
#define N_   512
#define D_   512
#define NI_  32
#define GH_  64
#define H_   8
#define OUT_ 128
#define NH_  8

#define BND   (B_*N_*D_)     // 4194304
#define BID   (B_*NI_*D_)    // 262144
#define DD    (D_*D_)        // 262144

#define SPS 520              // S row stride in bf16

typedef unsigned short u16;
typedef unsigned int   u32;
typedef __attribute__((ext_vector_type(8))) short short8;
typedef __attribute__((ext_vector_type(4))) short short4v;
typedef __attribute__((ext_vector_type(4))) float f32x4;

__device__ __forceinline__ u16 f2bf(float f){
  u32 x = __float_as_uint(f);
  x += 0x7fffu + ((x >> 16) & 1u);   // RNE
  return (u16)(x >> 16);
}
__device__ __forceinline__ float bf2f(u16 s){
  return __uint_as_float((u32)s << 16);
}

// blockDim must be 256
__device__ __forceinline__ float block_sum(float v, float* sm){
  #pragma unroll
  for (int o = 32; o; o >>= 1) v += __shfl_down(v, o, 64);
  int lane = threadIdx.x & 63, w = threadIdx.x >> 6;
  __syncthreads();
  if (lane == 0) sm[w] = v;
  __syncthreads();
  return sm[0] + sm[1] + sm[2] + sm[3];
}
__device__ __forceinline__ float block_max(float v, float* sm){
  #pragma unroll
  for (int o = 32; o; o >>= 1) v = fmaxf(v, __shfl_down(v, o, 64));
  int lane = threadIdx.x & 63, w = threadIdx.x >> 6;
  __syncthreads();
  if (lane == 0) sm[w] = v;
  __syncthreads();
  return fmaxf(fmaxf(sm[0], sm[1]), fmaxf(sm[2], sm[3]));
}
__device__ __forceinline__ float2 block_red2(float a, float b, float2* sm){
  #pragma unroll
  for (int o = 32; o; o >>= 1){ a += __shfl_down(a, o, 64); b += __shfl_down(b, o, 64); }
  int lane = threadIdx.x & 63, w = threadIdx.x >> 6;
  __syncthreads();
  if (lane == 0) sm[w] = make_float2(a, b);
  __syncthreads();
  float2 r;
  r.x = sm[0].x + sm[1].x + sm[2].x + sm[3].x;
  r.y = sm[0].y + sm[1].y + sm[2].y + sm[3].y;
  return r;
}

// ---------- mask bit-pack (adj>0 -> 1 bit) ----------
__global__ __launch_bounds__(256) void pack_mask_k(const int* __restrict__ adj, u32* __restrict__ bits){
  int i = blockIdx.x * 256 + threadIdx.x;
  unsigned long long m = __ballot(adj[i] > 0);
  if ((threadIdx.x & 63) == 0){
    bits[(i >> 5)]     = (u32)m;
    bits[(i >> 5) + 1] = (u32)(m >> 32);
  }
}

// ---------- elementwise ----------
__global__ __launch_bounds__(256) void bcast_k(const float* __restrict__ s, float* __restrict__ d, int n){
  int i = blockIdx.x * 256 + threadIdx.x;
  if (i < n) d[i] = s[i & (NI_*D_ - 1)];
}
// fp32 -> bf16 vector convert (n multiple of 2048)
__global__ __launch_bounds__(256) void cvt_bf16_k(const float* __restrict__ s, u16* __restrict__ d){
  int i = (blockIdx.x * 256 + threadIdx.x) * 8;
  float4 f0 = *(const float4*)(s + i), f1 = *(const float4*)(s + i + 4);
  u16 t8[8] = {f2bf(f0.x),f2bf(f0.y),f2bf(f0.z),f2bf(f0.w),
               f2bf(f1.x),f2bf(f1.y),f2bf(f1.z),f2bf(f1.w)};
  *(short8*)&d[i] = *(short8*)t8;
}

// ---------- weight swizzle into MFMA B-fragment order ----------
__global__ __launch_bounds__(256) void swz_k(const float* __restrict__ W, u16* __restrict__ o,
                                             int Nc, size_t sW, size_t sO){
  int gw = blockIdx.x * 4 + (threadIdx.x >> 6);
  int lane = threadIdx.x & 63;
  int ntc = Nc >> 4;
  int s = gw / ntc, nt = gw - s * ntc;
  const float* Wb = W + sW * blockIdx.y;
  u16* ob = o + sO * blockIdx.y;
  int n = nt*16 + (lane & 15);
  int kb = s*32 + ((lane >> 4) << 3);
  u16 t8[8];
  #pragma unroll
  for (int j = 0; j < 8; j++) t8[j] = f2bf(Wb[(size_t)(kb + j) * Nc + n]);
  *(short8*)&ob[((size_t)(s * ntc + nt) * 64 + lane) * 8] = *(short8*)t8;
}
// gat_W [H,D,GH] -> head-major-concat [D,512], swizzled
__global__ __launch_bounds__(256) void swz_gatW_k(const float* __restrict__ gw_, u16* __restrict__ o){
  int gw = blockIdx.x * 4 + (threadIdx.x >> 6);  // 512 waves
  int lane = threadIdx.x & 63;
  int s = gw >> 5, nt = gw & 31;
  int n = nt*16 + (lane & 15);
  int h = n >> 6, f = n & 63;
  int kb = s*32 + ((lane >> 4) << 3);
  u16 t8[8];
  #pragma unroll
  for (int j = 0; j < 8; j++) t8[j] = f2bf(gw_[((size_t)(h*512) + kb + j) * 64 + f]);
  *(short8*)&o[((size_t)(s*32 + nt) * 64 + lane) * 8] = *(short8*)t8;
}

// ---------- MFMA GEMM (register-prefetch double-buffered) ----------
// A source: fp32 A or bf16 Ab (one non-null). K = 512 fixed.
// C modes (bitmask): 1 = fp32 C[M,Nc]; 2 = bf16 Cb[M,Nc]; 4 = bf16 transposed Cx[Nc,Mtot];
//                    8 = bf16 B-fragment order Cx (batched per row>>9, Nc must be 512).
// act: 0 none, 1 leaky, 2 elu. Batched over blockIdx.z via strides.
__global__ __launch_bounds__(256) void gemm_mfma(
    const float* __restrict__ A, const u16* __restrict__ Ab, const u16* __restrict__ Bw,
    const float* __restrict__ bias, const float* __restrict__ resid,
    float* __restrict__ C, u16* __restrict__ Cb, u16* __restrict__ Cx,
    int Mtot, int Nc, int act, int mode,
    size_t sA, size_t sB, size_t sC, size_t sR)
{
  __shared__ __align__(16) u16 As[128*64];
  __shared__ __align__(16) u16 Bs[64*128];
  if (A)  A  += sA * blockIdx.z;
  if (Ab) Ab += sA * blockIdx.z;
  Bw += sB * blockIdx.z;
  if (C) C += sC * blockIdx.z;
  if (resid) resid += sR * blockIdx.z;

  int tid = threadIdx.x, lane = tid & 63, wave = tid >> 6;
  int wm = wave & 1, wn = wave >> 1;
  int row0 = blockIdx.y << 7, col0 = blockIdx.x << 7;
  int ntc = Nc >> 4, nt0 = col0 >> 4;

  const float* aSrcF[4];
  const u16*   aSrcB[4];
  #pragma unroll
  for (int r = 0; r < 4; r++){
    int u = tid + (r << 8);
    int l = u & 63, kt = (u >> 6) & 1, mt = u >> 7;
    size_t off = (size_t)(row0 + (mt << 4) + (l & 15)) * 512 + (kt << 5) + ((l >> 4) << 3);
    aSrcF[r] = A  ? A  + off : nullptr;
    aSrcB[r] = Ab ? Ab + off : nullptr;
  }
  const u16* bSrc[2][2];
  #pragma unroll
  for (int kt = 0; kt < 2; kt++)
    #pragma unroll
    for (int r = 0; r < 2; r++)
      bSrc[kt][r] = Bw + (((size_t)(kt * ntc + nt0)) << 9) + (((size_t)(tid + (r << 8))) << 3);
  size_t bStep = (size_t)ntc << 10;

  float4 aF[4][2];
  short8 aB[4];
  short8 bP[2][2];

  auto doLoad = [&](int ks){
    if (Ab){
      #pragma unroll
      for (int r = 0; r < 4; r++) aB[r] = *(const short8*)(aSrcB[r] + (ks << 6));
    } else {
      #pragma unroll
      for (int r = 0; r < 4; r++){
        aF[r][0] = *(const float4*)(aSrcF[r] + (ks << 6));
        aF[r][1] = *(const float4*)(aSrcF[r] + (ks << 6) + 4);
      }
    }
    #pragma unroll
    for (int kt = 0; kt < 2; kt++)
      #pragma unroll
      for (int r = 0; r < 2; r++)
        bP[kt][r] = *(const short8*)(bSrc[kt][r] + (size_t)ks * bStep);
  };

  f32x4 acc[4][4] = {};
  doLoad(0);
  for (int ks = 0; ks < 8; ks++){
    if (Ab){
      #pragma unroll
      for (int r = 0; r < 4; r++) *(short8*)&As[(size_t)(tid + (r<<8)) * 8] = aB[r];
    } else {
      #pragma unroll
      for (int r = 0; r < 4; r++){
        u16 t8[8] = {f2bf(aF[r][0].x), f2bf(aF[r][0].y), f2bf(aF[r][0].z), f2bf(aF[r][0].w),
                     f2bf(aF[r][1].x), f2bf(aF[r][1].y), f2bf(aF[r][1].z), f2bf(aF[r][1].w)};
        *(short8*)&As[(size_t)(tid + (r<<8)) * 8] = *(short8*)t8;
      }
    }
    #pragma unroll
    for (int kt = 0; kt < 2; kt++)
      #pragma unroll
      for (int r = 0; r < 2; r++)
        *(short8*)&Bs[(kt << 12) + ((size_t)(tid + (r<<8)) << 3)] = bP[kt][r];
    __syncthreads();
    if (ks < 7) doLoad(ks + 1);
    #pragma unroll
    for (int kt = 0; kt < 2; kt++){
      short8 a[4], b[4];
      #pragma unroll
      for (int i = 0; i < 4; i++)
        a[i] = *(short8*)&As[(((((wm<<2)+i) << 1) + kt) * 64 + lane) << 3];
      #pragma unroll
      for (int n = 0; n < 4; n++)
        b[n] = *(short8*)&Bs[(((kt << 3) + (wn<<2) + n) * 64 + lane) << 3];
      #pragma unroll
      for (int i = 0; i < 4; i++)
        #pragma unroll
        for (int n = 0; n < 4; n++)
          acc[i][n] = __builtin_amdgcn_mfma_f32_16x16x32_bf16(a[i], b[n], acc[i][n], 0, 0, 0);
    }
    __syncthreads();
  }

  int cq = lane >> 4, cn = lane & 15;
  #pragma unroll
  for (int i = 0; i < 4; i++){
    #pragma unroll
    for (int n = 0; n < 4; n++){
      int col = col0 + (wn<<6) + (n<<4) + cn;
      float bi = bias ? bias[col] : 0.0f;
      int rowb = row0 + (wm<<6) + (i<<4) + (cq<<2);
      float vals[4];
      #pragma unroll
      for (int r = 0; r < 4; r++){
        float c = acc[i][n][r] + bi;
        if (act == 1) c = c > 0.0f ? c : 0.2f * c;
        else if (act == 2) c = c > 0.0f ? c : expf(c) - 1.0f;
        if (resid) c += resid[(size_t)(rowb + r) * Nc + col];
        vals[r] = c;
      }
      if (mode & 1){
        #pragma unroll
        for (int r = 0; r < 4; r++) C[(size_t)(rowb + r) * Nc + col] = vals[r];
      }
      if (mode & 2){
        #pragma unroll
        for (int r = 0; r < 4; r++) Cb[(size_t)(rowb + r) * Nc + col] = f2bf(vals[r]);
      }
      if (mode & 4){
        u16 t4[4] = {f2bf(vals[0]), f2bf(vals[1]), f2bf(vals[2]), f2bf(vals[3])};
        *(short4v*)&Cx[(size_t)col * Mtot + rowb] = *(short4v*)t4;
      }
      if (mode & 8){
        u16 t4[4] = {f2bf(vals[0]), f2bf(vals[1]), f2bf(vals[2]), f2bf(vals[3])};
        int kk = rowb & 511;
        int ln_ = (((kk >> 3) & 3) << 4) | (col & 15);
        size_t off = (size_t)(rowb >> 9) * DD
                   + ((((size_t)(kk >> 5) * 32 + ((col & 511) >> 4)) * 64 + ln_) << 3) + (kk & 7);
        *(short4v*)&Cx[off] = *(short4v*)t4;
      }
    }
  }
}

// ---------- multi-job GEMM: co-schedule independent Nc=512 GEMMs in one launch ----------
// Jobs found by blockIdx.x range. Per job: A fp32 or Ab bf16; mode 1(fp32+resid)/2(bf16)/4(bf16 T).
struct GJob {
  const float* A; const u16* Ab; const u16* W; const float* resid;
  float* C; u16* Cb; u16* Ct;
  int M; int mode; int blk0;
};
struct GJobs { GJob j[12]; int nj; };

__global__ __launch_bounds__(256) void gemm_multi(GJobs js)
{
  __shared__ __align__(16) u16 As[128*64];
  __shared__ __align__(16) u16 Bs[64*128];
  int jx = 0;
  #pragma unroll
  for (int t = 1; t < 12; t++)
    if (t < js.nj && (int)blockIdx.x >= js.j[t].blk0) jx = t;
  const float* A     = js.j[jx].A;
  const u16*   Ab    = js.j[jx].Ab;
  const u16*   Bw    = js.j[jx].W;
  const float* resid = js.j[jx].resid;
  float* C  = js.j[jx].C;
  u16*   Cb = js.j[jx].Cb;
  u16*   Ct = js.j[jx].Ct;
  int Mtot = js.j[jx].M, mode = js.j[jx].mode;
  int local = blockIdx.x - js.j[jx].blk0;
  int col0 = (local & 3) << 7, row0 = (local >> 2) << 7;
  int nt0 = col0 >> 4;                       // ntc = 32 (Nc=512)

  int tid = threadIdx.x, lane = tid & 63, wave = tid >> 6;
  int wm = wave & 1, wn = wave >> 1;

  const float* aSrcF[4];
  const u16*   aSrcB[4];
  #pragma unroll
  for (int r = 0; r < 4; r++){
    int u = tid + (r << 8);
    int l = u & 63, kt = (u >> 6) & 1, mt = u >> 7;
    size_t off = (size_t)(row0 + (mt << 4) + (l & 15)) * 512 + (kt << 5) + ((l >> 4) << 3);
    aSrcF[r] = A  ? A  + off : nullptr;
    aSrcB[r] = Ab ? Ab + off : nullptr;
  }
  const u16* bSrc[2][2];
  #pragma unroll
  for (int kt = 0; kt < 2; kt++)
    #pragma unroll
    for (int r = 0; r < 2; r++)
      bSrc[kt][r] = Bw + (((size_t)(kt * 32 + nt0)) << 9) + (((size_t)(tid + (r << 8))) << 3);

  float4 aF[4][2];
  short8 aB[4];
  short8 bP[2][2];
  auto doLoad = [&](int ks){
    if (Ab){
      #pragma unroll
      for (int r = 0; r < 4; r++) aB[r] = *(const short8*)(aSrcB[r] + (ks << 6));
    } else {
      #pragma unroll
      for (int r = 0; r < 4; r++){
        aF[r][0] = *(const float4*)(aSrcF[r] + (ks << 6));
        aF[r][1] = *(const float4*)(aSrcF[r] + (ks << 6) + 4);
      }
    }
    #pragma unroll
    for (int kt = 0; kt < 2; kt++)
      #pragma unroll
      for (int r = 0; r < 2; r++)
        bP[kt][r] = *(const short8*)(bSrc[kt][r] + ((size_t)ks << 15));   // 32<<10 per ks
  };

  f32x4 acc[4][4] = {};
  doLoad(0);
  for (int ks = 0; ks < 8; ks++){
    if (Ab){
      #pragma unroll
      for (int r = 0; r < 4; r++) *(short8*)&As[(size_t)(tid + (r<<8)) * 8] = aB[r];
    } else {
      #pragma unroll
      for (int r = 0; r < 4; r++){
        u16 t8[8] = {f2bf(aF[r][0].x), f2bf(aF[r][0].y), f2bf(aF[r][0].z), f2bf(aF[r][0].w),
                     f2bf(aF[r][1].x), f2bf(aF[r][1].y), f2bf(aF[r][1].z), f2bf(aF[r][1].w)};
        *(short8*)&As[(size_t)(tid + (r<<8)) * 8] = *(short8*)t8;
      }
    }
    #pragma unroll
    for (int kt = 0; kt < 2; kt++)
      #pragma unroll
      for (int r = 0; r < 2; r++)
        *(short8*)&Bs[(kt << 12) + ((size_t)(tid + (r<<8)) << 3)] = bP[kt][r];
    __syncthreads();
    if (ks < 7) doLoad(ks + 1);
    #pragma unroll
    for (int kt = 0; kt < 2; kt++){
      short8 a[4], b[4];
      #pragma unroll
      for (int i = 0; i < 4; i++)
        a[i] = *(short8*)&As[(((((wm<<2)+i) << 1) + kt) * 64 + lane) << 3];
      #pragma unroll
      for (int n = 0; n < 4; n++)
        b[n] = *(short8*)&Bs[(((kt << 3) + (wn<<2) + n) * 64 + lane) << 3];
      #pragma unroll
      for (int i = 0; i < 4; i++)
        #pragma unroll
        for (int n = 0; n < 4; n++)
          acc[i][n] = __builtin_amdgcn_mfma_f32_16x16x32_bf16(a[i], b[n], acc[i][n], 0, 0, 0);
    }
    __syncthreads();
  }

  int cq = lane >> 4, cn = lane & 15;
  #pragma unroll
  for (int i = 0; i < 4; i++){
    #pragma unroll
    for (int n = 0; n < 4; n++){
      int col = col0 + (wn<<6) + (n<<4) + cn;
      int rowb = row0 + (wm<<6) + (i<<4) + (cq<<2);
      float vals[4];
      #pragma unroll
      for (int r = 0; r < 4; r++){
        float c = acc[i][n][r];
        if (resid) c += resid[(size_t)(rowb + r) * 512 + col];
        vals[r] = c;
      }
      if (mode == 1){
        #pragma unroll
        for (int r = 0; r < 4; r++) C[(size_t)(rowb + r) * 512 + col] = vals[r];
      } else if (mode == 2){
        #pragma unroll
        for (int r = 0; r < 4; r++) Cb[(size_t)(rowb + r) * 512 + col] = f2bf(vals[r]);
      } else {
        u16 t4[4] = {f2bf(vals[0]), f2bf(vals[1]), f2bf(vals[2]), f2bf(vals[3])};
        *(short4v*)&Ct[(size_t)col * Mtot + rowb] = *(short4v*)t4;
      }
    }
  }
}

// ---------- MFMA MHA attention (bf16 in/out, V transposed, LDS mask, reg prefetch) ----------
__global__ __launch_bounds__(256) void attn_mfma(
    const u16* __restrict__ q, const u16* __restrict__ k, const u16* __restrict__ vt,
    const u32* __restrict__ mbits, u16* __restrict__ obf, int Lq, int Lk)
{
  __shared__ __align__(16) u16 S[32][SPS];      // scores, then P (bf16)
  __shared__ __align__(16) u16 KVf[8*64*8];     // K^T / V B-fragments
  __shared__ u32 maskw[32*16];
  __shared__ float inv[32];

  int tid = threadIdx.x, lane = tid & 63, wave = tid >> 6;
  int wm = wave & 1, wn = wave >> 1;
  int q0 = blockIdx.x << 5, h = blockIdx.y, b = blockIdx.z;
  int ntiles = (Lk + 63) >> 6;
  size_t vM = (size_t)B_ * Lk;

  if (Lk == 512){
    #pragma unroll
    for (int r = 0; r < 2; r++){
      int x = tid + (r << 8);
      maskw[x] = mbits[(((size_t)(b*Lq) + q0 + (x >> 4)) << 4) + (x & 15)];
    }
  } else {
    if (tid < 32) maskw[tid << 4] = mbits[(size_t)(b*Lq) + q0 + tid];
  }

  short8 aq[2];
  #pragma unroll
  for (int kt = 0; kt < 2; kt++)
    aq[kt] = *(const short8*)(q + ((size_t)(b*Lq + q0 + (wm<<4) + (lane & 15)))*512
                                + h*64 + (kt<<5) + ((lane >> 4) << 3));

  int cq = lane >> 4, cn = lane & 15;

  int keyOff[2]; const u16* kSrc[2];
  int keybOff[2]; const u16* vSrc[2];
  #pragma unroll
  for (int r = 0; r < 2; r++){
    int u = tid + (r << 8);
    int l = u & 63, unit = u >> 6;
    int kt = unit >> 2, nt = unit & 3;
    keyOff[r] = (nt<<4) + (l & 15);
    kSrc[r] = k + ((size_t)(b*Lk + keyOff[r]))*512 + h*64 + (kt<<5) + ((l >> 4) << 3);
    int d = (nt<<4) + (l & 15);
    keybOff[r] = (kt<<5) + ((l >> 4) << 3);
    vSrc[r] = vt + ((size_t)(h*64 + d))*vM + (size_t)b*Lk + keybOff[r];
  }
  short8 kR[2], vR[2];
  auto loadK = [&](int jt){
    #pragma unroll
    for (int r = 0; r < 2; r++){
      short8 val = {0,0,0,0,0,0,0,0};
      if (jt + keyOff[r] < Lk) val = *(const short8*)(kSrc[r] + (size_t)jt * 512);
      kR[r] = val;
    }
  };
  auto loadV = [&](int jt){
    #pragma unroll
    for (int r = 0; r < 2; r++){
      short8 val = {0,0,0,0,0,0,0,0};
      if (jt + keybOff[r] < Lk) val = *(const short8*)(vSrc[r] + jt);
      vR[r] = val;
    }
  };

  // ---- QK^T -> S ----
  loadK(0);
  for (int jt = 0; jt < (ntiles << 6); jt += 64){
    #pragma unroll
    for (int r = 0; r < 2; r++) *(short8*)&KVf[(size_t)(tid + (r<<8)) * 8] = kR[r];
    __syncthreads();
    if (jt + 64 < (ntiles << 6)) loadK(jt + 64);
    f32x4 accs[2] = {};
    #pragma unroll
    for (int kt = 0; kt < 2; kt++){
      #pragma unroll
      for (int ntl = 0; ntl < 2; ntl++){
        short8 bf = *(short8*)&KVf[((((kt<<2) + (wn<<1) + ntl)*64 + lane)) << 3];
        accs[ntl] = __builtin_amdgcn_mfma_f32_16x16x32_bf16(aq[kt], bf, accs[ntl], 0, 0, 0);
      }
    }
    int jb = jt + (wn<<5);
    if (jb < Lk){
      int wrd = (jt >> 5) + wn;
      #pragma unroll
      for (int r = 0; r < 4; r++){
        int srow = (wm<<4) + (cq<<2) + r;
        u32 mw = maskw[(srow << 4) + wrd];
        float e0 = ((mw >> cn) & 1u)      ? accs[0][r]*0.125f : -1.0e9f;
        float e1 = ((mw >> (16+cn)) & 1u) ? accs[1][r]*0.125f : -1.0e9f;
        S[srow][jb + cn]      = f2bf(e0);
        S[srow][jb + 16 + cn] = f2bf(e1);
      }
    } else {
      #pragma unroll
      for (int r = 0; r < 4; r++){
        int srow = (wm<<4) + (cq<<2) + r;
        S[srow][jb + cn]      = 0xFF80;
        S[srow][jb + 16 + cn] = 0xFF80;
      }
    }
    __syncthreads();
  }

  loadV(0);   // V tile 0 latency hides under softmax

  // ---- softmax (vectorized) ----
  {
    int row = tid >> 3, part = tid & 7;
    int CPT = ntiles;
    int base = part * (ntiles << 3);
    float mx = -3.0e38f;
    for (int c = 0; c < CPT; c++){
      int off = base + (((c + part) & (CPT - 1)) << 3);
      short8 sv = *(short8*)&S[row][off];
      #pragma unroll
      for (int jj = 0; jj < 8; jj++) mx = fmaxf(mx, bf2f((u16)sv[jj]));
    }
    #pragma unroll
    for (int m = 1; m < 8; m <<= 1) mx = fmaxf(mx, __shfl_xor(mx, m, 8));
    float sum = 0.0f;
    for (int c = 0; c < CPT; c++){
      int off = base + (((c + part) & (CPT - 1)) << 3);
      short8 sv = *(short8*)&S[row][off];
      u16 t8[8];
      #pragma unroll
      for (int jj = 0; jj < 8; jj++){
        float p = __expf(bf2f((u16)sv[jj]) - mx);
        sum += p;
        t8[jj] = f2bf(p);
      }
      *(short8*)&S[row][off] = *(short8*)t8;
    }
    #pragma unroll
    for (int m = 1; m < 8; m <<= 1) sum += __shfl_xor(sum, m, 8);
    if (part == 0) inv[row] = 1.0f / sum;
  }
  __syncthreads();

  // ---- PV ----
  f32x4 acco[2] = {};
  for (int jt = 0; jt < (ntiles << 6); jt += 64){
    #pragma unroll
    for (int r = 0; r < 2; r++) *(short8*)&KVf[(size_t)(tid + (r<<8)) * 8] = vR[r];
    __syncthreads();
    if (jt + 64 < (ntiles << 6)) loadV(jt + 64);
    #pragma unroll
    for (int kt = 0; kt < 2; kt++){
      short8 a = *(short8*)&S[(wm<<4) + (lane & 15)][jt + (kt<<5) + ((lane >> 4) << 3)];
      #pragma unroll
      for (int ntl = 0; ntl < 2; ntl++){
        short8 bf = *(short8*)&KVf[((((kt<<2) + (wn<<1) + ntl)*64 + lane)) << 3];
        acco[ntl] = __builtin_amdgcn_mfma_f32_16x16x32_bf16(a, bf, acco[ntl], 0, 0, 0);
      }
    }
    __syncthreads();
  }

  #pragma unroll
  for (int ntl = 0; ntl < 2; ntl++){
    int d = h*64 + (wn<<5) + (ntl<<4) + cn;
    #pragma unroll
    for (int r = 0; r < 4; r++){
      int srow = (wm<<4) + (cq<<2) + r;
      obf[((size_t)(b*Lq + q0 + srow))*512 + d] = f2bf(acco[ntl][r] * inv[srow]);
    }
  }
}

// ---------- GAT scores ----------
__global__ __launch_bounds__(256) void gat1_scores(const float* __restrict__ hall,
    const float* __restrict__ gata, float* __restrict__ s1, float* __restrict__ s2)
{
  int gw = blockIdx.x * 4 + (threadIdx.x >> 6);
  int lane = threadIdx.x & 63;
  int h = gw >> 13;
  int r = gw & 8191;
  float v = hall[(size_t)r * D_ + h * 64 + lane];
  float p1 = v * gata[h * 128 + lane];
  float p2 = v * gata[h * 128 + 64 + lane];
  #pragma unroll
  for (int o = 32; o; o >>= 1){ p1 += __shfl_down(p1, o, 64); p2 += __shfl_down(p2, o, 64); }
  if (lane == 0){ s1[h * 8192 + r] = p1; s2[h * 8192 + r] = p2; }
}
__global__ __launch_bounds__(256) void gat2_scores(const float* __restrict__ h2,
    const float* __restrict__ gatoa, float* __restrict__ s1, float* __restrict__ s2)
{
  int r = blockIdx.x * 4 + (threadIdx.x >> 6);
  int lane = threadIdx.x & 63;
  float p1 = 0.0f, p2 = 0.0f;
  for (int c = lane; c < D_; c += 64){
    float v = h2[(size_t)r * D_ + c];
    p1 += v * gatoa[c];
    p2 += v * gatoa[D_ + c];
  }
  #pragma unroll
  for (int o = 32; o; o >>= 1){ p1 += __shfl_down(p1, o, 64); p2 += __shfl_down(p2, o, 64); }
  if (lane == 0){ s1[r] = p1; s2[r] = p2; }
}

// ---------- MFMA GAT layer-1 attention (bf16 S/out, transposed bf16 hall, reg prefetch) ----------
__global__ __launch_bounds__(256) void gat1_mfma(const u32* __restrict__ mbits,
    const float* __restrict__ s1, const float* __restrict__ s2,
    const u16* __restrict__ ht, u16* __restrict__ xcb)
{
  __shared__ __align__(16) u16 S[32][SPS];
  __shared__ __align__(16) u16 Vf[8*64*8];
  __shared__ float inv[32];

  int tid = threadIdx.x, lane = tid & 63, wave = tid >> 6;
  int wm = wave & 1, wn = wave >> 1;
  int q0 = blockIdx.x << 5, h = blockIdx.y, b = blockIdx.z;
  int hb = h * 8192 + b * 512;

  int keybOff[2]; const u16* vSrc[2];
  #pragma unroll
  for (int r = 0; r < 2; r++){
    int u = tid + (r << 8);
    int l = u & 63, unit = u >> 6;
    int kt = unit >> 2, nt = unit & 3;
    int d = (nt<<4) + (l & 15);
    keybOff[r] = (kt<<5) + ((l >> 4) << 3);
    vSrc[r] = ht + ((size_t)(h*64 + d))*(size_t)(B_*N_) + (size_t)b*512 + keybOff[r];
  }
  short8 vR[2];
  auto loadV = [&](int jt){
    #pragma unroll
    for (int r = 0; r < 2; r++) vR[r] = *(const short8*)(vSrc[r] + jt);
  };

  for (int x = tid; x < 32*128; x += 256){
    int row = x >> 7, c4 = (x & 127) << 2;
    float s1v = s1[hb + q0 + row];
    float4 s2v = *(const float4*)(s2 + hb + c4);
    size_t bi = ((size_t)(b*512) + q0 + row)*512 + c4;
    u32 w = mbits[bi >> 5] >> (bi & 31);
    float t; u16 q4[4];
    t = s1v + s2v.x; t = t>0?t:0.2f*t; q4[0] = f2bf((w     & 1u) ? t : -9.0e15f);
    t = s1v + s2v.y; t = t>0?t:0.2f*t; q4[1] = f2bf(((w>>1) & 1u) ? t : -9.0e15f);
    t = s1v + s2v.z; t = t>0?t:0.2f*t; q4[2] = f2bf(((w>>2) & 1u) ? t : -9.0e15f);
    t = s1v + s2v.w; t = t>0?t:0.2f*t; q4[3] = f2bf(((w>>3) & 1u) ? t : -9.0e15f);
    *(short4v*)&S[row][c4] = *(short4v*)q4;
  }
  loadV(0);
  __syncthreads();

  {
    int row = tid >> 3, part = tid & 7;
    int base = part << 6;
    float mx = -3.0e38f;
    #pragma unroll
    for (int c = 0; c < 8; c++){
      int off = base + (((c + part) & 7) << 3);
      short8 sv = *(short8*)&S[row][off];
      #pragma unroll
      for (int jj = 0; jj < 8; jj++) mx = fmaxf(mx, bf2f((u16)sv[jj]));
    }
    #pragma unroll
    for (int m = 1; m < 8; m <<= 1) mx = fmaxf(mx, __shfl_xor(mx, m, 8));
    float sum = 0.0f;
    #pragma unroll
    for (int c = 0; c < 8; c++){
      int off = base + (((c + part) & 7) << 3);
      short8 sv = *(short8*)&S[row][off];
      u16 t8[8];
      #pragma unroll
      for (int jj = 0; jj < 8; jj++){
        float p = __expf(bf2f((u16)sv[jj]) - mx);
        sum += p;
        t8[jj] = f2bf(p);
      }
      *(short8*)&S[row][off] = *(short8*)t8;
    }
    #pragma unroll
    for (int m = 1; m < 8; m <<= 1) sum += __shfl_xor(sum, m, 8);
    if (part == 0) inv[row] = 1.0f / sum;
  }
  __syncthreads();

  f32x4 acco[2] = {};
  for (int jt = 0; jt < 512; jt += 64){
    #pragma unroll
    for (int r = 0; r < 2; r++) *(short8*)&Vf[(size_t)(tid + (r<<8)) * 8] = vR[r];
    __syncthreads();
    if (jt + 64 < 512) loadV(jt + 64);
    #pragma unroll
    for (int kt = 0; kt < 2; kt++){
      short8 a = *(short8*)&S[(wm<<4) + (lane & 15)][jt + (kt<<5) + ((lane >> 4) << 3)];
      #pragma unroll
      for (int ntl = 0; ntl < 2; ntl++){
        short8 bf = *(short8*)&Vf[((((kt<<2) + (wn<<1) + ntl)*64 + lane)) << 3];
        acco[ntl] = __builtin_amdgcn_mfma_f32_16x16x32_bf16(a, bf, acco[ntl], 0, 0, 0);
      }
    }
    __syncthreads();
  }

  int cq = lane >> 4, cn = lane & 15;
  #pragma unroll
  for (int ntl = 0; ntl < 2; ntl++){
    int d = h*64 + (wn<<5) + (ntl<<4) + cn;
    #pragma unroll
    for (int r = 0; r < 4; r++){
      int srow = (wm<<4) + (cq<<2) + r;
      float val = acco[ntl][r] * inv[srow];
      val = val > 0.0f ? val : expf(val) - 1.0f;
      xcb[((size_t)(b*512 + q0 + srow))*512 + d] = f2bf(val);
    }
  }
}

// ---------- GAT output-layer probabilities (bit-packed mask, bf16 P out) ----------
__global__ __launch_bounds__(256) void gat2_prob(const u32* __restrict__ mbits,
    const float* __restrict__ s1, const float* __restrict__ s2, u16* __restrict__ P)
{
  __shared__ float red[4];
  int r = blockIdx.x, tid = threadIdx.x;
  int b = r >> 9;
  float s1v = s1[r];
  float e0, e1;
  {
    size_t base = (size_t)r * 512;
    u32 w0 = mbits[(base + tid) >> 5];
    u32 w1 = mbits[(base + tid + 256) >> 5];
    float t = s1v + s2[b*512 + tid];       t = t>0?t:0.2f*t;
    e0 = ((w0 >> (tid & 31)) & 1u) ? t : -9.0e15f;
    t = s1v + s2[b*512 + tid + 256];       t = t>0?t:0.2f*t;
    e1 = ((w1 >> (tid & 31)) & 1u) ? t : -9.0e15f;
  }
  float mx = block_max(fmaxf(e0, e1), red);
  float p0 = __expf(e0 - mx), p1 = __expf(e1 - mx);
  float s = block_sum(p0 + p1, red);
  float inv = 1.0f / s;
  P[(size_t)r*512 + tid]       = f2bf(p0 * inv);
  P[(size_t)r*512 + tid + 256] = f2bf(p1 * inv);
}

// ---------- fused dual-LayerNorm + relu (+ optional resid, + optional bf16 copy) ----------
__global__ __launch_bounds__(256) void ln2_relu_k(
    const float* __restrict__ xa, const float* __restrict__ xb,
    const float* __restrict__ ga, const float* __restrict__ ba,
    const float* __restrict__ gb, const float* __restrict__ bb,
    const float* __restrict__ resid, float* __restrict__ out, u16* __restrict__ outb)
{
  __shared__ float2 red[4];
  int r = blockIdx.x, tid = threadIdx.x;
  const float* Ax = xa + (size_t)r * D_;
  const float* Bx = xb + (size_t)r * D_;
  float a0 = Ax[tid], a1 = Ax[tid + 256];
  float b0 = Bx[tid], b1 = Bx[tid + 256];
  float2 s = block_red2(a0 + a1, b0 + b1, red);
  float mua = s.x * (1.0f/512.0f), mub = s.y * (1.0f/512.0f);
  float da0 = a0 - mua, da1 = a1 - mua, db0 = b0 - mub, db1 = b1 - mub;
  float2 v = block_red2(da0*da0 + da1*da1, db0*db0 + db1*db1, red);
  float ia = rsqrtf(v.x * (1.0f/512.0f) + 1e-6f);
  float ib = rsqrtf(v.y * (1.0f/512.0f) + 1e-6f);
  float o0 = da0*ia*ga[tid]     + ba[tid]     + db0*ib*gb[tid]     + bb[tid];
  float o1 = da1*ia*ga[tid+256] + ba[tid+256] + db1*ib*gb[tid+256] + bb[tid+256];
  o0 = o0 > 0.0f ? o0 : 0.0f;
  o1 = o1 > 0.0f ? o1 : 0.0f;
  if (resid){ o0 += resid[(size_t)r*D_ + tid]; o1 += resid[(size_t)r*D_ + tid + 256]; }
  out[(size_t)r*D_ + tid]       = o0;
  out[(size_t)r*D_ + tid + 256] = o1;
  if (outb){
    outb[(size_t)r*D_ + tid]       = f2bf(o0);
    outb[(size_t)r*D_ + tid + 256] = f2bf(o1);
  }
}

// ---------- host helper: append job ----------
static void add_job(GJobs& js, int& nb, const float* A, const u16* Ab, const u16* W,
                    const float* rs, float* C, u16* Cb, u16* Ct, int M, int mode){
  js.j[js.nj] = GJob{A, Ab, W, rs, C, Cb, Ct, M, mode, nb};
  nb += 4 * (M >> 7);
  js.nj++;
}

extern "C" void kernel_launch(void* const* d_in, const int* in_sizes, int n_in,
                              void* d_out, int out_size, void* d_ws, size_t ws_size,
                              hipStream_t stream) {
  (void)in_sizes; (void)n_in; (void)out_size; (void)ws_size;

  const float* xf    = (const float*)d_in[0];
  const int* adj_i   = (const int*)d_in[2];
  const int* adj_s   = (const int*)d_in[3];
  const int* adj_is  = (const int*)d_in[4];
  const int* adj_si  = (const int*)d_in[5];
  const float* intent= (const float*)d_in[6];
  const float* gatW  = (const float*)d_in[7];
  const float* gata  = (const float*)d_in[8];
  const float* gatoW = (const float*)d_in[9];
  const float* gatoa = (const float*)d_in[10];
  const float* mhaw  = (const float*)d_in[11];
  const float* lng   = (const float*)d_in[12];
  const float* lnb   = (const float*)d_in[13];
  const float* linW1 = (const float*)d_in[14];
  const float* linb1 = (const float*)d_in[15];
  const float* linW2 = (const float*)d_in[16];
  const float* linb2 = (const float*)d_in[17];

  float* out0 = (float*)d_out;                   // slot_out      [B,N,D]
  float* out1 = out0 + BND;                      // slot_logits   [B,N,OUT]
  float* out2 = out1 + (size_t)B_*N_*OUT_;       // slot_graph_out[B,N,D]

  // ---- workspace carve ----
  float* Q    = (float*)d_ws;      // BND fp32 x6
  float* K    = Q   + BND;
  float* V    = K   + BND;
  float* O    = V   + BND;
  float* TMP  = O   + BND;
  float* HB1  = TMP + BND;
  float* ha0  = HB1 + BND;         // BID x4
  float* ha1  = ha0 + BID;
  float* sqa  = ha1 + BID;
  float* ska  = sqa + BID;
  float* s1   = ska + BID;         // 65536 x2
  float* s2   = s1  + 65536;
  float* s1o  = s2  + 65536;       // 8192 x2
  float* s2o  = s1o + 8192;
  u16* Wm  = (u16*)(s2o + 8192);   // 32*DD bf16 (all mhaw mats, swizzled)
  u16* Wg  = Wm  + (size_t)32*DD;
  u16* Wgo = Wg  + DD;
  u16* W1s = Wgo + DD;
  u16* W2s = W1s + DD;
  u32* pm_s  = (u32*)(W2s + DD/4);
  u32* pm_i  = pm_s + 131072;
  u32* pm_is = pm_i + 512;
  u32* pm_si = pm_is + 8192;

  // ---- bf16 overlay carve on Q..O (4 fp32 BND bufs = 8*BND u16 units) ----
  u16* base = (u16*)Q;
  u16* qb_b2b = base;                       // BND u16 each
  u16* kb_b2b = base + (size_t)1*BND;
  u16* vt_b2b = base + (size_t)2*BND;
  u16* qb_a2b = base + (size_t)3*BND;
  u16* kb_b2a = base + (size_t)4*BND;
  u16* vt_b2a = base + (size_t)5*BND;
  u16* sm     = base + (size_t)6*BND;       // smalls, DD u16 each
  u16* q_a2a  = sm + 0*(size_t)DD;
  u16* k_a2a  = sm + 1*(size_t)DD;
  u16* vt_a2a = sm + 2*(size_t)DD;
  u16* q_b2a  = sm + 3*(size_t)DD;
  u16* k_a2b  = sm + 4*(size_t)DD;
  u16* vt_a2b = sm + 5*(size_t)DD;
  u16* o_a2a  = sm + 6*(size_t)DD;
  u16* o_b2a  = sm + 7*(size_t)DD;
  u16* o_b2b  = (u16*)out2;                 // out2 fp32 BND = 2*BND u16 scratch
  u16* o_a2b  = (u16*)out2 + (size_t)BND;
  // bf16 activation copies (A-side traffic halving):
  u16* xfb  = (u16*)out0;                   // xf bf16; out0 dead until final ln2
  u16* hb1b = (u16*)out1;                   // h_b1 bf16; out1 dead until logits2
  u16* o0b  = (u16*)out1;                   // out0 bf16 (same slot, after hb1b dead)
  // GAT-phase overlays (same slots, later in time):
  u16* zb  = (u16*)Q;                       // logits bf16 (slot 0, dead qb_b2b)
  u16* htb = (u16*)O;                       // = sm region (dead smalls)
  u16* xcb = (u16*)K;                       // dead pre-LN K
  u16* h2f = (u16*)O;                       // htb dead after gat1
  u16* Pb  = (u16*)HB1;

  dim3 blk(256);

  // ---- mask packing ----
  pack_mask_k<<<(B_*N_*N_)/256,   blk, 0, stream>>>(adj_s,  pm_s);
  pack_mask_k<<<(B_*NI_*NI_)/256, blk, 0, stream>>>(adj_i,  pm_i);
  pack_mask_k<<<(B_*N_*NI_)/256,  blk, 0, stream>>>(adj_is, pm_is);
  pack_mask_k<<<(B_*NI_*N_)/256,  blk, 0, stream>>>(adj_si, pm_si);

  // ---- weight prep ----
  swz_k<<<dim3(128, 32), blk, 0, stream>>>(mhaw,  Wm,  D_,   DD, DD);
  swz_gatW_k<<<128, blk, 0, stream>>>(gatW, Wg);
  swz_k<<<dim3(128, 1), blk, 0, stream>>>(gatoW, Wgo, D_,   0, 0);
  swz_k<<<dim3(128, 1), blk, 0, stream>>>(linW1, W1s, D_,   0, 0);
  swz_k<<<dim3(32,  1), blk, 0, stream>>>(linW2, W2s, OUT_, 0, 0);

  bcast_k<<<BID/256, blk, 0, stream>>>(intent, ha0, BID);
  cvt_bf16_k<<<BND/2048, blk, 0, stream>>>(xf, xfb);

  // ================= layer 0 =================
  // Phase A: all 12 projections in one launch (smalls first; big jobs read bf16 xf)
  {
    GJobs pa{}; int nb = 0;
    add_job(pa, nb, ha0, 0, Wm +  (size_t)0*DD, 0, 0, q_a2a,  0, 512, 2);
    add_job(pa, nb, ha0, 0, Wm +  (size_t)1*DD, 0, 0, k_a2a,  0, 512, 2);
    add_job(pa, nb, ha0, 0, Wm +  (size_t)2*DD, 0, 0, 0, vt_a2a, 512, 4);
    add_job(pa, nb, ha0, 0, Wm + (size_t)12*DD, 0, 0, q_b2a,  0, 512, 2);
    add_job(pa, nb, ha0, 0, Wm +  (size_t)9*DD, 0, 0, k_a2b,  0, 512, 2);
    add_job(pa, nb, ha0, 0, Wm + (size_t)10*DD, 0, 0, 0, vt_a2b, 512, 4);
    add_job(pa, nb, 0, xfb, Wm + (size_t)13*DD, 0, 0, kb_b2a, 0, 8192, 2);
    add_job(pa, nb, 0, xfb, Wm + (size_t)14*DD, 0, 0, 0, vt_b2a, 8192, 4);
    add_job(pa, nb, 0, xfb, Wm +  (size_t)4*DD, 0, 0, qb_b2b, 0, 8192, 2);
    add_job(pa, nb, 0, xfb, Wm +  (size_t)5*DD, 0, 0, kb_b2b, 0, 8192, 2);
    add_job(pa, nb, 0, xfb, Wm +  (size_t)6*DD, 0, 0, 0, vt_b2b, 8192, 4);
    add_job(pa, nb, 0, xfb, Wm +  (size_t)8*DD, 0, 0, qb_a2b, 0, 8192, 2);
    gemm_multi<<<nb, blk, 0, stream>>>(pa);
  }
  // Phase B: 4 attentions
  attn_mfma<<<dim3(1, NH_, B_),  blk, 0, stream>>>(q_a2a,  k_a2a,  vt_a2a, pm_i,  o_a2a, NI_, NI_);
  attn_mfma<<<dim3(1, NH_, B_),  blk, 0, stream>>>(q_b2a,  kb_b2a, vt_b2a, pm_si, o_b2a, NI_, N_);
  attn_mfma<<<dim3(16, NH_, B_), blk, 0, stream>>>(qb_b2b, kb_b2b, vt_b2b, pm_s,  o_b2b, N_,  N_);
  attn_mfma<<<dim3(16, NH_, B_), blk, 0, stream>>>(qb_a2b, k_a2b,  vt_a2b, pm_is, o_a2b, N_,  NI_);
  // Phase C: 4 out-projections in one launch
  {
    GJobs pc{}; int nb = 0;
    add_job(pc, nb, 0, o_a2a, Wm +  (size_t)3*DD, ha0, sqa, 0, 0, 512, 1);
    add_job(pc, nb, 0, o_b2a, Wm + (size_t)15*DD, ha0, ska, 0, 0, 512, 1);
    add_job(pc, nb, 0, o_b2b, Wm +  (size_t)7*DD, xf,  HB1, 0, 0, 8192, 1);
    add_job(pc, nb, 0, o_a2b, Wm + (size_t)11*DD, xf,  TMP, 0, 0, 8192, 1);
    gemm_multi<<<nb, blk, 0, stream>>>(pc);
  }
  ln2_relu_k<<<dim3(B_*NI_), blk, 0, stream>>>(sqa, ska, lng + 0*D_, lnb + 0*D_,
               lng + 3*D_, lnb + 3*D_, nullptr, ha1, nullptr);             // h_a1
  ln2_relu_k<<<dim3(B_*N_), blk, 0, stream>>>(HB1, TMP, lng + 1*D_, lnb + 1*D_,
               lng + 2*D_, lnb + 2*D_, nullptr, HB1, hb1b);                // h_b1 (+bf16)

  // ================= layer 1 (a2a/b2a dead) =================
  {
    GJobs pe{}; int nb = 0;
    add_job(pe, nb, ha1, 0, Wm + (size_t)25*DD, 0, 0, k_a2b,  0, 512, 2);
    add_job(pe, nb, ha1, 0, Wm + (size_t)26*DD, 0, 0, 0, vt_a2b, 512, 4);
    add_job(pe, nb, 0, hb1b, Wm + (size_t)20*DD, 0, 0, qb_b2b, 0, 8192, 2);
    add_job(pe, nb, 0, hb1b, Wm + (size_t)21*DD, 0, 0, kb_b2b, 0, 8192, 2);
    add_job(pe, nb, 0, hb1b, Wm + (size_t)22*DD, 0, 0, 0, vt_b2b, 8192, 4);
    add_job(pe, nb, 0, hb1b, Wm + (size_t)24*DD, 0, 0, qb_a2b, 0, 8192, 2);
    gemm_multi<<<nb, blk, 0, stream>>>(pe);
  }
  attn_mfma<<<dim3(16, NH_, B_), blk, 0, stream>>>(qb_b2b, kb_b2b, vt_b2b, pm_s,  o_b2b, N_, N_);
  attn_mfma<<<dim3(16, NH_, B_), blk, 0, stream>>>(qb_a2b, k_a2b,  vt_a2b, pm_is, o_a2b, N_, NI_);
  {
    GJobs pg{}; int nb = 0;
    add_job(pg, nb, 0, o_b2b, Wm + (size_t)23*DD, HB1, K,   0, 0, 8192, 1);  // K overlays dead vt_b2b/qb_a2b
    add_job(pg, nb, 0, o_a2b, Wm + (size_t)27*DD, HB1, TMP, 0, 0, 8192, 1);
    gemm_multi<<<nb, blk, 0, stream>>>(pg);
  }
  ln2_relu_k<<<dim3(B_*N_), blk, 0, stream>>>(K, TMP, lng + 5*D_, lnb + 5*D_,
               lng + 6*D_, lnb + 6*D_, xf, out0, o0b);                     // slot_out (+bf16)

  // ---- logits (bf16 A and intermediate) ----
  gemm_mfma<<<dim3(4, (B_*N_)/128), blk, 0, stream>>>(nullptr, o0b, W1s, linb1, nullptr,
      nullptr, zb, nullptr, 0, D_, 1, 2, 0,0,0,0);
  gemm_mfma<<<dim3(1, (B_*N_)/128), blk, 0, stream>>>(nullptr, zb, W2s, linb2, nullptr,
      out1, nullptr, nullptr, 0, OUT_, 0, 1, 0,0,0,0);

  // ================= GAT branch =================
  gemm_mfma<<<dim3(4, (B_*N_)/128), blk, 0, stream>>>(xf, nullptr, Wg, nullptr, nullptr,
      Q, nullptr, htb, B_*N_, D_, 0, 5, 0,0,0,0);
  gat1_scores<<<(H_*B_*N_)/4, blk, 0, stream>>>(Q, gata, s1, s2);
  gat1_mfma<<<dim3(N_/32, H_, B_), blk, 0, stream>>>(pm_s, s1, s2, htb, xcb);
  gemm_mfma<<<dim3(4, (B_*N_)/128), blk, 0, stream>>>(nullptr, xcb, Wgo, nullptr, nullptr,
      V, nullptr, h2f, 0, D_, 0, 9, 0,0,0,0);
  gat2_scores<<<(B_*N_)/4, blk, 0, stream>>>(V, gatoa, s1o, s2o);
  gat2_prob<<<B_*N_, blk, 0, stream>>>(pm_s, s1o, s2o, Pb);
  gemm_mfma<<<dim3(4, N_/128, B_), blk, 0, stream>>>(nullptr, Pb, h2f, nullptr, xf,
      out2, nullptr, nullptr, 0, D_, 2, 1,
      (size_t)N_*N_, (size_t)DD, (size_t)N_*D_, (size_t)N_*D_);
}